// Round 1
// baseline (317.671 us; speedup 1.0000x reference)
//
#include <hip/hip_runtime.h>

#define NN 50000            // nodes
#define NE 800000           // edges
#define NF 128              // input features
#define NH 64               // hidden
#define NG 256              // graphs
#define NT (NE + NN)        // edges incl self-loops

// ---------------------------------------------------------------- degree
__global__ __launch_bounds__(256) void count_deg(const int* __restrict__ ei,
                                                 int* __restrict__ deg) {
    int e = blockIdx.x * 256 + threadIdx.x;
    if (e >= NE) return;
    atomicAdd(&deg[ei[NE + e]], 1);   // dst row
}

__global__ __launch_bounds__(256) void dis_kernel(const int* __restrict__ deg,
                                                  float* __restrict__ dis) {
    int i = blockIdx.x * 256 + threadIdx.x;
    if (i >= NN) return;
    dis[i] = rsqrtf((float)(deg[i] + 1));   // +1 = self-loop
}

// ---------------------------------------------------------------- scan (counts = deg+1)
__global__ __launch_bounds__(256) void scan_part(const int* __restrict__ deg,
                                                 int* __restrict__ partial) {
    int b = blockIdx.x, t = threadIdx.x;
    int base = b * 1024 + t * 4;
    int sum = 0;
#pragma unroll
    for (int j = 0; j < 4; ++j) {
        int i = base + j;
        if (i < NN) sum += deg[i] + 1;
    }
    for (int off = 32; off; off >>= 1) sum += __shfl_down(sum, off);
    __shared__ int ws_[4];
    if ((t & 63) == 0) ws_[t >> 6] = sum;
    __syncthreads();
    if (t == 0) partial[b] = ws_[0] + ws_[1] + ws_[2] + ws_[3];
}

__global__ void scan_off(const int* __restrict__ partial, int* __restrict__ poff,
                         int nb) {
    if (threadIdx.x == 0 && blockIdx.x == 0) {
        int r = 0;
        for (int i = 0; i < nb; ++i) { poff[i] = r; r += partial[i]; }
    }
}

__global__ __launch_bounds__(256) void scan_write(const int* __restrict__ deg,
                                                  const int* __restrict__ poff,
                                                  int* __restrict__ row_start,
                                                  int* __restrict__ cursor) {
    int b = blockIdx.x, t = threadIdx.x;
    int base = b * 1024 + t * 4;
    int c[4];
    int s4 = 0;
#pragma unroll
    for (int j = 0; j < 4; ++j) {
        int i = base + j;
        c[j] = (i < NN) ? (deg[i] + 1) : 0;
        s4 += c[j];
    }
    __shared__ int sc[256];
    sc[t] = s4;
    __syncthreads();
    for (int off = 1; off < 256; off <<= 1) {
        int v = (t >= off) ? sc[t - off] : 0;
        __syncthreads();
        sc[t] += v;
        __syncthreads();
    }
    int excl = sc[t] - s4 + poff[b];
#pragma unroll
    for (int j = 0; j < 4; ++j) {
        int i = base + j;
        if (i < NN) { row_start[i] = excl; cursor[i] = excl; }
        excl += c[j];
    }
    if (b == 0 && t == 0) row_start[NN] = NT;
}

// ---------------------------------------------------------------- CSR fill
__global__ __launch_bounds__(256) void fill_csr(const int* __restrict__ ei,
                                                const float* __restrict__ dis,
                                                int* __restrict__ cursor,
                                                int* __restrict__ csr_src,
                                                float* __restrict__ csr_norm) {
    int e = blockIdx.x * 256 + threadIdx.x;
    if (e >= NT) return;
    int s, d;
    if (e < NE) { s = ei[e]; d = ei[NE + e]; }
    else        { s = d = e - NE; }
    float nm = dis[s] * dis[d];
    int pos = atomicAdd(&cursor[d], 1);
    csr_src[pos]  = s;
    csr_norm[pos] = nm;
}

// ---------------------------------------------------------------- GEMM: Y[n x 64] = X[n x K] @ W[K x 64]
// 64-node x 64-col tile per block, 256 threads, 4x4 register tile.
// Xs transposed [k][node], stride 68: float4-aligned, <=2-way LDS bank alias.
template <int K>
__global__ __launch_bounds__(256) void gemm64(const float* __restrict__ X,
                                              const float* __restrict__ W,
                                              float* __restrict__ Y) {
    constexpr int XS = 68;
    __shared__ float Ws[K * 64];
    __shared__ float Xs[K * XS];
    const int t = threadIdx.x;
    const int base = blockIdx.x * 64;

    // stage W (row-major copy)
    for (int i = t * 4; i < K * 64; i += 1024)
        *(float4*)&Ws[i] = *(const float4*)&W[i];
    // stage X, transposed into Xs[k][node]
    for (int i = t * 4; i < 64 * K; i += 1024) {
        int node = i / K;
        int k = i - node * K;
        int gn = base + node;
        if (gn >= NN) gn = NN - 1;           // clamp (writes guarded later)
        float4 v = *(const float4*)&X[(size_t)gn * K + k];
        Xs[(k + 0) * XS + node] = v.x;
        Xs[(k + 1) * XS + node] = v.y;
        Xs[(k + 2) * XS + node] = v.z;
        Xs[(k + 3) * XS + node] = v.w;
    }
    __syncthreads();

    const int n0 = (t & 15) * 4;   // 16 node-groups x 4 nodes
    const int c0 = (t >> 4) * 4;   // 16 col-groups  x 4 cols
    float4 acc[4] = {};
#pragma unroll 4
    for (int k = 0; k < K; ++k) {
        const float4 xv = *(const float4*)&Xs[k * XS + n0];
        const float4 wv = *(const float4*)&Ws[k * 64 + c0];
        acc[0].x += xv.x * wv.x; acc[0].y += xv.x * wv.y; acc[0].z += xv.x * wv.z; acc[0].w += xv.x * wv.w;
        acc[1].x += xv.y * wv.x; acc[1].y += xv.y * wv.y; acc[1].z += xv.y * wv.z; acc[1].w += xv.y * wv.w;
        acc[2].x += xv.z * wv.x; acc[2].y += xv.z * wv.y; acc[2].z += xv.z * wv.z; acc[2].w += xv.z * wv.w;
        acc[3].x += xv.w * wv.x; acc[3].y += xv.w * wv.y; acc[3].z += xv.w * wv.z; acc[3].w += xv.w * wv.w;
    }
#pragma unroll
    for (int i = 0; i < 4; ++i) {
        int gn = base + n0 + i;
        if (gn < NN)
            *(float4*)&Y[(size_t)gn * 64 + c0] = acc[i];
    }
}

// ---------------------------------------------------------------- aggregation
// one wave per node; 16 lanes x float4 per edge, 4 edges in flight
__global__ __launch_bounds__(256) void agg_kernel(const float* __restrict__ h,
                                                  const int* __restrict__ row_start,
                                                  const int* __restrict__ csr_src,
                                                  const float* __restrict__ csr_norm,
                                                  const float* __restrict__ bias,
                                                  float* __restrict__ out) {
    const int gt = blockIdx.x * 256 + threadIdx.x;
    const int node = gt >> 6;                 // grid sized exactly: node < NN
    const int lane = threadIdx.x & 63;
    const int sub = lane >> 4;                // which of 4 concurrent edges
    const int q4 = (lane & 15) * 4;           // 4 dims of 64
    const int s = row_start[node];
    const int e = row_start[node + 1];
    float4 acc = {0.f, 0.f, 0.f, 0.f};
    for (int i = s + sub; i < e; i += 4) {
        const int src = csr_src[i];
        const float w = csr_norm[i];
        const float4 hv = *(const float4*)&h[(size_t)src * 64 + q4];
        acc.x += hv.x * w;
        acc.y += hv.y * w;
        acc.z += hv.z * w;
        acc.w += hv.w * w;
    }
    // reduce the 4 sub-groups (lanes q, q+16, q+32, q+48)
    acc.x += __shfl_xor(acc.x, 16); acc.y += __shfl_xor(acc.y, 16);
    acc.z += __shfl_xor(acc.z, 16); acc.w += __shfl_xor(acc.w, 16);
    acc.x += __shfl_xor(acc.x, 32); acc.y += __shfl_xor(acc.y, 32);
    acc.z += __shfl_xor(acc.z, 32); acc.w += __shfl_xor(acc.w, 32);
    if (sub == 0) {
        const float4 bv = *(const float4*)&bias[q4];
        float4 r;
        r.x = fmaxf(acc.x + bv.x, 0.f);
        r.y = fmaxf(acc.y + bv.y, 0.f);
        r.z = fmaxf(acc.z + bv.z, 0.f);
        r.w = fmaxf(acc.w + bv.w, 0.f);
        *(float4*)&out[(size_t)node * 64 + q4] = r;
    }
}

// ---------------------------------------------------------------- pool (mean per graph) + MLP head
__global__ __launch_bounds__(256) void pool_head(const float* __restrict__ h,
                                                 const int* __restrict__ batch,
                                                 const float* __restrict__ Wm1,
                                                 const float* __restrict__ bm1,
                                                 const float* __restrict__ Wm2,
                                                 const float* __restrict__ bm2,
                                                 float* __restrict__ out) {
    const int g = blockIdx.x;
    const int t = threadIdx.x;
    // lower_bound(batch, g) and lower_bound(batch, g+1) — batch is sorted
    int lo = 0, hi = NN;
    while (lo < hi) { int m = (lo + hi) >> 1; if (batch[m] < g) lo = m + 1; else hi = m; }
    const int s = lo;
    hi = NN;
    while (lo < hi) { int m = (lo + hi) >> 1; if (batch[m] < g + 1) lo = m + 1; else hi = m; }
    const int e = lo;

    const int lane = t & 63, w = t >> 6;
    float acc = 0.f;
    for (int i = s + w; i < e; i += 4)
        acc += h[(size_t)i * 64 + lane];
    __shared__ float red[4 * 64];
    __shared__ float pl[64];
    red[w * 64 + lane] = acc;
    __syncthreads();
    if (t < 64) {
        float v = red[t] + red[64 + t] + red[128 + t] + red[192 + t];
        int cnt = e - s;
        pl[t] = v / (float)(cnt > 0 ? cnt : 1);
    }
    __syncthreads();
    if (t < 64) {
        float z = bm1[t];
#pragma unroll 8
        for (int k = 0; k < 64; ++k)
            z += pl[k] * Wm1[k * 64 + t];
        z = fmaxf(z, 0.f);
        float y = z * Wm2[t];
        for (int off = 32; off; off >>= 1) y += __shfl_down(y, off);
        if (t == 0) out[g] = y + bm2[0];
    }
}

// ---------------------------------------------------------------- launch
extern "C" void kernel_launch(void* const* d_in, const int* in_sizes, int n_in,
                              void* d_out, int out_size, void* d_ws, size_t ws_size,
                              hipStream_t stream) {
    const float* x   = (const float*)d_in[0];
    const int*   ei  = (const int*)d_in[1];
    const int*   bat = (const int*)d_in[2];
    const float* W1  = (const float*)d_in[3];
    const float* b1  = (const float*)d_in[4];
    const float* W2  = (const float*)d_in[5];
    const float* b2  = (const float*)d_in[6];
    const float* Wm1 = (const float*)d_in[7];
    const float* bm1 = (const float*)d_in[8];
    const float* Wm2 = (const float*)d_in[9];
    const float* bm2 = (const float*)d_in[10];
    float* out = (float*)d_out;

    char* w = (char*)d_ws;
    int*   deg       = (int*)  (w + 0);          // 200000 B
    int*   cursor    = (int*)  (w + 200192);     // 200000 B
    int*   row_start = (int*)  (w + 400384);     // 200004 B
    float* dis       = (float*)(w + 600576);     // 200000 B
    int*   partial   = (int*)  (w + 800768);     // 196 B
    int*   poff      = (int*)  (w + 801024);     // 196 B
    int*   csr_src   = (int*)  (w + 801280);     // 3400000 B
    float* csr_norm  = (float*)(w + 4201472);    // 3400000 B
    float* bufA      = (float*)(w + 7601664);    // 12800000 B
    float* bufB      = (float*)(w + 20401920);   // 12800000 B  (end ~33.2 MB)

    hipMemsetAsync(deg, 0, NN * sizeof(int), stream);
    count_deg <<<(NE + 255) / 256, 256, 0, stream>>>(ei, deg);
    dis_kernel<<<(NN + 255) / 256, 256, 0, stream>>>(deg, dis);
    scan_part <<<(NN + 1023) / 1024, 256, 0, stream>>>(deg, partial);
    scan_off  <<<1, 64, 0, stream>>>(partial, poff, (NN + 1023) / 1024);
    scan_write<<<(NN + 1023) / 1024, 256, 0, stream>>>(deg, poff, row_start, cursor);
    fill_csr  <<<(NT + 255) / 256, 256, 0, stream>>>(ei, dis, cursor, csr_src, csr_norm);

    gemm64<NF><<<(NN + 63) / 64, 256, 0, stream>>>(x, W1, bufA);
    agg_kernel<<<(NN * 64) / 256, 256, 0, stream>>>(bufA, row_start, csr_src, csr_norm, b1, bufB);
    gemm64<NH><<<(NN + 63) / 64, 256, 0, stream>>>(bufB, W2, bufA);
    agg_kernel<<<(NN * 64) / 256, 256, 0, stream>>>(bufA, row_start, csr_src, csr_norm, b2, bufB);
    pool_head <<<NG, 256, 0, stream>>>(bufB, bat, Wm1, bm1, Wm2, bm2, out);
}

// Round 2
// 316.471 us; speedup vs baseline: 1.0038x; 1.0038x over previous
//
#include <hip/hip_runtime.h>

#define NN 50000            // nodes
#define NE 800000           // edges
#define NF 128              // input features
#define NH 64               // hidden
#define NG 256              // graphs
#define NT (NE + NN)        // edges incl self-loops

// ---------------------------------------------------------------- degree
__global__ __launch_bounds__(256) void count_deg(const int* __restrict__ ei,
                                                 int* __restrict__ deg) {
    int e = blockIdx.x * 256 + threadIdx.x;
    if (e >= NE) return;
    atomicAdd(&deg[ei[NE + e]], 1);   // dst row
}

__global__ __launch_bounds__(256) void dis_kernel(const int* __restrict__ deg,
                                                  float* __restrict__ dis) {
    int i = blockIdx.x * 256 + threadIdx.x;
    if (i >= NN) return;
    dis[i] = rsqrtf((float)(deg[i] + 1));   // +1 = self-loop
}

// ---------------------------------------------------------------- scan (counts = deg+1)
__global__ __launch_bounds__(256) void scan_part(const int* __restrict__ deg,
                                                 int* __restrict__ partial) {
    int b = blockIdx.x, t = threadIdx.x;
    int base = b * 1024 + t * 4;
    int sum = 0;
#pragma unroll
    for (int j = 0; j < 4; ++j) {
        int i = base + j;
        if (i < NN) sum += deg[i] + 1;
    }
    for (int off = 32; off; off >>= 1) sum += __shfl_down(sum, off);
    __shared__ int ws_[4];
    if ((t & 63) == 0) ws_[t >> 6] = sum;
    __syncthreads();
    if (t == 0) partial[b] = ws_[0] + ws_[1] + ws_[2] + ws_[3];
}

__global__ void scan_off(const int* __restrict__ partial, int* __restrict__ poff,
                         int nb) {
    if (threadIdx.x == 0 && blockIdx.x == 0) {
        int r = 0;
        for (int i = 0; i < nb; ++i) { poff[i] = r; r += partial[i]; }
    }
}

__global__ __launch_bounds__(256) void scan_write(const int* __restrict__ deg,
                                                  const int* __restrict__ poff,
                                                  int* __restrict__ row_start,
                                                  int* __restrict__ cursor) {
    int b = blockIdx.x, t = threadIdx.x;
    int base = b * 1024 + t * 4;
    int c[4];
    int s4 = 0;
#pragma unroll
    for (int j = 0; j < 4; ++j) {
        int i = base + j;
        c[j] = (i < NN) ? (deg[i] + 1) : 0;
        s4 += c[j];
    }
    __shared__ int sc[256];
    sc[t] = s4;
    __syncthreads();
    for (int off = 1; off < 256; off <<= 1) {
        int v = (t >= off) ? sc[t - off] : 0;
        __syncthreads();
        sc[t] += v;
        __syncthreads();
    }
    int excl = sc[t] - s4 + poff[b];
#pragma unroll
    for (int j = 0; j < 4; ++j) {
        int i = base + j;
        if (i < NN) { row_start[i] = excl; cursor[i] = excl; }
        excl += c[j];
    }
    if (b == 0 && t == 0) row_start[NN] = NT;
}

// ---------------------------------------------------------------- CSR fill (src only — norm factorized out)
__global__ __launch_bounds__(256) void fill_csr(const int* __restrict__ ei,
                                                int* __restrict__ cursor,
                                                int* __restrict__ csr_src) {
    int e = blockIdx.x * 256 + threadIdx.x;
    if (e >= NT) return;
    int s, d;
    if (e < NE) { s = ei[e]; d = ei[NE + e]; }
    else        { s = d = e - NE; }
    int pos = atomicAdd(&cursor[d], 1);
    csr_src[pos] = s;
}

// ---------------------------------------------------------------- GEMM: Y[n x 64] = X[n x K] @ W[K x 64]
// 64-node x 64-col tile per block, 256 threads, 4x4 register tile.
// Xs transposed [k][node], stride 68: float4-aligned, <=2-way LDS bank alias.
template <int K>
__global__ __launch_bounds__(256) void gemm64(const float* __restrict__ X,
                                              const float* __restrict__ W,
                                              float* __restrict__ Y) {
    constexpr int XS = 68;
    __shared__ float Ws[K * 64];
    __shared__ float Xs[K * XS];
    const int t = threadIdx.x;
    const int base = blockIdx.x * 64;

    // stage W (row-major copy)
    for (int i = t * 4; i < K * 64; i += 1024)
        *(float4*)&Ws[i] = *(const float4*)&W[i];
    // stage X, transposed into Xs[k][node]
    for (int i = t * 4; i < 64 * K; i += 1024) {
        int node = i / K;
        int k = i - node * K;
        int gn = base + node;
        if (gn >= NN) gn = NN - 1;           // clamp (writes guarded later)
        float4 v = *(const float4*)&X[(size_t)gn * K + k];
        Xs[(k + 0) * XS + node] = v.x;
        Xs[(k + 1) * XS + node] = v.y;
        Xs[(k + 2) * XS + node] = v.z;
        Xs[(k + 3) * XS + node] = v.w;
    }
    __syncthreads();

    const int n0 = (t & 15) * 4;   // 16 node-groups x 4 nodes
    const int c0 = (t >> 4) * 4;   // 16 col-groups  x 4 cols
    float4 acc[4] = {};
#pragma unroll 4
    for (int k = 0; k < K; ++k) {
        const float4 xv = *(const float4*)&Xs[k * XS + n0];
        const float4 wv = *(const float4*)&Ws[k * 64 + c0];
        acc[0].x += xv.x * wv.x; acc[0].y += xv.x * wv.y; acc[0].z += xv.x * wv.z; acc[0].w += xv.x * wv.w;
        acc[1].x += xv.y * wv.x; acc[1].y += xv.y * wv.y; acc[1].z += xv.y * wv.z; acc[1].w += xv.y * wv.w;
        acc[2].x += xv.z * wv.x; acc[2].y += xv.z * wv.y; acc[2].z += xv.z * wv.z; acc[2].w += xv.z * wv.w;
        acc[3].x += xv.w * wv.x; acc[3].y += xv.w * wv.y; acc[3].z += xv.w * wv.z; acc[3].w += xv.w * wv.w;
    }
#pragma unroll
    for (int i = 0; i < 4; ++i) {
        int gn = base + n0 + i;
        if (gn < NN)
            *(float4*)&Y[(size_t)gn * 64 + c0] = acc[i];
    }
}

// ---------------------------------------------------------------- aggregation
// one wave per node; 16 lanes x float4 per edge, 4 edges in flight.
// norm factorized: out[dst] = dis[dst] * sum_e dis[src]*h[src]  (+bias, relu)
__global__ __launch_bounds__(256) void agg_kernel(const float* __restrict__ h,
                                                  const int* __restrict__ row_start,
                                                  const int* __restrict__ csr_src,
                                                  const float* __restrict__ dis,
                                                  const float* __restrict__ bias,
                                                  float* __restrict__ out) {
    const int gt = blockIdx.x * 256 + threadIdx.x;
    const int node = gt >> 6;                 // grid sized exactly: node < NN
    const int lane = threadIdx.x & 63;
    const int sub = lane >> 4;                // which of 4 concurrent edges
    const int q4 = (lane & 15) * 4;           // 4 dims of 64
    const int s = row_start[node];
    const int e = row_start[node + 1];
    float4 acc = {0.f, 0.f, 0.f, 0.f};
    for (int i = s + sub; i < e; i += 4) {
        const int src = csr_src[i];
        const float w = dis[src];
        const float4 hv = *(const float4*)&h[(size_t)src * 64 + q4];
        acc.x += hv.x * w;
        acc.y += hv.y * w;
        acc.z += hv.z * w;
        acc.w += hv.w * w;
    }
    // reduce the 4 sub-groups (lanes q, q+16, q+32, q+48)
    acc.x += __shfl_xor(acc.x, 16); acc.y += __shfl_xor(acc.y, 16);
    acc.z += __shfl_xor(acc.z, 16); acc.w += __shfl_xor(acc.w, 16);
    acc.x += __shfl_xor(acc.x, 32); acc.y += __shfl_xor(acc.y, 32);
    acc.z += __shfl_xor(acc.z, 32); acc.w += __shfl_xor(acc.w, 32);
    if (sub == 0) {
        const float dn = dis[node];
        const float4 bv = *(const float4*)&bias[q4];
        float4 r;
        r.x = fmaxf(acc.x * dn + bv.x, 0.f);
        r.y = fmaxf(acc.y * dn + bv.y, 0.f);
        r.z = fmaxf(acc.z * dn + bv.z, 0.f);
        r.w = fmaxf(acc.w * dn + bv.w, 0.f);
        *(float4*)&out[(size_t)node * 64 + q4] = r;
    }
}

// ---------------------------------------------------------------- pool (mean per graph) + MLP head
__global__ __launch_bounds__(256) void pool_head(const float* __restrict__ h,
                                                 const int* __restrict__ batch,
                                                 const float* __restrict__ Wm1,
                                                 const float* __restrict__ bm1,
                                                 const float* __restrict__ Wm2,
                                                 const float* __restrict__ bm2,
                                                 float* __restrict__ out) {
    const int g = blockIdx.x;
    const int t = threadIdx.x;
    // lower_bound(batch, g) and lower_bound(batch, g+1) — batch is sorted
    int lo = 0, hi = NN;
    while (lo < hi) { int m = (lo + hi) >> 1; if (batch[m] < g) lo = m + 1; else hi = m; }
    const int s = lo;
    hi = NN;
    while (lo < hi) { int m = (lo + hi) >> 1; if (batch[m] < g + 1) lo = m + 1; else hi = m; }
    const int e = lo;

    const int lane = t & 63, w = t >> 6;
    float acc = 0.f;
    for (int i = s + w; i < e; i += 4)
        acc += h[(size_t)i * 64 + lane];
    __shared__ float red[4 * 64];
    __shared__ float pl[64];
    red[w * 64 + lane] = acc;
    __syncthreads();
    if (t < 64) {
        float v = red[t] + red[64 + t] + red[128 + t] + red[192 + t];
        int cnt = e - s;
        pl[t] = v / (float)(cnt > 0 ? cnt : 1);
    }
    __syncthreads();
    if (t < 64) {
        float z = bm1[t];
#pragma unroll 8
        for (int k = 0; k < 64; ++k)
            z += pl[k] * Wm1[k * 64 + t];
        z = fmaxf(z, 0.f);
        float y = z * Wm2[t];
        for (int off = 32; off; off >>= 1) y += __shfl_down(y, off);
        if (t == 0) out[g] = y + bm2[0];
    }
}

// ---------------------------------------------------------------- launch
extern "C" void kernel_launch(void* const* d_in, const int* in_sizes, int n_in,
                              void* d_out, int out_size, void* d_ws, size_t ws_size,
                              hipStream_t stream) {
    const float* x   = (const float*)d_in[0];
    const int*   ei  = (const int*)d_in[1];
    const int*   bat = (const int*)d_in[2];
    const float* W1  = (const float*)d_in[3];
    const float* b1  = (const float*)d_in[4];
    const float* W2  = (const float*)d_in[5];
    const float* b2  = (const float*)d_in[6];
    const float* Wm1 = (const float*)d_in[7];
    const float* bm1 = (const float*)d_in[8];
    const float* Wm2 = (const float*)d_in[9];
    const float* bm2 = (const float*)d_in[10];
    float* out = (float*)d_out;

    char* w = (char*)d_ws;
    int*   deg       = (int*)  (w + 0);          // 200000 B
    int*   cursor    = (int*)  (w + 200192);     // 200000 B
    int*   row_start = (int*)  (w + 400384);     // 200004 B
    float* dis       = (float*)(w + 600576);     // 200000 B
    int*   partial   = (int*)  (w + 800768);     // 196 B
    int*   poff      = (int*)  (w + 801024);     // 196 B
    int*   csr_src   = (int*)  (w + 801280);     // 3400000 B
    float* bufA      = (float*)(w + 4201472);    // 12800000 B
    float* bufB      = (float*)(w + 17001728);   // 12800000 B  (end ~29.8 MB)

    hipMemsetAsync(deg, 0, NN * sizeof(int), stream);
    count_deg <<<(NE + 255) / 256, 256, 0, stream>>>(ei, deg);
    dis_kernel<<<(NN + 255) / 256, 256, 0, stream>>>(deg, dis);
    scan_part <<<(NN + 1023) / 1024, 256, 0, stream>>>(deg, partial);
    scan_off  <<<1, 64, 0, stream>>>(partial, poff, (NN + 1023) / 1024);
    scan_write<<<(NN + 1023) / 1024, 256, 0, stream>>>(deg, poff, row_start, cursor);
    fill_csr  <<<(NT + 255) / 256, 256, 0, stream>>>(ei, cursor, csr_src);

    gemm64<NF><<<(NN + 63) / 64, 256, 0, stream>>>(x, W1, bufA);
    agg_kernel<<<(NN * 64) / 256, 256, 0, stream>>>(bufA, row_start, csr_src, dis, b1, bufB);
    gemm64<NH><<<(NN + 63) / 64, 256, 0, stream>>>(bufB, W2, bufA);
    agg_kernel<<<(NN * 64) / 256, 256, 0, stream>>>(bufA, row_start, csr_src, dis, b2, bufB);
    pool_head <<<NG, 256, 0, stream>>>(bufB, bat, Wm1, bm1, Wm2, bm2, out);
}

// Round 3
// 253.305 us; speedup vs baseline: 1.2541x; 1.2494x over previous
//
#include <hip/hip_runtime.h>

#define NN 50000            // nodes
#define NE 800000           // edges
#define NF 128              // input features
#define NH 64              // hidden
#define NG 256              // graphs
#define NT (NE + NN)        // edges incl self-loops
#define NB 196              // buckets of 256 dst nodes: ceil(50000/256)
#define CAP 5120            // per-bucket edge capacity (mean 4352, sigma ~64 -> 12 sigma)
#define CH 4096             // edges per partition block

// ---------------------------------------------------------------- cursor init
__global__ __launch_bounds__(256) void init_cursor(int* __restrict__ cursor) {
    int t = threadIdx.x;
    if (t < NB) cursor[t] = t * CAP;
}

// ---------------------------------------------------------------- level-1 partition (dense writes)
// Each block: 4096 edges -> LDS bucket-sort by dst>>8 -> one global range
// reservation per (bucket,block) -> cooperative contiguous flush.
__global__ __launch_bounds__(256) void part_scatter(const int* __restrict__ ei,
                                                    int* __restrict__ cursor,
                                                    int2* __restrict__ ebuf) {
    const int t = threadIdx.x;
    const int c0 = blockIdx.x * CH;
    __shared__ int hist[256];   // per-bucket count in this chunk
    __shared__ int incl[256];   // inclusive scan
    __shared__ int gbase[256];  // reserved global base per bucket
    __shared__ int lcur[256];   // running local cursor
    __shared__ int2 lpairs[CH]; // bucket-ordered (src,dst)

    hist[t] = 0;
    __syncthreads();

    int2 loc[16];
#pragma unroll
    for (int j = 0; j < 16; ++j) {
        int e = c0 + j * 256 + t;
        int s = -1, d = -1;
        if (e < NT) {
            if (e < NE) { s = ei[e]; d = ei[NE + e]; }
            else        { s = d = e - NE; }
            atomicAdd(&hist[d >> 8], 1);
        }
        loc[j] = make_int2(s, d);
    }
    __syncthreads();

    // Hillis-Steele inclusive scan of hist
    int v = hist[t];
    incl[t] = v;
    __syncthreads();
    for (int off = 1; off < 256; off <<= 1) {
        int u = (t >= off) ? incl[t - off] : 0;
        __syncthreads();
        incl[t] += u;
        __syncthreads();
    }
    int excl = incl[t] - v;
    if (v > 0) gbase[t] = atomicAdd(&cursor[t], v);
    lcur[t] = excl;
    __syncthreads();

    // place pairs into LDS, ordered by bucket
#pragma unroll
    for (int j = 0; j < 16; ++j) {
        int d = loc[j].y;
        if (d >= 0) {
            int p = atomicAdd(&lcur[d >> 8], 1);
            lpairs[p] = loc[j];
        }
    }
    __syncthreads();

    // contiguous flush: consecutive p -> consecutive global addresses per segment
    const int total = incl[255];
    for (int p = t; p < total; p += 256) {
        int2 pr = lpairs[p];
        int b = pr.y >> 8;
        ebuf[gbase[b] + (p - (incl[b] - hist[b]))] = pr;
    }
}

// ---------------------------------------------------------------- level-2: per-bucket CSR + deg/dis (all dense writes)
__global__ __launch_bounds__(256) void build_csr(const int2* __restrict__ ebuf,
                                                 const int* __restrict__ cursor,
                                                 int2* __restrict__ row_range,
                                                 float* __restrict__ dis,
                                                 int* __restrict__ csr_src) {
    const int b = blockIdx.x, t = threadIdx.x;
    const int e0 = b * CAP;
    const int cnt = cursor[b] - e0;
    __shared__ int deg_l[256];
    __shared__ int pre[256];
    __shared__ int cur[256];
    __shared__ int lsrc[CAP];

    deg_l[t] = 0;
    __syncthreads();
    for (int i = t; i < cnt; i += 256) {
        int2 p = ebuf[e0 + i];
        atomicAdd(&deg_l[p.y & 255], 1);
    }
    __syncthreads();
    int v = deg_l[t];
    pre[t] = v;
    __syncthreads();
    for (int off = 1; off < 256; off <<= 1) {
        int u = (t >= off) ? pre[t - off] : 0;
        __syncthreads();
        pre[t] += u;
        __syncthreads();
    }
    int excl = pre[t] - v;
    cur[t] = 0;
    int node = b * 256 + t;
    if (node < NN) {
        row_range[node] = make_int2(e0 + excl, e0 + excl + v);
        dis[node] = rsqrtf((float)v);   // v >= 1 (self-loop) -> deg+1 of reference
    }
    __syncthreads();
    for (int i = t; i < cnt; i += 256) {
        int2 p = ebuf[e0 + i];
        int d = p.y & 255;
        int pos = (pre[d] - deg_l[d]) + atomicAdd(&cur[d], 1);
        lsrc[pos] = p.x;
    }
    __syncthreads();
    for (int i = t; i < cnt; i += 256)
        csr_src[e0 + i] = lsrc[i];
}

// ---------------------------------------------------------------- GEMM: Y[n x 64] = X[n x K] @ W[K x 64]
template <int K>
__global__ __launch_bounds__(256) void gemm64(const float* __restrict__ X,
                                              const float* __restrict__ W,
                                              float* __restrict__ Y) {
    constexpr int XS = 68;
    __shared__ float Ws[K * 64];
    __shared__ float Xs[K * XS];
    const int t = threadIdx.x;
    const int base = blockIdx.x * 64;

    for (int i = t * 4; i < K * 64; i += 1024)
        *(float4*)&Ws[i] = *(const float4*)&W[i];
    for (int i = t * 4; i < 64 * K; i += 1024) {
        int node = i / K;
        int k = i - node * K;
        int gn = base + node;
        if (gn >= NN) gn = NN - 1;
        float4 v = *(const float4*)&X[(size_t)gn * K + k];
        Xs[(k + 0) * XS + node] = v.x;
        Xs[(k + 1) * XS + node] = v.y;
        Xs[(k + 2) * XS + node] = v.z;
        Xs[(k + 3) * XS + node] = v.w;
    }
    __syncthreads();

    const int n0 = (t & 15) * 4;
    const int c0 = (t >> 4) * 4;
    float4 acc[4] = {};
#pragma unroll 4
    for (int k = 0; k < K; ++k) {
        const float4 xv = *(const float4*)&Xs[k * XS + n0];
        const float4 wv = *(const float4*)&Ws[k * 64 + c0];
        acc[0].x += xv.x * wv.x; acc[0].y += xv.x * wv.y; acc[0].z += xv.x * wv.z; acc[0].w += xv.x * wv.w;
        acc[1].x += xv.y * wv.x; acc[1].y += xv.y * wv.y; acc[1].z += xv.y * wv.z; acc[1].w += xv.y * wv.w;
        acc[2].x += xv.z * wv.x; acc[2].y += xv.z * wv.y; acc[2].z += xv.z * wv.z; acc[2].w += xv.z * wv.w;
        acc[3].x += xv.w * wv.x; acc[3].y += xv.w * wv.y; acc[3].z += xv.w * wv.z; acc[3].w += xv.w * wv.w;
    }
#pragma unroll
    for (int i = 0; i < 4; ++i) {
        int gn = base + n0 + i;
        if (gn < NN)
            *(float4*)&Y[(size_t)gn * 64 + c0] = acc[i];
    }
}

// ---------------------------------------------------------------- aggregation
// out[dst] = relu(dis[dst] * sum_e dis[src]*h[src] + bias)
__global__ __launch_bounds__(256) void agg_kernel(const float* __restrict__ h,
                                                  const int2* __restrict__ row_range,
                                                  const int* __restrict__ csr_src,
                                                  const float* __restrict__ dis,
                                                  const float* __restrict__ bias,
                                                  float* __restrict__ out) {
    const int gt = blockIdx.x * 256 + threadIdx.x;
    const int node = gt >> 6;
    const int lane = threadIdx.x & 63;
    const int sub = lane >> 4;
    const int q4 = (lane & 15) * 4;
    const int2 rr = row_range[node];
    float4 acc = {0.f, 0.f, 0.f, 0.f};
    for (int i = rr.x + sub; i < rr.y; i += 4) {
        const int src = csr_src[i];
        const float w = dis[src];
        const float4 hv = *(const float4*)&h[(size_t)src * 64 + q4];
        acc.x += hv.x * w;
        acc.y += hv.y * w;
        acc.z += hv.z * w;
        acc.w += hv.w * w;
    }
    acc.x += __shfl_xor(acc.x, 16); acc.y += __shfl_xor(acc.y, 16);
    acc.z += __shfl_xor(acc.z, 16); acc.w += __shfl_xor(acc.w, 16);
    acc.x += __shfl_xor(acc.x, 32); acc.y += __shfl_xor(acc.y, 32);
    acc.z += __shfl_xor(acc.z, 32); acc.w += __shfl_xor(acc.w, 32);
    if (sub == 0) {
        const float dn = dis[node];
        const float4 bv = *(const float4*)&bias[q4];
        float4 r;
        r.x = fmaxf(acc.x * dn + bv.x, 0.f);
        r.y = fmaxf(acc.y * dn + bv.y, 0.f);
        r.z = fmaxf(acc.z * dn + bv.z, 0.f);
        r.w = fmaxf(acc.w * dn + bv.w, 0.f);
        *(float4*)&out[(size_t)node * 64 + q4] = r;
    }
}

// ---------------------------------------------------------------- pool (mean per graph) + MLP head
__global__ __launch_bounds__(256) void pool_head(const float* __restrict__ h,
                                                 const int* __restrict__ batch,
                                                 const float* __restrict__ Wm1,
                                                 const float* __restrict__ bm1,
                                                 const float* __restrict__ Wm2,
                                                 const float* __restrict__ bm2,
                                                 float* __restrict__ out) {
    const int g = blockIdx.x;
    const int t = threadIdx.x;
    int lo = 0, hi = NN;
    while (lo < hi) { int m = (lo + hi) >> 1; if (batch[m] < g) lo = m + 1; else hi = m; }
    const int s = lo;
    hi = NN;
    while (lo < hi) { int m = (lo + hi) >> 1; if (batch[m] < g + 1) lo = m + 1; else hi = m; }
    const int e = lo;

    const int lane = t & 63, w = t >> 6;
    float acc = 0.f;
    for (int i = s + w; i < e; i += 4)
        acc += h[(size_t)i * 64 + lane];
    __shared__ float red[4 * 64];
    __shared__ float pl[64];
    red[w * 64 + lane] = acc;
    __syncthreads();
    if (t < 64) {
        float v = red[t] + red[64 + t] + red[128 + t] + red[192 + t];
        int cnt = e - s;
        pl[t] = v / (float)(cnt > 0 ? cnt : 1);
    }
    __syncthreads();
    if (t < 64) {
        float z = bm1[t];
#pragma unroll 8
        for (int k = 0; k < 64; ++k)
            z += pl[k] * Wm1[k * 64 + t];
        z = fmaxf(z, 0.f);
        float y = z * Wm2[t];
        for (int off = 32; off; off >>= 1) y += __shfl_down(y, off);
        if (t == 0) out[g] = y + bm2[0];
    }
}

// ---------------------------------------------------------------- launch
extern "C" void kernel_launch(void* const* d_in, const int* in_sizes, int n_in,
                              void* d_out, int out_size, void* d_ws, size_t ws_size,
                              hipStream_t stream) {
    const float* x   = (const float*)d_in[0];
    const int*   ei  = (const int*)d_in[1];
    const int*   bat = (const int*)d_in[2];
    const float* W1  = (const float*)d_in[3];
    const float* b1  = (const float*)d_in[4];
    const float* W2  = (const float*)d_in[5];
    const float* b2  = (const float*)d_in[6];
    const float* Wm1 = (const float*)d_in[7];
    const float* bm1 = (const float*)d_in[8];
    const float* Wm2 = (const float*)d_in[9];
    const float* bm2 = (const float*)d_in[10];
    float* out = (float*)d_out;

    // workspace layout (ebuf aliased under bufB — ebuf dead after build_csr)
    char* w = (char*)d_ws;
    int*   cursor    = (int*)  (w + 0);          //      1024 B
    int2*  row_range = (int2*) (w + 1024);       //   400000 B
    float* dis       = (float*)(w + 401024);     //   200000 B
    int*   csr_src   = (int*)  (w + 601024);     //  4014080 B (NB*CAP*4)
    int2*  ebuf      = (int2*) (w + 4615104);    //  8028160 B (NB*CAP*8, aliased w/ bufB)
    float* bufB      = (float*)(w + 4615104);    // 12800000 B -> ends 17415104
    float* bufA      = (float*)(w + 17415104);   // 12800000 B -> ends 30215104 (~30.2 MB)

    init_cursor <<<1, 256, 0, stream>>>(cursor);
    part_scatter<<<(NT + CH - 1) / CH, 256, 0, stream>>>(ei, cursor, ebuf);
    build_csr   <<<NB, 256, 0, stream>>>(ebuf, cursor, row_range, dis, csr_src);

    gemm64<NF><<<(NN + 63) / 64, 256, 0, stream>>>(x, W1, bufA);
    agg_kernel<<<(NN * 64) / 256, 256, 0, stream>>>(bufA, row_range, csr_src, dis, b1, bufB);
    gemm64<NH><<<(NN + 63) / 64, 256, 0, stream>>>(bufB, W2, bufA);
    agg_kernel<<<(NN * 64) / 256, 256, 0, stream>>>(bufA, row_range, csr_src, dis, b2, bufB);
    pool_head <<<NG, 256, 0, stream>>>(bufB, bat, Wm1, bm1, Wm2, bm2, out);
}

// Round 4
// 239.399 us; speedup vs baseline: 1.3270x; 1.0581x over previous
//
#include <hip/hip_runtime.h>

#define NN 50000            // nodes
#define NE 800000           // edges
#define NF 128              // input features
#define NH 64               // hidden
#define NG 256              // graphs
#define NT (NE + NN)        // edges incl self-loops
#define NB 196              // buckets of 256 dst nodes
#define CAP 5120            // per-bucket edge capacity
#define CH 4096             // edges per partition block

static __device__ __forceinline__ float b2f(unsigned short u) {
    return __uint_as_float((unsigned)u << 16);
}
static __device__ __forceinline__ unsigned short f2bf(float f) {
    union { float f; unsigned u; } v; v.f = f;
    unsigned r = v.u + 0x7FFF + ((v.u >> 16) & 1);   // RNE
    return (unsigned short)(r >> 16);
}

// ---------------------------------------------------------------- level-1 partition (dense writes)
__global__ __launch_bounds__(256) void part_scatter(const int* __restrict__ ei,
                                                    int* __restrict__ cursor,
                                                    int2* __restrict__ ebuf) {
    const int t = threadIdx.x;
    const int c0 = blockIdx.x * CH;
    __shared__ int hist[256];
    __shared__ int incl[256];
    __shared__ int gbase[256];
    __shared__ int lcur[256];
    __shared__ int2 lpairs[CH];

    hist[t] = 0;
    __syncthreads();

    int2 loc[16];
#pragma unroll
    for (int j = 0; j < 16; ++j) {
        int e = c0 + j * 256 + t;
        int s = -1, d = -1;
        if (e < NT) {
            if (e < NE) { s = ei[e]; d = ei[NE + e]; }
            else        { s = d = e - NE; }
            atomicAdd(&hist[d >> 8], 1);
        }
        loc[j] = make_int2(s, d);
    }
    __syncthreads();

    int v = hist[t];
    incl[t] = v;
    __syncthreads();
    for (int off = 1; off < 256; off <<= 1) {
        int u = (t >= off) ? incl[t - off] : 0;
        __syncthreads();
        incl[t] += u;
        __syncthreads();
    }
    int excl = incl[t] - v;
    if (v > 0) gbase[t] = t * CAP + atomicAdd(&cursor[t], v);
    lcur[t] = excl;
    __syncthreads();

#pragma unroll
    for (int j = 0; j < 16; ++j) {
        int d = loc[j].y;
        if (d >= 0) {
            int p = atomicAdd(&lcur[d >> 8], 1);
            lpairs[p] = loc[j];
        }
    }
    __syncthreads();

    const int total = incl[255];
    for (int p = t; p < total; p += 256) {
        int2 pr = lpairs[p];
        int b = pr.y >> 8;
        ebuf[gbase[b] + (p - (incl[b] - hist[b]))] = pr;
    }
}

// ---------------------------------------------------------------- level-2: per-bucket CSR + dis
__global__ __launch_bounds__(256) void build_csr(const int2* __restrict__ ebuf,
                                                 const int* __restrict__ cursor,
                                                 int2* __restrict__ row_range,
                                                 float* __restrict__ dis,
                                                 int* __restrict__ csr_src) {
    const int b = blockIdx.x, t = threadIdx.x;
    const int e0 = b * CAP;
    const int cnt = cursor[b];
    __shared__ int deg_l[256];
    __shared__ int pre[256];
    __shared__ int cur[256];
    __shared__ int lsrc[CAP];

    deg_l[t] = 0;
    __syncthreads();
    for (int i = t; i < cnt; i += 256) {
        int2 p = ebuf[e0 + i];
        atomicAdd(&deg_l[p.y & 255], 1);
    }
    __syncthreads();
    int v = deg_l[t];
    pre[t] = v;
    __syncthreads();
    for (int off = 1; off < 256; off <<= 1) {
        int u = (t >= off) ? pre[t - off] : 0;
        __syncthreads();
        pre[t] += u;
        __syncthreads();
    }
    int excl = pre[t] - v;
    cur[t] = 0;
    int node = b * 256 + t;
    if (node < NN) {
        row_range[node] = make_int2(e0 + excl, e0 + excl + v);
        dis[node] = rsqrtf((float)v);   // v = deg+1 (self-loop included)
    }
    __syncthreads();
    for (int i = t; i < cnt; i += 256) {
        int2 p = ebuf[e0 + i];
        int d = p.y & 255;
        int pos = (pre[d] - deg_l[d]) + atomicAdd(&cur[d], 1);
        lsrc[pos] = p.x;
    }
    __syncthreads();
    for (int i = t; i < cnt; i += 256)
        csr_src[e0 + i] = lsrc[i];
}

// ---------------------------------------------------------------- GEMM: Y[n x 64] = X[n x K] @ W[K x 64], bf16 out
// SCALE_DIS: multiply output row by dis[node] (folds GCN src-norm into storage)
template <int K, bool BF16_IN, bool SCALE_DIS>
__global__ __launch_bounds__(256) void gemm64(const void* __restrict__ Xv,
                                              const float* __restrict__ W,
                                              const float* __restrict__ dis,
                                              unsigned short* __restrict__ Y) {
    constexpr int XS = 68;
    __shared__ float Ws[K * 64];
    __shared__ float Xs[K * XS];
    const int t = threadIdx.x;
    const int base = blockIdx.x * 64;

    for (int i = t * 4; i < K * 64; i += 1024)
        *(float4*)&Ws[i] = *(const float4*)&W[i];
    for (int i = t * 4; i < 64 * K; i += 1024) {
        int node = i / K;
        int k = i - node * K;
        int gn = base + node;
        if (gn >= NN) gn = NN - 1;
        float4 v;
        if (BF16_IN) {
            ushort4 u = *(const ushort4*)((const unsigned short*)Xv + (size_t)gn * K + k);
            v.x = b2f(u.x); v.y = b2f(u.y); v.z = b2f(u.z); v.w = b2f(u.w);
        } else {
            v = *(const float4*)((const float*)Xv + (size_t)gn * K + k);
        }
        Xs[(k + 0) * XS + node] = v.x;
        Xs[(k + 1) * XS + node] = v.y;
        Xs[(k + 2) * XS + node] = v.z;
        Xs[(k + 3) * XS + node] = v.w;
    }
    __syncthreads();

    const int n0 = (t & 15) * 4;
    const int c0 = (t >> 4) * 4;
    float4 acc[4] = {};
#pragma unroll 4
    for (int k = 0; k < K; ++k) {
        const float4 xv = *(const float4*)&Xs[k * XS + n0];
        const float4 wv = *(const float4*)&Ws[k * 64 + c0];
        acc[0].x += xv.x * wv.x; acc[0].y += xv.x * wv.y; acc[0].z += xv.x * wv.z; acc[0].w += xv.x * wv.w;
        acc[1].x += xv.y * wv.x; acc[1].y += xv.y * wv.y; acc[1].z += xv.y * wv.z; acc[1].w += xv.y * wv.w;
        acc[2].x += xv.z * wv.x; acc[2].y += xv.z * wv.y; acc[2].z += xv.z * wv.z; acc[2].w += xv.z * wv.w;
        acc[3].x += xv.w * wv.x; acc[3].y += xv.w * wv.y; acc[3].z += xv.w * wv.z; acc[3].w += xv.w * wv.w;
    }
#pragma unroll
    for (int i = 0; i < 4; ++i) {
        int gn = base + n0 + i;
        if (gn < NN) {
            float s = SCALE_DIS ? dis[gn] : 1.0f;
            float4 a = acc[i];
            ushort4 o;
            o.x = f2bf(a.x * s); o.y = f2bf(a.y * s);
            o.z = f2bf(a.z * s); o.w = f2bf(a.w * s);
            *(ushort4*)&Y[(size_t)gn * 64 + c0] = o;
        }
    }
}

// ---------------------------------------------------------------- aggregation (bf16 gather, fp32 acc)
// h rows are pre-scaled by dis[src]; out = relu(dis[dst]*sum + b), stored
// bf16, optionally re-scaled by dis[dst] (to feed the next layer's gemm).
template <bool SCALE_OUT>
__global__ __launch_bounds__(256) void agg_kernel(const unsigned short* __restrict__ h,
                                                  const int2* __restrict__ row_range,
                                                  const int* __restrict__ csr_src,
                                                  const float* __restrict__ dis,
                                                  const float* __restrict__ bias,
                                                  unsigned short* __restrict__ out) {
    const int gt = blockIdx.x * 256 + threadIdx.x;
    const int node = gt >> 6;
    const int lane = threadIdx.x & 63;
    const int sub = lane >> 4;
    const int q4 = (lane & 15) * 4;
    const int2 rr = row_range[node];
    float4 acc = {0.f, 0.f, 0.f, 0.f};
    for (int i = rr.x + sub; i < rr.y; i += 4) {
        const int src = csr_src[i];
        const ushort4 u = *(const ushort4*)&h[(size_t)src * 64 + q4];
        acc.x += b2f(u.x);
        acc.y += b2f(u.y);
        acc.z += b2f(u.z);
        acc.w += b2f(u.w);
    }
    acc.x += __shfl_xor(acc.x, 16); acc.y += __shfl_xor(acc.y, 16);
    acc.z += __shfl_xor(acc.z, 16); acc.w += __shfl_xor(acc.w, 16);
    acc.x += __shfl_xor(acc.x, 32); acc.y += __shfl_xor(acc.y, 32);
    acc.z += __shfl_xor(acc.z, 32); acc.w += __shfl_xor(acc.w, 32);
    if (sub == 0) {
        const float dn = dis[node];
        const float4 bv = *(const float4*)&bias[q4];
        const float so = SCALE_OUT ? dn : 1.0f;
        ushort4 o;
        o.x = f2bf(fmaxf(acc.x * dn + bv.x, 0.f) * so);
        o.y = f2bf(fmaxf(acc.y * dn + bv.y, 0.f) * so);
        o.z = f2bf(fmaxf(acc.z * dn + bv.z, 0.f) * so);
        o.w = f2bf(fmaxf(acc.w * dn + bv.w, 0.f) * so);
        *(ushort4*)&out[(size_t)node * 64 + q4] = o;
    }
}

// ---------------------------------------------------------------- pool (mean per graph) + MLP head
__global__ __launch_bounds__(256) void pool_head(const unsigned short* __restrict__ h,
                                                 const int* __restrict__ batch,
                                                 const float* __restrict__ Wm1,
                                                 const float* __restrict__ bm1,
                                                 const float* __restrict__ Wm2,
                                                 const float* __restrict__ bm2,
                                                 float* __restrict__ out) {
    const int g = blockIdx.x;
    const int t = threadIdx.x;
    int lo = 0, hi = NN;
    while (lo < hi) { int m = (lo + hi) >> 1; if (batch[m] < g) lo = m + 1; else hi = m; }
    const int s = lo;
    hi = NN;
    while (lo < hi) { int m = (lo + hi) >> 1; if (batch[m] < g + 1) lo = m + 1; else hi = m; }
    const int e = lo;

    const int lane = t & 63, w = t >> 6;
    float acc = 0.f;
    for (int i = s + w; i < e; i += 4)
        acc += b2f(h[(size_t)i * 64 + lane]);
    __shared__ float red[4 * 64];
    __shared__ float pl[64];
    red[w * 64 + lane] = acc;
    __syncthreads();
    if (t < 64) {
        float v = red[t] + red[64 + t] + red[128 + t] + red[192 + t];
        int cnt = e - s;
        pl[t] = v / (float)(cnt > 0 ? cnt : 1);
    }
    __syncthreads();
    if (t < 64) {
        float z = bm1[t];
#pragma unroll 8
        for (int k = 0; k < 64; ++k)
            z += pl[k] * Wm1[k * 64 + t];
        z = fmaxf(z, 0.f);
        float y = z * Wm2[t];
        for (int off = 32; off; off >>= 1) y += __shfl_down(y, off);
        if (t == 0) out[g] = y + bm2[0];
    }
}

// ---------------------------------------------------------------- launch
extern "C" void kernel_launch(void* const* d_in, const int* in_sizes, int n_in,
                              void* d_out, int out_size, void* d_ws, size_t ws_size,
                              hipStream_t stream) {
    const float* x   = (const float*)d_in[0];
    const int*   ei  = (const int*)d_in[1];
    const int*   bat = (const int*)d_in[2];
    const float* W1  = (const float*)d_in[3];
    const float* b1  = (const float*)d_in[4];
    const float* W2  = (const float*)d_in[5];
    const float* b2  = (const float*)d_in[6];
    const float* Wm1 = (const float*)d_in[7];
    const float* bm1 = (const float*)d_in[8];
    const float* Wm2 = (const float*)d_in[9];
    const float* bm2 = (const float*)d_in[10];
    float* out = (float*)d_out;

    char* w = (char*)d_ws;
    int*            cursor    = (int*)           (w + 0);          //      1024 B
    int2*           row_range = (int2*)          (w + 1024);       //   400000 B
    float*          dis       = (float*)         (w + 401024);     //   200000 B
    int*            csr_src   = (int*)           (w + 601024);     //  4014080 B
    int2*           ebuf      = (int2*)          (w + 4615104);    //  8028160 B
    unsigned short* bufA      = (unsigned short*)(w + 12643264);   //  6400000 B
    unsigned short* bufB      = (unsigned short*)(w + 19043264);   //  6400000 B (end ~25.4 MB)

    hipMemsetAsync(cursor, 0, NB * sizeof(int), stream);
    part_scatter<<<(NT + CH - 1) / CH, 256, 0, stream>>>(ei, cursor, ebuf);
    build_csr   <<<NB, 256, 0, stream>>>(ebuf, cursor, row_range, dis, csr_src);

    gemm64<NF, false, true><<<(NN + 63) / 64, 256, 0, stream>>>(x, W1, dis, bufA);
    agg_kernel<true>       <<<(NN * 64) / 256, 256, 0, stream>>>(bufA, row_range, csr_src, dis, b1, bufB);
    gemm64<NH, true, false><<<(NN + 63) / 64, 256, 0, stream>>>(bufB, W2, dis, bufA);
    agg_kernel<false>      <<<(NN * 64) / 256, 256, 0, stream>>>(bufA, row_range, csr_src, dis, b2, bufB);
    pool_head <<<NG, 256, 0, stream>>>(bufB, bat, Wm1, bm1, Wm2, bm2, out);
}

// Round 5
// 231.402 us; speedup vs baseline: 1.3728x; 1.0346x over previous
//
#include <hip/hip_runtime.h>

#define NN 50000            // nodes
#define NE 800000           // edges
#define NF 128              // input features
#define NH 64               // hidden
#define NG 256              // graphs
#define NB 196              // buckets of 256 dst nodes
#define NC 196              // chunks: ceil(NE/CH)
#define CH 4096             // edges per partition block
#define CELL 80             // per-(chunk,bucket) capacity (mean 21, 13 sigma)
#define CAP 5120            // per-bucket CSR capacity (mean 4352)

static __device__ __forceinline__ float b2f(unsigned short u) {
    return __uint_as_float((unsigned)u << 16);
}
static __device__ __forceinline__ unsigned short f2bf(float f) {
    union { float f; unsigned u; } v; v.f = f;
    unsigned r = v.u + 0x7FFF + ((v.u >> 16) & 1);   // RNE
    return (unsigned short)(r >> 16);
}

// ---------------------------------------------------------------- level-1 partition
// No global atomics: chunk c writes bucket-b edges to fixed cell (b*NC+c)*CELL
// and the count to histg[c*NB+b]. Real edges only (self-loops analytic).
__global__ __launch_bounds__(256) void part_scatter(const int* __restrict__ ei,
                                                    int* __restrict__ histg,
                                                    int2* __restrict__ ebuf) {
    const int t = threadIdx.x;
    const int c = blockIdx.x;
    const int c0 = c * CH;
    __shared__ int hist[256];
    __shared__ int incl[256];
    __shared__ int lcur[256];
    __shared__ int2 lpairs[CH];

    hist[t] = 0;
    __syncthreads();

    int2 loc[16];
#pragma unroll
    for (int j = 0; j < 16; ++j) {
        int e = c0 + j * 256 + t;
        int s = -1, d = -1;
        if (e < NE) {
            s = ei[e]; d = ei[NE + e];
            atomicAdd(&hist[d >> 8], 1);
        }
        loc[j] = make_int2(s, d);
    }
    __syncthreads();

    int v = hist[t];
    incl[t] = v;
    __syncthreads();
    for (int off = 1; off < 256; off <<= 1) {
        int u = (t >= off) ? incl[t - off] : 0;
        __syncthreads();
        incl[t] += u;
        __syncthreads();
    }
    lcur[t] = incl[t] - v;          // exclusive
    if (t < NB) histg[c * NB + t] = v;
    __syncthreads();

#pragma unroll
    for (int j = 0; j < 16; ++j) {
        int d = loc[j].y;
        if (d >= 0) {
            int p = atomicAdd(&lcur[d >> 8], 1);
            lpairs[p] = loc[j];
        }
    }
    __syncthreads();

    const int total = incl[255];
    for (int p = t; p < total; p += 256) {
        int2 pr = lpairs[p];
        int b = pr.y >> 8;
        // position within this chunk's bucket segment
        int i = p - (incl[b] - hist[b]);
        ebuf[(b * NC + c) * CELL + i] = pr;
    }
}

// ---------------------------------------------------------------- level-2: per-bucket CSR + dis
__global__ __launch_bounds__(256) void build_csr(const int2* __restrict__ ebuf,
                                                 const int* __restrict__ histg,
                                                 int2* __restrict__ row_range,
                                                 float* __restrict__ dis,
                                                 int* __restrict__ csr_src) {
    const int b = blockIdx.x, t = threadIdx.x;
    const int e0 = b * CAP;
    const int node = b * 256 + t;
    __shared__ int cnts[256];
    __shared__ int coff[256];    // inclusive scan of cnts
    __shared__ int deg_l[256];
    __shared__ int pre[256];
    __shared__ int cur[256];
    __shared__ int2 lpairs[CAP];
    __shared__ int lsrc[CAP];

    int cv = (t < NB) ? histg[t * NB + b] : 0;
    cnts[t] = cv;
    coff[t] = cv;
    __syncthreads();
    for (int off = 1; off < 256; off <<= 1) {
        int u = (t >= off) ? coff[t - off] : 0;
        __syncthreads();
        coff[t] += u;
        __syncthreads();
    }
    // gather this bucket's cells into LDS (thread t = chunk t)
    if (cv > 0) {
        const int2* src = &ebuf[(b * NC + t) * CELL];
        int dst = coff[t] - cv;
        for (int i = 0; i < cv; ++i)
            lpairs[dst + i] = src[i];
    }
    deg_l[t] = (node < NN) ? 1 : 0;   // self-loop
    __syncthreads();

    const int total = coff[255];
    for (int i = t; i < total; i += 256)
        atomicAdd(&deg_l[lpairs[i].y & 255], 1);
    __syncthreads();

    int v = deg_l[t];
    pre[t] = v;
    __syncthreads();
    for (int off = 1; off < 256; off <<= 1) {
        int u = (t >= off) ? pre[t - off] : 0;
        __syncthreads();
        pre[t] += u;
        __syncthreads();
    }
    int excl = pre[t] - v;
    cur[t] = 1;                        // slot 0 = self-loop
    if (node < NN) {
        lsrc[excl] = node;
        row_range[node] = make_int2(e0 + excl, e0 + pre[t]);
        dis[node] = rsqrtf((float)v);  // v = deg+1
    }
    __syncthreads();
    for (int i = t; i < total; i += 256) {
        int2 p = lpairs[i];
        int d = p.y & 255;
        int pos = (pre[d] - deg_l[d]) + atomicAdd(&cur[d], 1);
        lsrc[pos] = p.x;
    }
    __syncthreads();
    const int tot_all = pre[255];
    for (int i = t; i < tot_all; i += 256)
        csr_src[e0 + i] = lsrc[i];
}

// ---------------------------------------------------------------- GEMM1: Y = dis .* (X @ W1), bf16 out
template <int K>
__global__ __launch_bounds__(256) void gemm64(const float* __restrict__ X,
                                              const float* __restrict__ W,
                                              const float* __restrict__ dis,
                                              unsigned short* __restrict__ Y) {
    constexpr int XS = 68;
    __shared__ float Ws[K * 64];
    __shared__ float Xs[K * XS];
    const int t = threadIdx.x;
    const int base = blockIdx.x * 64;

    for (int i = t * 4; i < K * 64; i += 1024)
        *(float4*)&Ws[i] = *(const float4*)&W[i];
    for (int i = t * 4; i < 64 * K; i += 1024) {
        int node = i / K;
        int k = i - node * K;
        int gn = base + node;
        if (gn >= NN) gn = NN - 1;
        float4 v = *(const float4*)&X[(size_t)gn * K + k];
        Xs[(k + 0) * XS + node] = v.x;
        Xs[(k + 1) * XS + node] = v.y;
        Xs[(k + 2) * XS + node] = v.z;
        Xs[(k + 3) * XS + node] = v.w;
    }
    __syncthreads();

    const int n0 = (t & 15) * 4;
    const int c0 = (t >> 4) * 4;
    float4 acc[4] = {};
#pragma unroll 4
    for (int k = 0; k < K; ++k) {
        const float4 xv = *(const float4*)&Xs[k * XS + n0];
        const float4 wv = *(const float4*)&Ws[k * 64 + c0];
        acc[0].x += xv.x * wv.x; acc[0].y += xv.x * wv.y; acc[0].z += xv.x * wv.z; acc[0].w += xv.x * wv.w;
        acc[1].x += xv.y * wv.x; acc[1].y += xv.y * wv.y; acc[1].z += xv.y * wv.z; acc[1].w += xv.y * wv.w;
        acc[2].x += xv.z * wv.x; acc[2].y += xv.z * wv.y; acc[2].z += xv.z * wv.z; acc[2].w += xv.z * wv.w;
        acc[3].x += xv.w * wv.x; acc[3].y += xv.w * wv.y; acc[3].z += xv.w * wv.z; acc[3].w += xv.w * wv.w;
    }
#pragma unroll
    for (int i = 0; i < 4; ++i) {
        int gn = base + n0 + i;
        if (gn < NN) {
            float s = dis[gn];
            float4 a = acc[i];
            ushort4 o;
            o.x = f2bf(a.x * s); o.y = f2bf(a.y * s);
            o.z = f2bf(a.z * s); o.w = f2bf(a.w * s);
            *(ushort4*)&Y[(size_t)gn * 64 + c0] = o;
        }
    }
}

// ---------------------------------------------------------------- agg1 + gemm2 fused
// per node (one wave): acc = sum_src h[src]; h1 = relu(dis*acc + b1);
// g = (dis*h1) @ W2  (W2 staged in LDS), stored bf16.
__global__ __launch_bounds__(256) void agg_gemv(const unsigned short* __restrict__ h,
                                                const int2* __restrict__ row_range,
                                                const int* __restrict__ csr_src,
                                                const float* __restrict__ dis,
                                                const float* __restrict__ b1,
                                                const float* __restrict__ W2,
                                                unsigned short* __restrict__ g) {
    __shared__ float W2s[64 * 64];
    __shared__ float aS[4 * 64];
    const int t = threadIdx.x;
    for (int i = t * 4; i < 4096; i += 1024)
        *(float4*)&W2s[i] = *(const float4*)&W2[i];

    const int gt = blockIdx.x * 256 + t;
    const int node = gt >> 6;
    const int wave = (t >> 6);
    const int lane = t & 63;
    const int sub = lane >> 4;
    const int q4 = (lane & 15) * 4;
    const int2 rr = row_range[node];
    __syncthreads();

    float4 acc = {0.f, 0.f, 0.f, 0.f};
    for (int i = rr.x + sub; i < rr.y; i += 4) {
        const int src = csr_src[i];
        const ushort4 u = *(const ushort4*)&h[(size_t)src * 64 + q4];
        acc.x += b2f(u.x);
        acc.y += b2f(u.y);
        acc.z += b2f(u.z);
        acc.w += b2f(u.w);
    }
    acc.x += __shfl_xor(acc.x, 16); acc.y += __shfl_xor(acc.y, 16);
    acc.z += __shfl_xor(acc.z, 16); acc.w += __shfl_xor(acc.w, 16);
    acc.x += __shfl_xor(acc.x, 32); acc.y += __shfl_xor(acc.y, 32);
    acc.z += __shfl_xor(acc.z, 32); acc.w += __shfl_xor(acc.w, 32);
    if (sub == 0) {
        const float dn = dis[node];
        const float4 bv = *(const float4*)&b1[q4];
        float4 r;
        r.x = fmaxf(acc.x * dn + bv.x, 0.f) * dn;
        r.y = fmaxf(acc.y * dn + bv.y, 0.f) * dn;
        r.z = fmaxf(acc.z * dn + bv.z, 0.f) * dn;
        r.w = fmaxf(acc.w * dn + bv.w, 0.f) * dn;
        *(float4*)&aS[wave * 64 + q4] = r;
    }
    __syncthreads();

    // GEMV: lane c computes g[node][c] = sum_k a[k] * W2[k][c]
    float z = 0.f;
#pragma unroll
    for (int k4 = 0; k4 < 64; k4 += 4) {
        const float4 av = *(const float4*)&aS[wave * 64 + k4];
        z += av.x * W2s[(k4 + 0) * 64 + lane];
        z += av.y * W2s[(k4 + 1) * 64 + lane];
        z += av.z * W2s[(k4 + 2) * 64 + lane];
        z += av.w * W2s[(k4 + 3) * 64 + lane];
    }
    g[(size_t)node * 64 + lane] = f2bf(z);
}

// ---------------------------------------------------------------- agg2 (bf16 gather, fp32 acc)
__global__ __launch_bounds__(256) void agg_kernel(const unsigned short* __restrict__ h,
                                                  const int2* __restrict__ row_range,
                                                  const int* __restrict__ csr_src,
                                                  const float* __restrict__ dis,
                                                  const float* __restrict__ bias,
                                                  unsigned short* __restrict__ out) {
    const int gt = blockIdx.x * 256 + threadIdx.x;
    const int node = gt >> 6;
    const int lane = threadIdx.x & 63;
    const int sub = lane >> 4;
    const int q4 = (lane & 15) * 4;
    const int2 rr = row_range[node];
    float4 acc = {0.f, 0.f, 0.f, 0.f};
    for (int i = rr.x + sub; i < rr.y; i += 4) {
        const int src = csr_src[i];
        const ushort4 u = *(const ushort4*)&h[(size_t)src * 64 + q4];
        acc.x += b2f(u.x);
        acc.y += b2f(u.y);
        acc.z += b2f(u.z);
        acc.w += b2f(u.w);
    }
    acc.x += __shfl_xor(acc.x, 16); acc.y += __shfl_xor(acc.y, 16);
    acc.z += __shfl_xor(acc.z, 16); acc.w += __shfl_xor(acc.w, 16);
    acc.x += __shfl_xor(acc.x, 32); acc.y += __shfl_xor(acc.y, 32);
    acc.z += __shfl_xor(acc.z, 32); acc.w += __shfl_xor(acc.w, 32);
    if (sub == 0) {
        const float dn = dis[node];
        const float4 bv = *(const float4*)&bias[q4];
        ushort4 o;
        o.x = f2bf(fmaxf(acc.x * dn + bv.x, 0.f));
        o.y = f2bf(fmaxf(acc.y * dn + bv.y, 0.f));
        o.z = f2bf(fmaxf(acc.z * dn + bv.z, 0.f));
        o.w = f2bf(fmaxf(acc.w * dn + bv.w, 0.f));
        *(ushort4*)&out[(size_t)node * 64 + q4] = o;
    }
}

// ---------------------------------------------------------------- pool (mean per graph) + MLP head
__global__ __launch_bounds__(256) void pool_head(const unsigned short* __restrict__ h,
                                                 const int* __restrict__ batch,
                                                 const float* __restrict__ Wm1,
                                                 const float* __restrict__ bm1,
                                                 const float* __restrict__ Wm2,
                                                 const float* __restrict__ bm2,
                                                 float* __restrict__ out) {
    const int g = blockIdx.x;
    const int t = threadIdx.x;
    int lo = 0, hi = NN;
    while (lo < hi) { int m = (lo + hi) >> 1; if (batch[m] < g) lo = m + 1; else hi = m; }
    const int s = lo;
    hi = NN;
    while (lo < hi) { int m = (lo + hi) >> 1; if (batch[m] < g + 1) lo = m + 1; else hi = m; }
    const int e = lo;

    const int lane = t & 63, w = t >> 6;
    float acc = 0.f;
    for (int i = s + w; i < e; i += 4)
        acc += b2f(h[(size_t)i * 64 + lane]);
    __shared__ float red[4 * 64];
    __shared__ float pl[64];
    red[w * 64 + lane] = acc;
    __syncthreads();
    if (t < 64) {
        float v = red[t] + red[64 + t] + red[128 + t] + red[192 + t];
        int cnt = e - s;
        pl[t] = v / (float)(cnt > 0 ? cnt : 1);
    }
    __syncthreads();
    if (t < 64) {
        float z = bm1[t];
#pragma unroll 8
        for (int k = 0; k < 64; ++k)
            z += pl[k] * Wm1[k * 64 + t];
        z = fmaxf(z, 0.f);
        float y = z * Wm2[t];
        for (int off = 32; off; off >>= 1) y += __shfl_down(y, off);
        if (t == 0) out[g] = y + bm2[0];
    }
}

// ---------------------------------------------------------------- launch
extern "C" void kernel_launch(void* const* d_in, const int* in_sizes, int n_in,
                              void* d_out, int out_size, void* d_ws, size_t ws_size,
                              hipStream_t stream) {
    const float* x   = (const float*)d_in[0];
    const int*   ei  = (const int*)d_in[1];
    const int*   bat = (const int*)d_in[2];
    const float* W1  = (const float*)d_in[3];
    const float* b1  = (const float*)d_in[4];
    const float* W2  = (const float*)d_in[5];
    const float* b2  = (const float*)d_in[6];
    const float* Wm1 = (const float*)d_in[7];
    const float* bm1 = (const float*)d_in[8];
    const float* Wm2 = (const float*)d_in[9];
    const float* bm2 = (const float*)d_in[10];
    float* out = (float*)d_out;

    char* w = (char*)d_ws;
    int*            histg     = (int*)           (w + 0);          //   153664 B
    int2*           row_range = (int2*)          (w + 153664);     //   400000 B
    float*          dis       = (float*)         (w + 553664);     //   200000 B
    int*            csr_src   = (int*)           (w + 753664);     //  4014080 B
    int2*           ebuf      = (int2*)          (w + 4767744);    // 24586240 B
    unsigned short* bufA      = (unsigned short*)(w + 29353984);   //  6400000 B
    unsigned short* bufB      = (unsigned short*)(w + 35753984);   //  6400000 B (end ~42.2 MB)

    part_scatter<<<NC, 256, 0, stream>>>(ei, histg, ebuf);
    build_csr   <<<NB, 256, 0, stream>>>(ebuf, histg, row_range, dis, csr_src);

    gemm64<NF><<<(NN + 63) / 64, 256, 0, stream>>>(x, W1, dis, bufA);
    agg_gemv  <<<(NN * 64) / 256, 256, 0, stream>>>(bufA, row_range, csr_src, dis, b1, W2, bufB);
    agg_kernel<<<(NN * 64) / 256, 256, 0, stream>>>(bufB, row_range, csr_src, dis, b2, bufA);
    pool_head <<<NG, 256, 0, stream>>>(bufA, bat, Wm1, bm1, Wm2, bm2, out);
}

// Round 6
// 216.676 us; speedup vs baseline: 1.4661x; 1.0680x over previous
//
#include <hip/hip_runtime.h>

#define NN 50000            // nodes
#define NE 800000           // edges
#define NF 128              // input features
#define NH 64               // hidden
#define NG 256              // graphs
#define NB 196              // buckets of 256 dst nodes
#define NC 196              // chunks: ceil(NE/CH)
#define CH 4096             // edges per partition block
#define CELL 80             // per-(chunk,bucket) capacity (mean 21, 13 sigma)
#define CAP 5120            // per-bucket CSR capacity (mean 4352)

static __device__ __forceinline__ float b2f(unsigned short u) {
    return __uint_as_float((unsigned)u << 16);
}
static __device__ __forceinline__ unsigned short f2bf(float f) {
    union { float f; unsigned u; } v; v.f = f;
    unsigned r = v.u + 0x7FFF + ((v.u >> 16) & 1);   // RNE
    return (unsigned short)(r >> 16);
}
static __device__ __forceinline__ float lo16(unsigned u) {
    return __uint_as_float(u << 16);
}
static __device__ __forceinline__ float hi16(unsigned u) {
    return __uint_as_float(u & 0xFFFF0000u);
}

// ---------------------------------------------------------------- level-1 partition
__global__ __launch_bounds__(256) void part_scatter(const int* __restrict__ ei,
                                                    int* __restrict__ histg,
                                                    int2* __restrict__ ebuf) {
    const int t = threadIdx.x;
    const int c = blockIdx.x;
    const int c0 = c * CH;
    __shared__ int hist[256];
    __shared__ int incl[256];
    __shared__ int lcur[256];
    __shared__ int2 lpairs[CH];

    hist[t] = 0;
    __syncthreads();

    int2 loc[16];
#pragma unroll
    for (int j = 0; j < 16; ++j) {
        int e = c0 + j * 256 + t;
        int s = -1, d = -1;
        if (e < NE) {
            s = ei[e]; d = ei[NE + e];
            atomicAdd(&hist[d >> 8], 1);
        }
        loc[j] = make_int2(s, d);
    }
    __syncthreads();

    int v = hist[t];
    incl[t] = v;
    __syncthreads();
    for (int off = 1; off < 256; off <<= 1) {
        int u = (t >= off) ? incl[t - off] : 0;
        __syncthreads();
        incl[t] += u;
        __syncthreads();
    }
    lcur[t] = incl[t] - v;
    if (t < NB) histg[c * NB + t] = v;
    __syncthreads();

#pragma unroll
    for (int j = 0; j < 16; ++j) {
        int d = loc[j].y;
        if (d >= 0) {
            int p = atomicAdd(&lcur[d >> 8], 1);
            lpairs[p] = loc[j];
        }
    }
    __syncthreads();

    const int total = incl[255];
    for (int p = t; p < total; p += 256) {
        int2 pr = lpairs[p];
        int b = pr.y >> 8;
        int i = p - (incl[b] - hist[b]);
        ebuf[(b * NC + c) * CELL + i] = pr;
    }
}

// ---------------------------------------------------------------- level-2: per-bucket CSR + dis
__global__ __launch_bounds__(256) void build_csr(const int2* __restrict__ ebuf,
                                                 const int* __restrict__ histg,
                                                 int2* __restrict__ row_range,
                                                 float* __restrict__ dis,
                                                 int* __restrict__ csr_src) {
    const int b = blockIdx.x, t = threadIdx.x;
    const int e0 = b * CAP;
    const int node = b * 256 + t;
    __shared__ int coff[256];
    __shared__ int deg_l[256];
    __shared__ int pre[256];
    __shared__ int cur[256];
    __shared__ int2 lpairs[CAP];
    __shared__ int lsrc[CAP];

    int cv = (t < NB) ? histg[t * NB + b] : 0;
    coff[t] = cv;
    __syncthreads();
    for (int off = 1; off < 256; off <<= 1) {
        int u = (t >= off) ? coff[t - off] : 0;
        __syncthreads();
        coff[t] += u;
        __syncthreads();
    }
    if (cv > 0) {
        const int2* src = &ebuf[(b * NC + t) * CELL];
        int dst = coff[t] - cv;
        for (int i = 0; i < cv; ++i)
            lpairs[dst + i] = src[i];
    }
    deg_l[t] = (node < NN) ? 1 : 0;   // self-loop
    __syncthreads();

    const int total = coff[255];
    for (int i = t; i < total; i += 256)
        atomicAdd(&deg_l[lpairs[i].y & 255], 1);
    __syncthreads();

    int v = deg_l[t];
    pre[t] = v;
    __syncthreads();
    for (int off = 1; off < 256; off <<= 1) {
        int u = (t >= off) ? pre[t - off] : 0;
        __syncthreads();
        pre[t] += u;
        __syncthreads();
    }
    int excl = pre[t] - v;
    cur[t] = 1;                        // slot 0 = self-loop
    if (node < NN) {
        lsrc[excl] = node;
        row_range[node] = make_int2(e0 + excl, e0 + pre[t]);
        dis[node] = rsqrtf((float)v);  // v = deg+1
    }
    __syncthreads();
    for (int i = t; i < total; i += 256) {
        int2 p = lpairs[i];
        int d = p.y & 255;
        int pos = (pre[d] - deg_l[d]) + atomicAdd(&cur[d], 1);
        lsrc[pos] = p.x;
    }
    __syncthreads();
    const int tot_all = pre[255];
    for (int i = t; i < tot_all; i += 256)
        csr_src[e0 + i] = lsrc[i];
}

// ---------------------------------------------------------------- GEMM1: Y = dis .* (X @ W1), bf16 out
template <int K>
__global__ __launch_bounds__(256) void gemm64(const float* __restrict__ X,
                                              const float* __restrict__ W,
                                              const float* __restrict__ dis,
                                              unsigned short* __restrict__ Y) {
    constexpr int XS = 68;
    __shared__ float Ws[K * 64];
    __shared__ float Xs[K * XS];
    const int t = threadIdx.x;
    const int base = blockIdx.x * 64;

    for (int i = t * 4; i < K * 64; i += 1024)
        *(float4*)&Ws[i] = *(const float4*)&W[i];
    for (int i = t * 4; i < 64 * K; i += 1024) {
        int node = i / K;
        int k = i - node * K;
        int gn = base + node;
        if (gn >= NN) gn = NN - 1;
        float4 v = *(const float4*)&X[(size_t)gn * K + k];
        Xs[(k + 0) * XS + node] = v.x;
        Xs[(k + 1) * XS + node] = v.y;
        Xs[(k + 2) * XS + node] = v.z;
        Xs[(k + 3) * XS + node] = v.w;
    }
    __syncthreads();

    const int n0 = (t & 15) * 4;
    const int c0 = (t >> 4) * 4;
    float4 acc[4] = {};
#pragma unroll 4
    for (int k = 0; k < K; ++k) {
        const float4 xv = *(const float4*)&Xs[k * XS + n0];
        const float4 wv = *(const float4*)&Ws[k * 64 + c0];
        acc[0].x += xv.x * wv.x; acc[0].y += xv.x * wv.y; acc[0].z += xv.x * wv.z; acc[0].w += xv.x * wv.w;
        acc[1].x += xv.y * wv.x; acc[1].y += xv.y * wv.y; acc[1].z += xv.y * wv.z; acc[1].w += xv.y * wv.w;
        acc[2].x += xv.z * wv.x; acc[2].y += xv.z * wv.y; acc[2].z += xv.z * wv.z; acc[2].w += xv.z * wv.w;
        acc[3].x += xv.w * wv.x; acc[3].y += xv.w * wv.y; acc[3].z += xv.w * wv.z; acc[3].w += xv.w * wv.w;
    }
#pragma unroll
    for (int i = 0; i < 4; ++i) {
        int gn = base + n0 + i;
        if (gn < NN) {
            float s = dis[gn];
            float4 a = acc[i];
            ushort4 o;
            o.x = f2bf(a.x * s); o.y = f2bf(a.y * s);
            o.z = f2bf(a.z * s); o.w = f2bf(a.w * s);
            *(ushort4*)&Y[(size_t)gn * 64 + c0] = o;
        }
    }
}

// ---------------------------------------------------------------- edge accumulate helper: 16B of a row (8 bf16 dims)
#define ACC8(u)                                   \
    do {                                          \
        acc[0] += lo16((u).x); acc[1] += hi16((u).x); \
        acc[2] += lo16((u).y); acc[3] += hi16((u).y); \
        acc[4] += lo16((u).z); acc[5] += hi16((u).z); \
        acc[6] += lo16((u).w); acc[7] += hi16((u).w); \
    } while (0)

// ---------------------------------------------------------------- agg1 + gemm2 fused
// one wave per node, 8 sub-groups x 8 lanes x 16B: 8 edges in flight, 2x unrolled.
__global__ __launch_bounds__(256) void agg_gemv(const unsigned short* __restrict__ h,
                                                const int2* __restrict__ row_range,
                                                const int* __restrict__ csr_src,
                                                const float* __restrict__ dis,
                                                const float* __restrict__ b1,
                                                const float* __restrict__ W2,
                                                unsigned short* __restrict__ g) {
    __shared__ float W2s[64 * 64];
    __shared__ float aS[4 * 64];
    const int t = threadIdx.x;
    for (int i = t * 4; i < 4096; i += 1024)
        *(float4*)&W2s[i] = *(const float4*)&W2[i];

    const int node = (blockIdx.x * 256 + t) >> 6;
    const int wave = t >> 6;
    const int lane = t & 63;
    const int sub = lane >> 3;            // 8 edges in flight
    const int q8 = (lane & 7) * 8;        // 8 dims of 64
    const int2 rr = row_range[node];
    __syncthreads();

    float acc[8] = {};
    int i = rr.x + sub;
    const int n = rr.y;
    for (; i + 8 < n; i += 16) {          // two independent gathers in flight
        const int s0 = csr_src[i];
        const int s1 = csr_src[i + 8];
        const uint4 u0 = *(const uint4*)&h[(size_t)s0 * 64 + q8];
        const uint4 u1 = *(const uint4*)&h[(size_t)s1 * 64 + q8];
        ACC8(u0);
        ACC8(u1);
    }
    if (i < n) {
        const int s0 = csr_src[i];
        const uint4 u0 = *(const uint4*)&h[(size_t)s0 * 64 + q8];
        ACC8(u0);
    }
#pragma unroll
    for (int j = 0; j < 8; ++j) {
        acc[j] += __shfl_xor(acc[j], 8);
        acc[j] += __shfl_xor(acc[j], 16);
        acc[j] += __shfl_xor(acc[j], 32);
    }
    if (sub == 0) {                       // lanes 0..7 hold dims q8..q8+7
        const float dn = dis[node];
        const float4 bv0 = *(const float4*)&b1[q8];
        const float4 bv1 = *(const float4*)&b1[q8 + 4];
        float4 r0, r1;
        r0.x = fmaxf(acc[0] * dn + bv0.x, 0.f) * dn;
        r0.y = fmaxf(acc[1] * dn + bv0.y, 0.f) * dn;
        r0.z = fmaxf(acc[2] * dn + bv0.z, 0.f) * dn;
        r0.w = fmaxf(acc[3] * dn + bv0.w, 0.f) * dn;
        r1.x = fmaxf(acc[4] * dn + bv1.x, 0.f) * dn;
        r1.y = fmaxf(acc[5] * dn + bv1.y, 0.f) * dn;
        r1.z = fmaxf(acc[6] * dn + bv1.z, 0.f) * dn;
        r1.w = fmaxf(acc[7] * dn + bv1.w, 0.f) * dn;
        *(float4*)&aS[wave * 64 + q8] = r0;
        *(float4*)&aS[wave * 64 + q8 + 4] = r1;
    }
    __syncthreads();

    // GEMV: lane c computes g[node][c] = sum_k a[k] * W2[k][c]
    float z = 0.f;
#pragma unroll
    for (int k4 = 0; k4 < 64; k4 += 4) {
        const float4 av = *(const float4*)&aS[wave * 64 + k4];
        z += av.x * W2s[(k4 + 0) * 64 + lane];
        z += av.y * W2s[(k4 + 1) * 64 + lane];
        z += av.z * W2s[(k4 + 2) * 64 + lane];
        z += av.w * W2s[(k4 + 3) * 64 + lane];
    }
    g[(size_t)node * 64 + lane] = f2bf(z);
}

// ---------------------------------------------------------------- agg2 (bf16 gather, fp32 acc)
__global__ __launch_bounds__(256) void agg_kernel(const unsigned short* __restrict__ h,
                                                  const int2* __restrict__ row_range,
                                                  const int* __restrict__ csr_src,
                                                  const float* __restrict__ dis,
                                                  const float* __restrict__ bias,
                                                  unsigned short* __restrict__ out) {
    const int node = (blockIdx.x * 256 + threadIdx.x) >> 6;
    const int lane = threadIdx.x & 63;
    const int sub = lane >> 3;
    const int q8 = (lane & 7) * 8;
    const int2 rr = row_range[node];
    float acc[8] = {};
    int i = rr.x + sub;
    const int n = rr.y;
    for (; i + 8 < n; i += 16) {
        const int s0 = csr_src[i];
        const int s1 = csr_src[i + 8];
        const uint4 u0 = *(const uint4*)&h[(size_t)s0 * 64 + q8];
        const uint4 u1 = *(const uint4*)&h[(size_t)s1 * 64 + q8];
        ACC8(u0);
        ACC8(u1);
    }
    if (i < n) {
        const int s0 = csr_src[i];
        const uint4 u0 = *(const uint4*)&h[(size_t)s0 * 64 + q8];
        ACC8(u0);
    }
#pragma unroll
    for (int j = 0; j < 8; ++j) {
        acc[j] += __shfl_xor(acc[j], 8);
        acc[j] += __shfl_xor(acc[j], 16);
        acc[j] += __shfl_xor(acc[j], 32);
    }
    if (sub == 0) {
        const float dn = dis[node];
        const float4 bv0 = *(const float4*)&bias[q8];
        const float4 bv1 = *(const float4*)&bias[q8 + 4];
        uint4 o;
        o.x = (unsigned)f2bf(fmaxf(acc[0] * dn + bv0.x, 0.f)) |
              ((unsigned)f2bf(fmaxf(acc[1] * dn + bv0.y, 0.f)) << 16);
        o.y = (unsigned)f2bf(fmaxf(acc[2] * dn + bv0.z, 0.f)) |
              ((unsigned)f2bf(fmaxf(acc[3] * dn + bv0.w, 0.f)) << 16);
        o.z = (unsigned)f2bf(fmaxf(acc[4] * dn + bv1.x, 0.f)) |
              ((unsigned)f2bf(fmaxf(acc[5] * dn + bv1.y, 0.f)) << 16);
        o.w = (unsigned)f2bf(fmaxf(acc[6] * dn + bv1.z, 0.f)) |
              ((unsigned)f2bf(fmaxf(acc[7] * dn + bv1.w, 0.f)) << 16);
        *(uint4*)&out[(size_t)node * 64 + q8] = o;
    }
}

// ---------------------------------------------------------------- pool (mean per graph) + MLP head
__global__ __launch_bounds__(256) void pool_head(const unsigned short* __restrict__ h,
                                                 const int* __restrict__ batch,
                                                 const float* __restrict__ Wm1,
                                                 const float* __restrict__ bm1,
                                                 const float* __restrict__ Wm2,
                                                 const float* __restrict__ bm2,
                                                 float* __restrict__ out) {
    const int g = blockIdx.x;
    const int t = threadIdx.x;
    int lo = 0, hi = NN;
    while (lo < hi) { int m = (lo + hi) >> 1; if (batch[m] < g) lo = m + 1; else hi = m; }
    const int s = lo;
    hi = NN;
    while (lo < hi) { int m = (lo + hi) >> 1; if (batch[m] < g + 1) lo = m + 1; else hi = m; }
    const int e = lo;

    const int lane = t & 63, w = t >> 6;
    float acc = 0.f;
    for (int i = s + w; i < e; i += 4)
        acc += b2f(h[(size_t)i * 64 + lane]);
    __shared__ float red[4 * 64];
    __shared__ float pl[64];
    red[w * 64 + lane] = acc;
    __syncthreads();
    if (t < 64) {
        float v = red[t] + red[64 + t] + red[128 + t] + red[192 + t];
        int cnt = e - s;
        pl[t] = v / (float)(cnt > 0 ? cnt : 1);
    }
    __syncthreads();
    if (t < 64) {
        float z = bm1[t];
#pragma unroll 8
        for (int k = 0; k < 64; ++k)
            z += pl[k] * Wm1[k * 64 + t];
        z = fmaxf(z, 0.f);
        float y = z * Wm2[t];
        for (int off = 32; off; off >>= 1) y += __shfl_down(y, off);
        if (t == 0) out[g] = y + bm2[0];
    }
}

// ---------------------------------------------------------------- launch
extern "C" void kernel_launch(void* const* d_in, const int* in_sizes, int n_in,
                              void* d_out, int out_size, void* d_ws, size_t ws_size,
                              hipStream_t stream) {
    const float* x   = (const float*)d_in[0];
    const int*   ei  = (const int*)d_in[1];
    const int*   bat = (const int*)d_in[2];
    const float* W1  = (const float*)d_in[3];
    const float* b1  = (const float*)d_in[4];
    const float* W2  = (const float*)d_in[5];
    const float* b2  = (const float*)d_in[6];
    const float* Wm1 = (const float*)d_in[7];
    const float* bm1 = (const float*)d_in[8];
    const float* Wm2 = (const float*)d_in[9];
    const float* bm2 = (const float*)d_in[10];
    float* out = (float*)d_out;

    char* w = (char*)d_ws;
    int*            histg     = (int*)           (w + 0);          //   153664 B
    int2*           row_range = (int2*)          (w + 153664);     //   400000 B
    float*          dis       = (float*)         (w + 553664);     //   200000 B
    int*            csr_src   = (int*)           (w + 753664);     //  4014080 B
    int2*           ebuf      = (int2*)          (w + 4767744);    // 24586240 B
    unsigned short* bufA      = (unsigned short*)(w + 29353984);   //  6400000 B
    unsigned short* bufB      = (unsigned short*)(w + 35753984);   //  6400000 B (end ~42.2 MB)

    part_scatter<<<NC, 256, 0, stream>>>(ei, histg, ebuf);
    build_csr   <<<NB, 256, 0, stream>>>(ebuf, histg, row_range, dis, csr_src);

    gemm64<NF><<<(NN + 63) / 64, 256, 0, stream>>>(x, W1, dis, bufA);
    agg_gemv  <<<(NN * 64) / 256, 256, 0, stream>>>(bufA, row_range, csr_src, dis, b1, W2, bufB);
    agg_kernel<<<(NN * 64) / 256, 256, 0, stream>>>(bufB, row_range, csr_src, dis, b2, bufA);
    pool_head <<<NG, 256, 0, stream>>>(bufA, bat, Wm1, bm1, Wm2, bm2, out);
}

// Round 8
// 215.471 us; speedup vs baseline: 1.4743x; 1.0056x over previous
//
#include <hip/hip_runtime.h>

#define NN 50000            // nodes
#define NE 800000           // edges
#define NF 128              // input features
#define NH 64               // hidden
#define NG 256              // graphs
#define NB 196              // buckets of 256 dst nodes
#define NC 196              // chunks: ceil(NE/CH)
#define CH 4096             // edges per partition block
#define CELL 80             // per-(chunk,bucket) capacity
#define CAP 5120            // per-bucket CSR capacity

static __device__ __forceinline__ float b2f(unsigned short u) {
    return __uint_as_float((unsigned)u << 16);
}
static __device__ __forceinline__ unsigned short f2bf(float f) {
    union { float f; unsigned u; } v; v.f = f;
    unsigned r = v.u + 0x7FFF + ((v.u >> 16) & 1);   // RNE
    return (unsigned short)(r >> 16);
}
static __device__ __forceinline__ float lo16(unsigned u) {
    return __uint_as_float(u << 16);
}
static __device__ __forceinline__ float hi16(unsigned u) {
    return __uint_as_float(u & 0xFFFF0000u);
}

// ---------------------------------------------------------------- level-1 partition
__global__ __launch_bounds__(256) void part_scatter(const int* __restrict__ ei,
                                                    int* __restrict__ histg,
                                                    int2* __restrict__ ebuf) {
    const int t = threadIdx.x;
    const int c = blockIdx.x;
    const int c0 = c * CH;
    __shared__ int hist[256];
    __shared__ int incl[256];
    __shared__ int lcur[256];
    __shared__ int2 lpairs[CH];

    hist[t] = 0;
    __syncthreads();

    int2 loc[16];
#pragma unroll
    for (int j = 0; j < 16; ++j) {
        int e = c0 + j * 256 + t;
        int s = -1, d = -1;
        if (e < NE) {
            s = ei[e]; d = ei[NE + e];
            atomicAdd(&hist[d >> 8], 1);
        }
        loc[j] = make_int2(s, d);
    }
    __syncthreads();

    int v = hist[t];
    incl[t] = v;
    __syncthreads();
    for (int off = 1; off < 256; off <<= 1) {
        int u = (t >= off) ? incl[t - off] : 0;
        __syncthreads();
        incl[t] += u;
        __syncthreads();
    }
    lcur[t] = incl[t] - v;
    if (t < NB) histg[c * NB + t] = v;
    __syncthreads();

#pragma unroll
    for (int j = 0; j < 16; ++j) {
        int d = loc[j].y;
        if (d >= 0) {
            int p = atomicAdd(&lcur[d >> 8], 1);
            lpairs[p] = loc[j];
        }
    }
    __syncthreads();

    const int total = incl[255];
    for (int p = t; p < total; p += 256) {
        int2 pr = lpairs[p];
        int b = pr.y >> 8;
        int i = p - (incl[b] - hist[b]);
        ebuf[(b * NC + c) * CELL + i] = pr;
    }
}

// ---------------------------------------------------------------- level-2: per-bucket CSR + dis
__global__ __launch_bounds__(256) void build_csr(const int2* __restrict__ ebuf,
                                                 const int* __restrict__ histg,
                                                 int2* __restrict__ row_range,
                                                 float* __restrict__ dis,
                                                 int* __restrict__ csr_src) {
    const int b = blockIdx.x, t = threadIdx.x;
    const int e0 = b * CAP;
    const int node = b * 256 + t;
    __shared__ int coff[256];
    __shared__ int deg_l[256];
    __shared__ int pre[256];
    __shared__ int cur[256];
    __shared__ int2 lpairs[CAP];
    __shared__ int lsrc[CAP];

    int cv = (t < NB) ? histg[t * NB + b] : 0;
    coff[t] = cv;
    __syncthreads();
    for (int off = 1; off < 256; off <<= 1) {
        int u = (t >= off) ? coff[t - off] : 0;
        __syncthreads();
        coff[t] += u;
        __syncthreads();
    }
    if (cv > 0) {
        const int2* src = &ebuf[(b * NC + t) * CELL];
        int dst = coff[t] - cv;
        for (int i = 0; i < cv; ++i)
            lpairs[dst + i] = src[i];
    }
    deg_l[t] = (node < NN) ? 1 : 0;   // self-loop
    __syncthreads();

    const int total = coff[255];
    for (int i = t; i < total; i += 256)
        atomicAdd(&deg_l[lpairs[i].y & 255], 1);
    __syncthreads();

    int v = deg_l[t];
    pre[t] = v;
    __syncthreads();
    for (int off = 1; off < 256; off <<= 1) {
        int u = (t >= off) ? pre[t - off] : 0;
        __syncthreads();
        pre[t] += u;
        __syncthreads();
    }
    int excl = pre[t] - v;
    cur[t] = 1;                        // slot 0 = self-loop
    if (node < NN) {
        lsrc[excl] = node;
        row_range[node] = make_int2(e0 + excl, e0 + pre[t]);
        dis[node] = rsqrtf((float)v);  // v = deg+1
    }
    __syncthreads();
    for (int i = t; i < total; i += 256) {
        int2 p = lpairs[i];
        int d = p.y & 255;
        int pos = (pre[d] - deg_l[d]) + atomicAdd(&cur[d], 1);
        lsrc[pos] = p.x;
    }
    __syncthreads();
    const int tot_all = pre[255];
    for (int i = t; i < tot_all; i += 256)
        csr_src[e0 + i] = lsrc[i];
}

// ---------------------------------------------------------------- GEMM1: Y = dis .* (X @ W1), bf16 out
template <int K>
__global__ __launch_bounds__(256) void gemm64(const float* __restrict__ X,
                                              const float* __restrict__ W,
                                              const float* __restrict__ dis,
                                              unsigned short* __restrict__ Y) {
    constexpr int XS = 68;
    __shared__ float Ws[K * 64];
    __shared__ float Xs[K * XS];
    const int t = threadIdx.x;
    const int base = blockIdx.x * 64;

    for (int i = t * 4; i < K * 64; i += 1024)
        *(float4*)&Ws[i] = *(const float4*)&W[i];
    for (int i = t * 4; i < 64 * K; i += 1024) {
        int node = i / K;
        int k = i - node * K;
        int gn = base + node;
        if (gn >= NN) gn = NN - 1;
        float4 v = *(const float4*)&X[(size_t)gn * K + k];
        Xs[(k + 0) * XS + node] = v.x;
        Xs[(k + 1) * XS + node] = v.y;
        Xs[(k + 2) * XS + node] = v.z;
        Xs[(k + 3) * XS + node] = v.w;
    }
    __syncthreads();

    const int n0 = (t & 15) * 4;
    const int c0 = (t >> 4) * 4;
    float4 acc[4] = {};
#pragma unroll 4
    for (int k = 0; k < K; ++k) {
        const float4 xv = *(const float4*)&Xs[k * XS + n0];
        const float4 wv = *(const float4*)&Ws[k * 64 + c0];
        acc[0].x += xv.x * wv.x; acc[0].y += xv.x * wv.y; acc[0].z += xv.x * wv.z; acc[0].w += xv.x * wv.w;
        acc[1].x += xv.y * wv.x; acc[1].y += xv.y * wv.y; acc[1].z += xv.y * wv.z; acc[1].w += xv.y * wv.w;
        acc[2].x += xv.z * wv.x; acc[2].y += xv.z * wv.y; acc[2].z += xv.z * wv.z; acc[2].w += xv.z * wv.w;
        acc[3].x += xv.w * wv.x; acc[3].y += xv.w * wv.y; acc[3].z += xv.w * wv.z; acc[3].w += xv.w * wv.w;
    }
#pragma unroll
    for (int i = 0; i < 4; ++i) {
        int gn = base + n0 + i;
        if (gn < NN) {
            float s = dis[gn];
            float4 a = acc[i];
            ushort4 o;
            o.x = f2bf(a.x * s); o.y = f2bf(a.y * s);
            o.z = f2bf(a.z * s); o.w = f2bf(a.w * s);
            *(ushort4*)&Y[(size_t)gn * 64 + c0] = o;
        }
    }
}

// ---------------------------------------------------------------- edge accumulate: 16B of a row (8 bf16 dims)
#define ACC8(u)                                       \
    do {                                              \
        acc[0] += lo16((u).x); acc[1] += hi16((u).x); \
        acc[2] += lo16((u).y); acc[3] += hi16((u).y); \
        acc[4] += lo16((u).z); acc[5] += hi16((u).z); \
        acc[6] += lo16((u).w); acc[7] += hi16((u).w); \
    } while (0)

// Gather loop: one coalesced index load per 64 edges, shfl-broadcast with
// WAVE-UNIFORM trip counts (ds_bpermute from an inactive lane is undefined —
// the R7 bug). Full batches need no predication; the tail clamps shfl
// sources to cd-1 (all lanes active) and predicates only the accumulates.
#define GATHER_EDGES(hptr)                                                    \
    for (int base_ = rr.x; base_ < rr.y; base_ += 64) {                       \
        const int cd = min(64, rr.y - base_);                                 \
        int myidx = 0;                                                        \
        if (lane < cd) myidx = csr_src[base_ + lane];                         \
        int jj = 0;                                                           \
        for (; jj + 32 <= cd; jj += 32) {                                     \
            const int i0 = __shfl(myidx, jj + sub);                           \
            const int i1 = __shfl(myidx, jj + sub + 8);                       \
            const int i2 = __shfl(myidx, jj + sub + 16);                      \
            const int i3 = __shfl(myidx, jj + sub + 24);                      \
            const uint4 u0 = *(const uint4*)&(hptr)[(i0 << 6) + q8];          \
            const uint4 u1 = *(const uint4*)&(hptr)[(i1 << 6) + q8];          \
            const uint4 u2 = *(const uint4*)&(hptr)[(i2 << 6) + q8];          \
            const uint4 u3 = *(const uint4*)&(hptr)[(i3 << 6) + q8];          \
            ACC8(u0); ACC8(u1); ACC8(u2); ACC8(u3);                           \
        }                                                                     \
        if (jj < cd) {                  /* wave-uniform entry */              \
            const int cl = cd - 1;                                            \
            const int e0 = jj + sub;                                          \
            const int e1 = e0 + 8, e2 = e0 + 16, e3 = e0 + 24;                \
            const int i0 = __shfl(myidx, min(e0, cl));                        \
            const int i1 = __shfl(myidx, min(e1, cl));                        \
            const int i2 = __shfl(myidx, min(e2, cl));                        \
            const int i3 = __shfl(myidx, min(e3, cl));                        \
            const uint4 u0 = *(const uint4*)&(hptr)[(i0 << 6) + q8];          \
            const uint4 u1 = *(const uint4*)&(hptr)[(i1 << 6) + q8];          \
            const uint4 u2 = *(const uint4*)&(hptr)[(i2 << 6) + q8];          \
            const uint4 u3 = *(const uint4*)&(hptr)[(i3 << 6) + q8];          \
            if (e0 < cd) ACC8(u0);                                            \
            if (e1 < cd) ACC8(u1);                                            \
            if (e2 < cd) ACC8(u2);                                            \
            if (e3 < cd) ACC8(u3);                                            \
        }                                                                     \
    }

#define REDUCE8()                                     \
    _Pragma("unroll")                                 \
    for (int j_ = 0; j_ < 8; ++j_) {                  \
        acc[j_] += __shfl_xor(acc[j_], 8);            \
        acc[j_] += __shfl_xor(acc[j_], 16);           \
        acc[j_] += __shfl_xor(acc[j_], 32);           \
    }

// ---------------------------------------------------------------- agg1 + gemm2 fused
__global__ __launch_bounds__(256) void agg_gemv(const unsigned short* __restrict__ h,
                                                const int2* __restrict__ row_range,
                                                const int* __restrict__ csr_src,
                                                const float* __restrict__ dis,
                                                const float* __restrict__ b1,
                                                const float* __restrict__ W2,
                                                unsigned short* __restrict__ g) {
    __shared__ float W2s[64 * 64];
    __shared__ float aS[4 * 64];
    const int t = threadIdx.x;
    for (int i = t * 4; i < 4096; i += 1024)
        *(float4*)&W2s[i] = *(const float4*)&W2[i];

    const int node = (blockIdx.x * 256 + t) >> 6;
    const int wave = t >> 6;
    const int lane = t & 63;
    const int sub = lane >> 3;
    const int q8 = (lane & 7) * 8;
    const int2 rr = row_range[node];
    __syncthreads();

    float acc[8] = {};
    GATHER_EDGES(h);
    REDUCE8();
    if (sub == 0) {
        const float dn = dis[node];
        const float4 bv0 = *(const float4*)&b1[q8];
        const float4 bv1 = *(const float4*)&b1[q8 + 4];
        float4 r0, r1;
        r0.x = fmaxf(acc[0] * dn + bv0.x, 0.f) * dn;
        r0.y = fmaxf(acc[1] * dn + bv0.y, 0.f) * dn;
        r0.z = fmaxf(acc[2] * dn + bv0.z, 0.f) * dn;
        r0.w = fmaxf(acc[3] * dn + bv0.w, 0.f) * dn;
        r1.x = fmaxf(acc[4] * dn + bv1.x, 0.f) * dn;
        r1.y = fmaxf(acc[5] * dn + bv1.y, 0.f) * dn;
        r1.z = fmaxf(acc[6] * dn + bv1.z, 0.f) * dn;
        r1.w = fmaxf(acc[7] * dn + bv1.w, 0.f) * dn;
        *(float4*)&aS[wave * 64 + q8] = r0;
        *(float4*)&aS[wave * 64 + q8 + 4] = r1;
    }
    __syncthreads();

    float z = 0.f;
#pragma unroll
    for (int k4 = 0; k4 < 64; k4 += 4) {
        const float4 av = *(const float4*)&aS[wave * 64 + k4];
        z += av.x * W2s[(k4 + 0) * 64 + lane];
        z += av.y * W2s[(k4 + 1) * 64 + lane];
        z += av.z * W2s[(k4 + 2) * 64 + lane];
        z += av.w * W2s[(k4 + 3) * 64 + lane];
    }
    g[(size_t)node * 64 + lane] = f2bf(z);
}

// ---------------------------------------------------------------- agg2
__global__ __launch_bounds__(256) void agg_kernel(const unsigned short* __restrict__ h,
                                                  const int2* __restrict__ row_range,
                                                  const int* __restrict__ csr_src,
                                                  const float* __restrict__ dis,
                                                  const float* __restrict__ bias,
                                                  unsigned short* __restrict__ out) {
    const int node = (blockIdx.x * 256 + threadIdx.x) >> 6;
    const int lane = threadIdx.x & 63;
    const int sub = lane >> 3;
    const int q8 = (lane & 7) * 8;
    const int2 rr = row_range[node];
    float acc[8] = {};
    GATHER_EDGES(h);
    REDUCE8();
    if (sub == 0) {
        const float dn = dis[node];
        const float4 bv0 = *(const float4*)&bias[q8];
        const float4 bv1 = *(const float4*)&bias[q8 + 4];
        uint4 o;
        o.x = (unsigned)f2bf(fmaxf(acc[0] * dn + bv0.x, 0.f)) |
              ((unsigned)f2bf(fmaxf(acc[1] * dn + bv0.y, 0.f)) << 16);
        o.y = (unsigned)f2bf(fmaxf(acc[2] * dn + bv0.z, 0.f)) |
              ((unsigned)f2bf(fmaxf(acc[3] * dn + bv0.w, 0.f)) << 16);
        o.z = (unsigned)f2bf(fmaxf(acc[4] * dn + bv1.x, 0.f)) |
              ((unsigned)f2bf(fmaxf(acc[5] * dn + bv1.y, 0.f)) << 16);
        o.w = (unsigned)f2bf(fmaxf(acc[6] * dn + bv1.z, 0.f)) |
              ((unsigned)f2bf(fmaxf(acc[7] * dn + bv1.w, 0.f)) << 16);
        *(uint4*)&out[(size_t)node * 64 + q8] = o;
    }
}

// ---------------------------------------------------------------- pool (mean per graph) + MLP head
__global__ __launch_bounds__(256) void pool_head(const unsigned short* __restrict__ h,
                                                 const int* __restrict__ batch,
                                                 const float* __restrict__ Wm1,
                                                 const float* __restrict__ bm1,
                                                 const float* __restrict__ Wm2,
                                                 const float* __restrict__ bm2,
                                                 float* __restrict__ out) {
    const int g = blockIdx.x;
    const int t = threadIdx.x;
    int lo = 0, hi = NN;
    while (lo < hi) { int m = (lo + hi) >> 1; if (batch[m] < g) lo = m + 1; else hi = m; }
    const int s = lo;
    hi = NN;
    while (lo < hi) { int m = (lo + hi) >> 1; if (batch[m] < g + 1) lo = m + 1; else hi = m; }
    const int e = lo;

    const int lane = t & 63, w = t >> 6;
    float acc = 0.f;
    for (int i = s + w; i < e; i += 4)
        acc += b2f(h[(size_t)i * 64 + lane]);
    __shared__ float red[4 * 64];
    __shared__ float pl[64];
    red[w * 64 + lane] = acc;
    __syncthreads();
    if (t < 64) {
        float v = red[t] + red[64 + t] + red[128 + t] + red[192 + t];
        int cnt = e - s;
        pl[t] = v / (float)(cnt > 0 ? cnt : 1);
    }
    __syncthreads();
    if (t < 64) {
        float z = bm1[t];
#pragma unroll 8
        for (int k = 0; k < 64; ++k)
            z += pl[k] * Wm1[k * 64 + t];
        z = fmaxf(z, 0.f);
        float y = z * Wm2[t];
        for (int off = 32; off; off >>= 1) y += __shfl_down(y, off);
        if (t == 0) out[g] = y + bm2[0];
    }
}

// ---------------------------------------------------------------- launch
extern "C" void kernel_launch(void* const* d_in, const int* in_sizes, int n_in,
                              void* d_out, int out_size, void* d_ws, size_t ws_size,
                              hipStream_t stream) {
    const float* x   = (const float*)d_in[0];
    const int*   ei  = (const int*)d_in[1];
    const int*   bat = (const int*)d_in[2];
    const float* W1  = (const float*)d_in[3];
    const float* b1  = (const float*)d_in[4];
    const float* W2  = (const float*)d_in[5];
    const float* b2  = (const float*)d_in[6];
    const float* Wm1 = (const float*)d_in[7];
    const float* bm1 = (const float*)d_in[8];
    const float* Wm2 = (const float*)d_in[9];
    const float* bm2 = (const float*)d_in[10];
    float* out = (float*)d_out;

    char* w = (char*)d_ws;
    int*            histg     = (int*)           (w + 0);          //   153664 B
    int2*           row_range = (int2*)          (w + 153664);     //   400000 B
    float*          dis       = (float*)         (w + 553664);     //   200000 B
    int*            csr_src   = (int*)           (w + 753664);     //  4014080 B
    int2*           ebuf      = (int2*)          (w + 4767744);    // 24586240 B
    unsigned short* bufA      = (unsigned short*)(w + 29353984);   //  6400000 B
    unsigned short* bufB      = (unsigned short*)(w + 35753984);   //  6400000 B (end ~42.2 MB)

    part_scatter<<<NC, 256, 0, stream>>>(ei, histg, ebuf);
    build_csr   <<<NB, 256, 0, stream>>>(ebuf, histg, row_range, dis, csr_src);

    gemm64<NF><<<(NN + 63) / 64, 256, 0, stream>>>(x, W1, dis, bufA);
    agg_gemv  <<<(NN * 64) / 256, 256, 0, stream>>>(bufA, row_range, csr_src, dis, b1, W2, bufB);
    agg_kernel<<<(NN * 64) / 256, 256, 0, stream>>>(bufB, row_range, csr_src, dis, b2, bufA);
    pool_head <<<NG, 256, 0, stream>>>(bufA, bat, Wm1, bm1, Wm2, bm2, out);
}

// Round 9
// 199.055 us; speedup vs baseline: 1.5959x; 1.0825x over previous
//
#include <hip/hip_runtime.h>

#define NN 50000            // nodes
#define NE 800000           // edges
#define NF 128              // input features
#define NH 64               // hidden
#define NG 256              // graphs
#define NB 196              // buckets of 256 dst nodes
#define NC 196              // chunks: ceil(NE/CH)
#define CH 4096             // edges per partition block
#define CELL 80             // per-(chunk,bucket) capacity
#define CAP 5120            // per-bucket CSR capacity

static __device__ __forceinline__ float b2f(unsigned short u) {
    return __uint_as_float((unsigned)u << 16);
}
static __device__ __forceinline__ unsigned short f2bf(float f) {
    union { float f; unsigned u; } v; v.f = f;
    unsigned r = v.u + 0x7FFF + ((v.u >> 16) & 1);   // RNE
    return (unsigned short)(r >> 16);
}
static __device__ __forceinline__ float lo16(unsigned u) {
    return __uint_as_float(u << 16);
}
static __device__ __forceinline__ float hi16(unsigned u) {
    return __uint_as_float(u & 0xFFFF0000u);
}

// ---------------------------------------------------------------- level-1 partition
__global__ __launch_bounds__(256) void part_scatter(const int* __restrict__ ei,
                                                    int* __restrict__ histg,
                                                    int2* __restrict__ ebuf) {
    const int t = threadIdx.x;
    const int c = blockIdx.x;
    const int c0 = c * CH;
    __shared__ int hist[256];
    __shared__ int incl[256];
    __shared__ int lcur[256];
    __shared__ int2 lpairs[CH];

    hist[t] = 0;
    __syncthreads();

    int2 loc[16];
#pragma unroll
    for (int j = 0; j < 16; ++j) {
        int e = c0 + j * 256 + t;
        int s = -1, d = -1;
        if (e < NE) {
            s = ei[e]; d = ei[NE + e];
            atomicAdd(&hist[d >> 8], 1);
        }
        loc[j] = make_int2(s, d);
    }
    __syncthreads();

    int v = hist[t];
    incl[t] = v;
    __syncthreads();
    for (int off = 1; off < 256; off <<= 1) {
        int u = (t >= off) ? incl[t - off] : 0;
        __syncthreads();
        incl[t] += u;
        __syncthreads();
    }
    lcur[t] = incl[t] - v;
    if (t < NB) histg[c * NB + t] = v;
    __syncthreads();

#pragma unroll
    for (int j = 0; j < 16; ++j) {
        int d = loc[j].y;
        if (d >= 0) {
            int p = atomicAdd(&lcur[d >> 8], 1);
            lpairs[p] = loc[j];
        }
    }
    __syncthreads();

    const int total = incl[255];
    for (int p = t; p < total; p += 256) {
        int2 pr = lpairs[p];
        int b = pr.y >> 8;
        int i = p - (incl[b] - hist[b]);
        ebuf[(b * NC + c) * CELL + i] = pr;
    }
}

// ---------------------------------------------------------------- level-2: per-bucket CSR + dis
__global__ __launch_bounds__(256) void build_csr(const int2* __restrict__ ebuf,
                                                 const int* __restrict__ histg,
                                                 int2* __restrict__ row_range,
                                                 float* __restrict__ dis,
                                                 int* __restrict__ csr_src) {
    const int b = blockIdx.x, t = threadIdx.x;
    const int e0 = b * CAP;
    const int node = b * 256 + t;
    __shared__ int coff[256];
    __shared__ int deg_l[256];
    __shared__ int pre[256];
    __shared__ int cur[256];
    __shared__ int2 lpairs[CAP];
    __shared__ int lsrc[CAP];

    int cv = (t < NB) ? histg[t * NB + b] : 0;
    coff[t] = cv;
    __syncthreads();
    for (int off = 1; off < 256; off <<= 1) {
        int u = (t >= off) ? coff[t - off] : 0;
        __syncthreads();
        coff[t] += u;
        __syncthreads();
    }
    if (cv > 0) {
        const int2* src = &ebuf[(b * NC + t) * CELL];
        int dst = coff[t] - cv;
        for (int i = 0; i < cv; ++i)
            lpairs[dst + i] = src[i];
    }
    deg_l[t] = (node < NN) ? 1 : 0;   // self-loop
    __syncthreads();

    const int total = coff[255];
    for (int i = t; i < total; i += 256)
        atomicAdd(&deg_l[lpairs[i].y & 255], 1);
    __syncthreads();

    int v = deg_l[t];
    pre[t] = v;
    __syncthreads();
    for (int off = 1; off < 256; off <<= 1) {
        int u = (t >= off) ? pre[t - off] : 0;
        __syncthreads();
        pre[t] += u;
        __syncthreads();
    }
    int excl = pre[t] - v;
    cur[t] = 1;                        // slot 0 = self-loop
    if (node < NN) {
        lsrc[excl] = node;
        row_range[node] = make_int2(e0 + excl, e0 + pre[t]);
        dis[node] = rsqrtf((float)v);  // v = deg+1
    }
    __syncthreads();
    for (int i = t; i < total; i += 256) {
        int2 p = lpairs[i];
        int d = p.y & 255;
        int pos = (pre[d] - deg_l[d]) + atomicAdd(&cur[d], 1);
        lsrc[pos] = p.x;
    }
    __syncthreads();
    const int tot_all = pre[255];
    for (int i = t; i < tot_all; i += 256)
        csr_src[e0 + i] = lsrc[i];
}

// ---------------------------------------------------------------- GEMM1: Y = dis .* (X @ W1), bf16 out
template <int K>
__global__ __launch_bounds__(256) void gemm64(const float* __restrict__ X,
                                              const float* __restrict__ W,
                                              const float* __restrict__ dis,
                                              unsigned short* __restrict__ Y) {
    constexpr int XS = 68;
    __shared__ float Ws[K * 64];
    __shared__ float Xs[K * XS];
    const int t = threadIdx.x;
    const int base = blockIdx.x * 64;

    for (int i = t * 4; i < K * 64; i += 1024)
        *(float4*)&Ws[i] = *(const float4*)&W[i];
    for (int i = t * 4; i < 64 * K; i += 1024) {
        int node = i / K;
        int k = i - node * K;
        int gn = base + node;
        if (gn >= NN) gn = NN - 1;
        float4 v = *(const float4*)&X[(size_t)gn * K + k];
        Xs[(k + 0) * XS + node] = v.x;
        Xs[(k + 1) * XS + node] = v.y;
        Xs[(k + 2) * XS + node] = v.z;
        Xs[(k + 3) * XS + node] = v.w;
    }
    __syncthreads();

    const int n0 = (t & 15) * 4;
    const int c0 = (t >> 4) * 4;
    float4 acc[4] = {};
#pragma unroll 4
    for (int k = 0; k < K; ++k) {
        const float4 xv = *(const float4*)&Xs[k * XS + n0];
        const float4 wv = *(const float4*)&Ws[k * 64 + c0];
        acc[0].x += xv.x * wv.x; acc[0].y += xv.x * wv.y; acc[0].z += xv.x * wv.z; acc[0].w += xv.x * wv.w;
        acc[1].x += xv.y * wv.x; acc[1].y += xv.y * wv.y; acc[1].z += xv.y * wv.z; acc[1].w += xv.y * wv.w;
        acc[2].x += xv.z * wv.x; acc[2].y += xv.z * wv.y; acc[2].z += xv.z * wv.z; acc[2].w += xv.z * wv.w;
        acc[3].x += xv.w * wv.x; acc[3].y += xv.w * wv.y; acc[3].z += xv.w * wv.z; acc[3].w += xv.w * wv.w;
    }
#pragma unroll
    for (int i = 0; i < 4; ++i) {
        int gn = base + n0 + i;
        if (gn < NN) {
            float s = dis[gn];
            float4 a = acc[i];
            ushort4 o;
            o.x = f2bf(a.x * s); o.y = f2bf(a.y * s);
            o.z = f2bf(a.z * s); o.w = f2bf(a.w * s);
            *(ushort4*)&Y[(size_t)gn * 64 + c0] = o;
        }
    }
}

// ---------------------------------------------------------------- sub-group aggregation core
// 8 lanes own one node: lane p holds dims p*8..p*8+7 (16 B of the 128 B row).
// Indices are sub-uniform same-address loads (no shfl anywhere); per-sub
// serial loop is exec-mask safe under divergence. 2 gathers in flight/sub
// -> 16 per wave.
static __device__ __forceinline__ void acc8(float* acc, const uint4 u) {
    acc[0] += lo16(u.x); acc[1] += hi16(u.x);
    acc[2] += lo16(u.y); acc[3] += hi16(u.y);
    acc[4] += lo16(u.z); acc[5] += hi16(u.z);
    acc[6] += lo16(u.w); acc[7] += hi16(u.w);
}

static __device__ __forceinline__ void gather_rows(const unsigned short* __restrict__ h,
                                                   const int* __restrict__ csr_src,
                                                   int lo, int hi, int p8, float* acc) {
    int i = lo;
    for (; i + 2 <= hi; i += 2) {
        const int i0 = csr_src[i];
        const int i1 = csr_src[i + 1];
        const uint4 u0 = *(const uint4*)&h[(i0 << 6) + p8];
        const uint4 u1 = *(const uint4*)&h[(i1 << 6) + p8];
        acc8(acc, u0);
        acc8(acc, u1);
    }
    if (i < hi) {
        const int i0 = csr_src[i];
        acc8(acc, *(const uint4*)&h[(i0 << 6) + p8]);
    }
}

// ---------------------------------------------------------------- agg1 + gemm2 fused
// phase 1: 32 nodes/block, sub-per-node gather -> h1 rows (fp32) into LDS
//          transposed aS[dim][node] (stride 36: phase-2 reads conflict-free;
//          the 8 scatter-writes take an accepted 8-way conflict).
// phase 2: 32x64x64 outer-product tile (4 nodes x 2 cols per thread).
__global__ __launch_bounds__(256) void agg_gemv(const unsigned short* __restrict__ h,
                                                const int2* __restrict__ row_range,
                                                const int* __restrict__ csr_src,
                                                const float* __restrict__ dis,
                                                const float* __restrict__ b1,
                                                const float* __restrict__ W2,
                                                unsigned short* __restrict__ g) {
    __shared__ float W2s[64 * 64];
    __shared__ float aS[64 * 36];
    const int t = threadIdx.x;
    for (int i = t * 4; i < 4096; i += 1024)
        *(float4*)&W2s[i] = *(const float4*)&W2[i];

    const int base = blockIdx.x * 32;
    const int nloc = t >> 3;
    const int p8 = (t & 7) * 8;
    const int n = base + nloc;
    float acc[8] = {};
    if (n < NN) {
        const int2 rr = row_range[n];
        gather_rows(h, csr_src, rr.x, rr.y, p8, acc);
        const float dn = dis[n];
        const float4 bv0 = *(const float4*)&b1[p8];
        const float4 bv1 = *(const float4*)&b1[p8 + 4];
        acc[0] = fmaxf(acc[0] * dn + bv0.x, 0.f) * dn;
        acc[1] = fmaxf(acc[1] * dn + bv0.y, 0.f) * dn;
        acc[2] = fmaxf(acc[2] * dn + bv0.z, 0.f) * dn;
        acc[3] = fmaxf(acc[3] * dn + bv0.w, 0.f) * dn;
        acc[4] = fmaxf(acc[4] * dn + bv1.x, 0.f) * dn;
        acc[5] = fmaxf(acc[5] * dn + bv1.y, 0.f) * dn;
        acc[6] = fmaxf(acc[6] * dn + bv1.z, 0.f) * dn;
        acc[7] = fmaxf(acc[7] * dn + bv1.w, 0.f) * dn;
    }
#pragma unroll
    for (int j = 0; j < 8; ++j)
        aS[(p8 + j) * 36 + nloc] = acc[j];
    __syncthreads();

    // phase 2: outer-product tile
    const int n0 = (t & 7) * 4;
    const int c0 = (t >> 3) * 2;
    float a0x = 0, a0y = 0, a1x = 0, a1y = 0;
    float a2x = 0, a2y = 0, a3x = 0, a3y = 0;
#pragma unroll 8
    for (int k = 0; k < 64; ++k) {
        const float4 xv = *(const float4*)&aS[k * 36 + n0];
        const float2 wv = *(const float2*)&W2s[k * 64 + c0];
        a0x += xv.x * wv.x; a0y += xv.x * wv.y;
        a1x += xv.y * wv.x; a1y += xv.y * wv.y;
        a2x += xv.z * wv.x; a2y += xv.z * wv.y;
        a3x += xv.w * wv.x; a3y += xv.w * wv.y;
    }
    const int gn = base + n0;
    if (gn + 0 < NN) *(unsigned*)&g[(gn + 0) * 64 + c0] = (unsigned)f2bf(a0x) | ((unsigned)f2bf(a0y) << 16);
    if (gn + 1 < NN) *(unsigned*)&g[(gn + 1) * 64 + c0] = (unsigned)f2bf(a1x) | ((unsigned)f2bf(a1y) << 16);
    if (gn + 2 < NN) *(unsigned*)&g[(gn + 2) * 64 + c0] = (unsigned)f2bf(a2x) | ((unsigned)f2bf(a2y) << 16);
    if (gn + 3 < NN) *(unsigned*)&g[(gn + 3) * 64 + c0] = (unsigned)f2bf(a3x) | ((unsigned)f2bf(a3y) << 16);
}

// ---------------------------------------------------------------- agg2 (sub-per-node, zero LDS)
__global__ __launch_bounds__(256) void agg_kernel(const unsigned short* __restrict__ h,
                                                  const int2* __restrict__ row_range,
                                                  const int* __restrict__ csr_src,
                                                  const float* __restrict__ dis,
                                                  const float* __restrict__ bias,
                                                  unsigned short* __restrict__ out) {
    const int t = threadIdx.x;
    const int n = blockIdx.x * 32 + (t >> 3);
    const int p8 = (t & 7) * 8;
    if (n >= NN) return;
    const int2 rr = row_range[n];
    float acc[8] = {};
    gather_rows(h, csr_src, rr.x, rr.y, p8, acc);
    const float dn = dis[n];
    const float4 bv0 = *(const float4*)&bias[p8];
    const float4 bv1 = *(const float4*)&bias[p8 + 4];
    uint4 o;
    o.x = (unsigned)f2bf(fmaxf(acc[0] * dn + bv0.x, 0.f)) |
          ((unsigned)f2bf(fmaxf(acc[1] * dn + bv0.y, 0.f)) << 16);
    o.y = (unsigned)f2bf(fmaxf(acc[2] * dn + bv0.z, 0.f)) |
          ((unsigned)f2bf(fmaxf(acc[3] * dn + bv0.w, 0.f)) << 16);
    o.z = (unsigned)f2bf(fmaxf(acc[4] * dn + bv1.x, 0.f)) |
          ((unsigned)f2bf(fmaxf(acc[5] * dn + bv1.y, 0.f)) << 16);
    o.w = (unsigned)f2bf(fmaxf(acc[6] * dn + bv1.z, 0.f)) |
          ((unsigned)f2bf(fmaxf(acc[7] * dn + bv1.w, 0.f)) << 16);
    *(uint4*)&out[n * 64 + p8] = o;   // consecutive lanes -> consecutive 16B: coalesced
}

// ---------------------------------------------------------------- pool (mean per graph) + MLP head
__global__ __launch_bounds__(256) void pool_head(const unsigned short* __restrict__ h,
                                                 const int* __restrict__ batch,
                                                 const float* __restrict__ Wm1,
                                                 const float* __restrict__ bm1,
                                                 const float* __restrict__ Wm2,
                                                 const float* __restrict__ bm2,
                                                 float* __restrict__ out) {
    const int g = blockIdx.x;
    const int t = threadIdx.x;
    int lo = 0, hi = NN;
    while (lo < hi) { int m = (lo + hi) >> 1; if (batch[m] < g) lo = m + 1; else hi = m; }
    const int s = lo;
    hi = NN;
    while (lo < hi) { int m = (lo + hi) >> 1; if (batch[m] < g + 1) lo = m + 1; else hi = m; }
    const int e = lo;

    const int lane = t & 63, w = t >> 6;
    float acc = 0.f;
    for (int i = s + w; i < e; i += 4)
        acc += b2f(h[(size_t)i * 64 + lane]);
    __shared__ float red[4 * 64];
    __shared__ float pl[64];
    red[w * 64 + lane] = acc;
    __syncthreads();
    if (t < 64) {
        float v = red[t] + red[64 + t] + red[128 + t] + red[192 + t];
        int cnt = e - s;
        pl[t] = v / (float)(cnt > 0 ? cnt : 1);
    }
    __syncthreads();
    if (t < 64) {
        float z = bm1[t];
#pragma unroll 8
        for (int k = 0; k < 64; ++k)
            z += pl[k] * Wm1[k * 64 + t];
        z = fmaxf(z, 0.f);
        float y = z * Wm2[t];
        for (int off = 32; off; off >>= 1) y += __shfl_down(y, off);
        if (t == 0) out[g] = y + bm2[0];
    }
}

// ---------------------------------------------------------------- launch
extern "C" void kernel_launch(void* const* d_in, const int* in_sizes, int n_in,
                              void* d_out, int out_size, void* d_ws, size_t ws_size,
                              hipStream_t stream) {
    const float* x   = (const float*)d_in[0];
    const int*   ei  = (const int*)d_in[1];
    const int*   bat = (const int*)d_in[2];
    const float* W1  = (const float*)d_in[3];
    const float* b1  = (const float*)d_in[4];
    const float* W2  = (const float*)d_in[5];
    const float* b2  = (const float*)d_in[6];
    const float* Wm1 = (const float*)d_in[7];
    const float* bm1 = (const float*)d_in[8];
    const float* Wm2 = (const float*)d_in[9];
    const float* bm2 = (const float*)d_in[10];
    float* out = (float*)d_out;

    char* w = (char*)d_ws;
    int*            histg     = (int*)           (w + 0);          //   153664 B
    int2*           row_range = (int2*)          (w + 153664);     //   400000 B
    float*          dis       = (float*)         (w + 553664);     //   200000 B
    int*            csr_src   = (int*)           (w + 753664);     //  4014080 B
    int2*           ebuf      = (int2*)          (w + 4767744);    // 24586240 B
    unsigned short* bufA      = (unsigned short*)(w + 29353984);   //  6400000 B
    unsigned short* bufB      = (unsigned short*)(w + 35753984);   //  6400000 B (end ~42.2 MB)

    part_scatter<<<NC, 256, 0, stream>>>(ei, histg, ebuf);
    build_csr   <<<NB, 256, 0, stream>>>(ebuf, histg, row_range, dis, csr_src);

    gemm64<NF><<<(NN + 63) / 64, 256, 0, stream>>>(x, W1, dis, bufA);
    agg_gemv  <<<(NN + 31) / 32, 256, 0, stream>>>(bufA, row_range, csr_src, dis, b1, W2, bufB);
    agg_kernel<<<(NN + 31) / 32, 256, 0, stream>>>(bufB, row_range, csr_src, dis, b2, bufA);
    pool_head <<<NG, 256, 0, stream>>>(bufA, bat, Wm1, bm1, Wm2, bm2, out);
}

// Round 10
// 176.664 us; speedup vs baseline: 1.7982x; 1.1267x over previous
//
#include <hip/hip_runtime.h>

#define NN 50000            // nodes
#define NE 800000           // edges
#define NF 128              // input features
#define NH 64               // hidden
#define NG 256              // graphs
#define NB 196              // buckets of 256 dst nodes
#define NC 196              // chunks: ceil(NE/CH)
#define CH 4096             // edges per partition block
#define CELL 80             // per-(chunk,bucket) capacity
#define CAP 5120            // per-bucket CSR capacity

typedef __attribute__((ext_vector_type(8))) short bf16x8;
typedef __attribute__((ext_vector_type(4))) float f32x4;

static __device__ __forceinline__ float b2f(unsigned short u) {
    return __uint_as_float((unsigned)u << 16);
}
static __device__ __forceinline__ unsigned short f2bf(float f) {
    union { float f; unsigned u; } v; v.f = f;
    unsigned r = v.u + 0x7FFF + ((v.u >> 16) & 1);   // RNE
    return (unsigned short)(r >> 16);
}
static __device__ __forceinline__ float lo16(unsigned u) {
    return __uint_as_float(u << 16);
}
static __device__ __forceinline__ float hi16(unsigned u) {
    return __uint_as_float(u & 0xFFFF0000u);
}

// ---------------------------------------------------------------- level-1 partition
__global__ __launch_bounds__(256) void part_scatter(const int* __restrict__ ei,
                                                    int* __restrict__ histg,
                                                    int2* __restrict__ ebuf) {
    const int t = threadIdx.x;
    const int c = blockIdx.x;
    const int c0 = c * CH;
    __shared__ int hist[256];
    __shared__ int incl[256];
    __shared__ int lcur[256];
    __shared__ int2 lpairs[CH];

    hist[t] = 0;
    __syncthreads();

    int2 loc[16];
#pragma unroll
    for (int j = 0; j < 16; ++j) {
        int e = c0 + j * 256 + t;
        int s = -1, d = -1;
        if (e < NE) {
            s = ei[e]; d = ei[NE + e];
            atomicAdd(&hist[d >> 8], 1);
        }
        loc[j] = make_int2(s, d);
    }
    __syncthreads();

    int v = hist[t];
    incl[t] = v;
    __syncthreads();
    for (int off = 1; off < 256; off <<= 1) {
        int u = (t >= off) ? incl[t - off] : 0;
        __syncthreads();
        incl[t] += u;
        __syncthreads();
    }
    lcur[t] = incl[t] - v;
    if (t < NB) histg[c * NB + t] = v;
    __syncthreads();

#pragma unroll
    for (int j = 0; j < 16; ++j) {
        int d = loc[j].y;
        if (d >= 0) {
            int p = atomicAdd(&lcur[d >> 8], 1);
            lpairs[p] = loc[j];
        }
    }
    __syncthreads();

    const int total = incl[255];
    for (int p = t; p < total; p += 256) {
        int2 pr = lpairs[p];
        int b = pr.y >> 8;
        int i = p - (incl[b] - hist[b]);
        ebuf[(b * NC + c) * CELL + i] = pr;
    }
}

// ---------------------------------------------------------------- level-2: per-bucket CSR + dis
__global__ __launch_bounds__(256) void build_csr(const int2* __restrict__ ebuf,
                                                 const int* __restrict__ histg,
                                                 int2* __restrict__ row_range,
                                                 float* __restrict__ dis,
                                                 int* __restrict__ csr_src) {
    const int b = blockIdx.x, t = threadIdx.x;
    const int e0 = b * CAP;
    const int node = b * 256 + t;
    __shared__ int coff[256];
    __shared__ int deg_l[256];
    __shared__ int pre[256];
    __shared__ int cur[256];
    __shared__ int2 lpairs[CAP];
    __shared__ int lsrc[CAP];

    int cv = (t < NB) ? histg[t * NB + b] : 0;
    coff[t] = cv;
    __syncthreads();
    for (int off = 1; off < 256; off <<= 1) {
        int u = (t >= off) ? coff[t - off] : 0;
        __syncthreads();
        coff[t] += u;
        __syncthreads();
    }
    if (cv > 0) {
        const int2* src = &ebuf[(b * NC + t) * CELL];
        int dst = coff[t] - cv;
        for (int i = 0; i < cv; ++i)
            lpairs[dst + i] = src[i];
    }
    deg_l[t] = (node < NN) ? 1 : 0;   // self-loop
    __syncthreads();

    const int total = coff[255];
    for (int i = t; i < total; i += 256)
        atomicAdd(&deg_l[lpairs[i].y & 255], 1);
    __syncthreads();

    int v = deg_l[t];
    pre[t] = v;
    __syncthreads();
    for (int off = 1; off < 256; off <<= 1) {
        int u = (t >= off) ? pre[t - off] : 0;
        __syncthreads();
        pre[t] += u;
        __syncthreads();
    }
    int excl = pre[t] - v;
    cur[t] = 1;                        // slot 0 = self-loop
    if (node < NN) {
        lsrc[excl] = node;
        row_range[node] = make_int2(e0 + excl, e0 + pre[t]);
        dis[node] = rsqrtf((float)v);  // v = deg+1
    }
    __syncthreads();
    for (int i = t; i < total; i += 256) {
        int2 p = lpairs[i];
        int d = p.y & 255;
        int pos = (pre[d] - deg_l[d]) + atomicAdd(&cur[d], 1);
        lsrc[pos] = p.x;
    }
    __syncthreads();
    const int tot_all = pre[255];
    for (int i = t; i < tot_all; i += 256)
        csr_src[e0 + i] = lsrc[i];
}

// ---------------------------------------------------------------- GEMM1 via MFMA:
// Y = bf16(dis .* (X @ W1)); 64x64 tile, K=128, 4 waves (16 rows each).
// A layout [m=lane&15][k=quad*8+j], B layout [n=lane&15][k=quad*8+j],
// C layout col=lane&15, row=quad*4+reg (m120/m89-verified mappings).
__global__ __launch_bounds__(256) void gemm1_mfma(const float* __restrict__ X,
                                                  const float* __restrict__ W,
                                                  const float* __restrict__ dis,
                                                  unsigned short* __restrict__ Y) {
    __shared__ unsigned short Xs[64 * 136];  // [node][k] bf16, stride 136 (2-way alias only)
    __shared__ unsigned int   Wt[64 * 68];   // [n][kpair] packed bf16x2, stride 68
    const int t = threadIdx.x;
    const int base = blockIdx.x * 64;

    for (int i = t * 4; i < 64 * 128; i += 1024) {
        int node = i >> 7, k = i & 127;
        int gn = base + node; if (gn >= NN) gn = NN - 1;
        float4 v = *(const float4*)&X[(size_t)gn * 128 + k];
        ushort4 o = { f2bf(v.x), f2bf(v.y), f2bf(v.z), f2bf(v.w) };
        *(ushort4*)&Xs[node * 136 + k] = o;
    }
    for (int idx = t; idx < 64 * 64; idx += 256) {
        int n = idx & 63, kp = idx >> 6;
        float w0 = W[(2 * kp) * 64 + n];
        float w1 = W[(2 * kp + 1) * 64 + n];
        Wt[n * 68 + kp] = (unsigned)f2bf(w0) | ((unsigned)f2bf(w1) << 16);
    }
    __syncthreads();

    const int w = t >> 6;
    const int lane = t & 63;
    const int l15 = lane & 15;
    const int quad = lane >> 4;
    f32x4 acc[4] = {{0.f,0.f,0.f,0.f},{0.f,0.f,0.f,0.f},{0.f,0.f,0.f,0.f},{0.f,0.f,0.f,0.f}};
#pragma unroll
    for (int kk = 0; kk < 4; ++kk) {
        const bf16x8 a = *(const bf16x8*)&Xs[(w * 16 + l15) * 136 + quad * 8 + kk * 32];
#pragma unroll
        for (int nt = 0; nt < 4; ++nt) {
            const bf16x8 b = *(const bf16x8*)&Wt[(nt * 16 + l15) * 68 + quad * 4 + kk * 16];
            acc[nt] = __builtin_amdgcn_mfma_f32_16x16x32_bf16(a, b, acc[nt], 0, 0, 0);
        }
    }
    const int r0 = base + w * 16 + quad * 4;
    float4 d4 = *(const float4*)&dis[r0];   // possible tail over-read; stores guarded
    const float dd[4] = { d4.x, d4.y, d4.z, d4.w };
#pragma unroll
    for (int reg = 0; reg < 4; ++reg) {
        const int row = r0 + reg;
        if (row < NN) {
#pragma unroll
            for (int nt = 0; nt < 4; ++nt)
                Y[(size_t)row * 64 + nt * 16 + l15] = f2bf(acc[nt][reg] * dd[reg]);
        }
    }
}

// ---------------------------------------------------------------- sub-group gather core
static __device__ __forceinline__ void acc8(float* acc, const uint4 u) {
    acc[0] += lo16(u.x); acc[1] += hi16(u.x);
    acc[2] += lo16(u.y); acc[3] += hi16(u.y);
    acc[4] += lo16(u.z); acc[5] += hi16(u.z);
    acc[6] += lo16(u.w); acc[7] += hi16(u.w);
}

static __device__ __forceinline__ void gather_rows(const unsigned short* __restrict__ h,
                                                   const int* __restrict__ csr_src,
                                                   int lo, int hi, int p8, float* acc) {
    int i = lo;
    for (; i + 2 <= hi; i += 2) {
        const int i0 = csr_src[i];
        const int i1 = csr_src[i + 1];
        const uint4 u0 = *(const uint4*)&h[(i0 << 6) + p8];
        const uint4 u1 = *(const uint4*)&h[(i1 << 6) + p8];
        acc8(acc, u0);
        acc8(acc, u1);
    }
    if (i < hi) {
        const int i0 = csr_src[i];
        acc8(acc, *(const uint4*)&h[(i0 << 6) + p8]);
    }
}

// ---------------------------------------------------------------- agg1 + gemm2 fused (unchanged from R9)
__global__ __launch_bounds__(256) void agg_gemv(const unsigned short* __restrict__ h,
                                                const int2* __restrict__ row_range,
                                                const int* __restrict__ csr_src,
                                                const float* __restrict__ dis,
                                                const float* __restrict__ b1,
                                                const float* __restrict__ W2,
                                                unsigned short* __restrict__ g) {
    __shared__ float W2s[64 * 64];
    __shared__ float aS[64 * 36];
    const int t = threadIdx.x;
    for (int i = t * 4; i < 4096; i += 1024)
        *(float4*)&W2s[i] = *(const float4*)&W2[i];

    const int base = blockIdx.x * 32;
    const int nloc = t >> 3;
    const int p8 = (t & 7) * 8;
    const int n = base + nloc;
    float acc[8] = {};
    if (n < NN) {
        const int2 rr = row_range[n];
        gather_rows(h, csr_src, rr.x, rr.y, p8, acc);
        const float dn = dis[n];
        const float4 bv0 = *(const float4*)&b1[p8];
        const float4 bv1 = *(const float4*)&b1[p8 + 4];
        acc[0] = fmaxf(acc[0] * dn + bv0.x, 0.f) * dn;
        acc[1] = fmaxf(acc[1] * dn + bv0.y, 0.f) * dn;
        acc[2] = fmaxf(acc[2] * dn + bv0.z, 0.f) * dn;
        acc[3] = fmaxf(acc[3] * dn + bv0.w, 0.f) * dn;
        acc[4] = fmaxf(acc[4] * dn + bv1.x, 0.f) * dn;
        acc[5] = fmaxf(acc[5] * dn + bv1.y, 0.f) * dn;
        acc[6] = fmaxf(acc[6] * dn + bv1.z, 0.f) * dn;
        acc[7] = fmaxf(acc[7] * dn + bv1.w, 0.f) * dn;
    }
#pragma unroll
    for (int j = 0; j < 8; ++j)
        aS[(p8 + j) * 36 + nloc] = acc[j];
    __syncthreads();

    const int n0 = (t & 7) * 4;
    const int c0 = (t >> 3) * 2;
    float a0x = 0, a0y = 0, a1x = 0, a1y = 0;
    float a2x = 0, a2y = 0, a3x = 0, a3y = 0;
#pragma unroll 8
    for (int k = 0; k < 64; ++k) {
        const float4 xv = *(const float4*)&aS[k * 36 + n0];
        const float2 wv = *(const float2*)&W2s[k * 64 + c0];
        a0x += xv.x * wv.x; a0y += xv.x * wv.y;
        a1x += xv.y * wv.x; a1y += xv.y * wv.y;
        a2x += xv.z * wv.x; a2y += xv.z * wv.y;
        a3x += xv.w * wv.x; a3y += xv.w * wv.y;
    }
    const int gn = base + n0;
    if (gn + 0 < NN) *(unsigned*)&g[(gn + 0) * 64 + c0] = (unsigned)f2bf(a0x) | ((unsigned)f2bf(a0y) << 16);
    if (gn + 1 < NN) *(unsigned*)&g[(gn + 1) * 64 + c0] = (unsigned)f2bf(a1x) | ((unsigned)f2bf(a1y) << 16);
    if (gn + 2 < NN) *(unsigned*)&g[(gn + 2) * 64 + c0] = (unsigned)f2bf(a2x) | ((unsigned)f2bf(a2y) << 16);
    if (gn + 3 < NN) *(unsigned*)&g[(gn + 3) * 64 + c0] = (unsigned)f2bf(a3x) | ((unsigned)f2bf(a3y) << 16);
}

// ---------------------------------------------------------------- agg2 + pooling fused
// h2 rows never hit global: block-local segment-reduce (batch sorted) ->
// fp32 atomics into psum[graph][dim].
__global__ __launch_bounds__(256) void agg_pool(const unsigned short* __restrict__ h,
                                                const int2* __restrict__ row_range,
                                                const int* __restrict__ csr_src,
                                                const float* __restrict__ dis,
                                                const float* __restrict__ bias,
                                                const int* __restrict__ batch,
                                                float* __restrict__ psum) {
    __shared__ float rowsL[32 * 68];
    __shared__ int nb[32];
    const int t = threadIdx.x;
    const int nloc = t >> 3;
    const int n = blockIdx.x * 32 + nloc;
    const int p8 = (t & 7) * 8;
    if ((t & 7) == 0) nb[nloc] = (n < NN) ? batch[n] : -1;
    if (n < NN) {
        const int2 rr = row_range[n];
        float acc[8] = {};
        gather_rows(h, csr_src, rr.x, rr.y, p8, acc);
        const float dn = dis[n];
        const float4 bv0 = *(const float4*)&bias[p8];
        const float4 bv1 = *(const float4*)&bias[p8 + 4];
        float4 r0, r1;
        r0.x = fmaxf(acc[0] * dn + bv0.x, 0.f);
        r0.y = fmaxf(acc[1] * dn + bv0.y, 0.f);
        r0.z = fmaxf(acc[2] * dn + bv0.z, 0.f);
        r0.w = fmaxf(acc[3] * dn + bv0.w, 0.f);
        r1.x = fmaxf(acc[4] * dn + bv1.x, 0.f);
        r1.y = fmaxf(acc[5] * dn + bv1.y, 0.f);
        r1.z = fmaxf(acc[6] * dn + bv1.z, 0.f);
        r1.w = fmaxf(acc[7] * dn + bv1.w, 0.f);
        *(float4*)&rowsL[nloc * 68 + p8] = r0;
        *(float4*)&rowsL[nloc * 68 + p8 + 4] = r1;
    }
    __syncthreads();
    if (t < 64) {
        float s = 0.f; int curg = -2;
        for (int r = 0; r < 32; ++r) {
            const int gg = nb[r];                 // wave-uniform
            if (gg != curg) {
                if (curg >= 0) atomicAdd(&psum[curg * 64 + t], s);
                s = 0.f; curg = gg;
            }
            if (gg >= 0) s += rowsL[r * 68 + t];
        }
        if (curg >= 0) atomicAdd(&psum[curg * 64 + t], s);
    }
}

// ---------------------------------------------------------------- head: mean + MLP
__global__ __launch_bounds__(64) void head_kernel(const float* __restrict__ psum,
                                                  const int* __restrict__ batch,
                                                  const float* __restrict__ Wm1,
                                                  const float* __restrict__ bm1,
                                                  const float* __restrict__ Wm2,
                                                  const float* __restrict__ bm2,
                                                  float* __restrict__ out) {
    const int g = blockIdx.x;
    const int t = threadIdx.x;
    int lo = 0, hi = NN;
    while (lo < hi) { int m = (lo + hi) >> 1; if (batch[m] < g) lo = m + 1; else hi = m; }
    const int s = lo;
    hi = NN;
    while (lo < hi) { int m = (lo + hi) >> 1; if (batch[m] < g + 1) lo = m + 1; else hi = m; }
    const int cnt = lo - s;

    __shared__ float pl[64];
    pl[t] = psum[g * 64 + t] / (float)(cnt > 0 ? cnt : 1);
    __syncthreads();
    float z = bm1[t];
#pragma unroll 8
    for (int k = 0; k < 64; ++k)
        z += pl[k] * Wm1[k * 64 + t];
    z = fmaxf(z, 0.f);
    float y = z * Wm2[t];
    for (int off = 32; off; off >>= 1) y += __shfl_down(y, off);
    if (t == 0) out[g] = y + bm2[0];
}

// ---------------------------------------------------------------- launch
extern "C" void kernel_launch(void* const* d_in, const int* in_sizes, int n_in,
                              void* d_out, int out_size, void* d_ws, size_t ws_size,
                              hipStream_t stream) {
    const float* x   = (const float*)d_in[0];
    const int*   ei  = (const int*)d_in[1];
    const int*   bat = (const int*)d_in[2];
    const float* W1  = (const float*)d_in[3];
    const float* b1  = (const float*)d_in[4];
    const float* W2  = (const float*)d_in[5];
    const float* b2  = (const float*)d_in[6];
    const float* Wm1 = (const float*)d_in[7];
    const float* bm1 = (const float*)d_in[8];
    const float* Wm2 = (const float*)d_in[9];
    const float* bm2 = (const float*)d_in[10];
    float* out = (float*)d_out;

    char* w = (char*)d_ws;
    int*            histg     = (int*)           (w + 0);          //   153664 B
    int2*           row_range = (int2*)          (w + 153664);     //   400000 B
    float*          dis       = (float*)         (w + 553664);     //   200000 B
    int*            csr_src   = (int*)           (w + 753664);     //  4014080 B
    int2*           ebuf      = (int2*)          (w + 4767744);    // 24586240 B
    unsigned short* bufA      = (unsigned short*)(w + 29353984);   //  6400000 B
    unsigned short* bufB      = (unsigned short*)(w + 35753984);   //  6400000 B
    float*          psum      = (float*)         (w + 42153984);   //    65536 B (end ~42.2 MB)

    hipMemsetAsync(psum, 0, NG * NH * sizeof(float), stream);
    part_scatter<<<NC, 256, 0, stream>>>(ei, histg, ebuf);
    build_csr   <<<NB, 256, 0, stream>>>(ebuf, histg, row_range, dis, csr_src);

    gemm1_mfma<<<(NN + 63) / 64, 256, 0, stream>>>(x, W1, dis, bufA);
    agg_gemv  <<<(NN + 31) / 32, 256, 0, stream>>>(bufA, row_range, csr_src, dis, b1, W2, bufB);
    agg_pool  <<<(NN + 31) / 32, 256, 0, stream>>>(bufB, row_range, csr_src, dis, b2, bat, psum);
    head_kernel<<<NG, 64, 0, stream>>>(psum, bat, Wm1, bm1, Wm2, bm2, out);
}

// Round 11
// 161.342 us; speedup vs baseline: 1.9689x; 1.0950x over previous
//
#include <hip/hip_runtime.h>

#define NN 50000            // nodes
#define NE 800000           // edges
#define NF 128              // input features
#define NH 64               // hidden
#define NG 256              // graphs
#define NB 196              // buckets of 256 dst nodes
#define NC 196              // chunks: ceil(NE/CH)
#define CH 4096             // edges per partition block
#define CELL 80             // per-(chunk,bucket) capacity
#define CAP 5120            // per-bucket CSR capacity

typedef __attribute__((ext_vector_type(8))) short bf16x8;
typedef __attribute__((ext_vector_type(4))) float f32x4;

static __device__ __forceinline__ unsigned short f2bf(float f) {
    union { float f; unsigned u; } v; v.f = f;
    unsigned r = v.u + 0x7FFF + ((v.u >> 16) & 1);   // RNE
    return (unsigned short)(r >> 16);
}
static __device__ __forceinline__ float lo16(unsigned u) {
    return __uint_as_float(u << 16);
}
static __device__ __forceinline__ float hi16(unsigned u) {
    return __uint_as_float(u & 0xFFFF0000u);
}

// ---------------------------------------------------------------- level-1 partition
__global__ __launch_bounds__(256) void part_scatter(const int* __restrict__ ei,
                                                    int* __restrict__ histg,
                                                    int2* __restrict__ ebuf) {
    const int t = threadIdx.x;
    const int c = blockIdx.x;
    const int c0 = c * CH;
    __shared__ int hist[256];
    __shared__ int incl[256];
    __shared__ int lcur[256];
    __shared__ int2 lpairs[CH];

    hist[t] = 0;
    __syncthreads();

    int2 loc[16];
#pragma unroll
    for (int j = 0; j < 16; ++j) {
        int e = c0 + j * 256 + t;
        int s = -1, d = -1;
        if (e < NE) {
            s = ei[e]; d = ei[NE + e];
            atomicAdd(&hist[d >> 8], 1);
        }
        loc[j] = make_int2(s, d);
    }
    __syncthreads();

    int v = hist[t];
    incl[t] = v;
    __syncthreads();
    for (int off = 1; off < 256; off <<= 1) {
        int u = (t >= off) ? incl[t - off] : 0;
        __syncthreads();
        incl[t] += u;
        __syncthreads();
    }
    lcur[t] = incl[t] - v;
    if (t < NB) histg[c * NB + t] = v;
    __syncthreads();

#pragma unroll
    for (int j = 0; j < 16; ++j) {
        int d = loc[j].y;
        if (d >= 0) {
            int p = atomicAdd(&lcur[d >> 8], 1);
            lpairs[p] = loc[j];
        }
    }
    __syncthreads();

    const int total = incl[255];
    for (int p = t; p < total; p += 256) {
        int2 pr = lpairs[p];
        int b = pr.y >> 8;
        int i = p - (incl[b] - hist[b]);
        ebuf[(b * NC + c) * CELL + i] = pr;
    }
}

// ---------------------------------------------------------------- level-2: per-bucket CSR + dis
__global__ __launch_bounds__(256) void build_csr(const int2* __restrict__ ebuf,
                                                 const int* __restrict__ histg,
                                                 int2* __restrict__ row_range,
                                                 float* __restrict__ dis,
                                                 int* __restrict__ csr_src) {
    const int b = blockIdx.x, t = threadIdx.x;
    const int e0 = b * CAP;
    const int node = b * 256 + t;
    __shared__ int coff[256];
    __shared__ int deg_l[256];
    __shared__ int pre[256];
    __shared__ int cur[256];
    __shared__ int2 lpairs[CAP];
    __shared__ int lsrc[CAP];

    int cv = (t < NB) ? histg[t * NB + b] : 0;
    coff[t] = cv;
    __syncthreads();
    for (int off = 1; off < 256; off <<= 1) {
        int u = (t >= off) ? coff[t - off] : 0;
        __syncthreads();
        coff[t] += u;
        __syncthreads();
    }
    if (cv > 0) {
        const int2* src = &ebuf[(b * NC + t) * CELL];
        int dst = coff[t] - cv;
        for (int i = 0; i < cv; ++i)
            lpairs[dst + i] = src[i];
    }
    deg_l[t] = (node < NN) ? 1 : 0;   // self-loop
    __syncthreads();

    const int total = coff[255];
    for (int i = t; i < total; i += 256)
        atomicAdd(&deg_l[lpairs[i].y & 255], 1);
    __syncthreads();

    int v = deg_l[t];
    pre[t] = v;
    __syncthreads();
    for (int off = 1; off < 256; off <<= 1) {
        int u = (t >= off) ? pre[t - off] : 0;
        __syncthreads();
        pre[t] += u;
        __syncthreads();
    }
    int excl = pre[t] - v;
    cur[t] = 1;                        // slot 0 = self-loop
    if (node < NN) {
        lsrc[excl] = node;
        row_range[node] = make_int2(e0 + excl, e0 + pre[t]);
        dis[node] = rsqrtf((float)v);  // v = deg+1
    }
    __syncthreads();
    for (int i = t; i < total; i += 256) {
        int2 p = lpairs[i];
        int d = p.y & 255;
        int pos = (pre[d] - deg_l[d]) + atomicAdd(&cur[d], 1);
        lsrc[pos] = p.x;
    }
    __syncthreads();
    const int tot_all = pre[255];
    for (int i = t; i < tot_all; i += 256)
        csr_src[e0 + i] = lsrc[i];
}

// ---------------------------------------------------------------- GEMM1 via MFMA:
// Y = bf16(dis .* (X @ W1)); 64x64 tile, K=128, 4 waves (16 rows each).
__global__ __launch_bounds__(256) void gemm1_mfma(const float* __restrict__ X,
                                                  const float* __restrict__ W,
                                                  const float* __restrict__ dis,
                                                  unsigned short* __restrict__ Y) {
    __shared__ unsigned short Xs[64 * 136];  // [node][k] bf16, stride 136
    __shared__ unsigned int   Wt[64 * 68];   // [n][kpair] packed bf16x2, stride 68
    const int t = threadIdx.x;
    const int base = blockIdx.x * 64;

    for (int i = t * 4; i < 64 * 128; i += 1024) {
        int node = i >> 7, k = i & 127;
        int gn = base + node; if (gn >= NN) gn = NN - 1;
        float4 v = *(const float4*)&X[(size_t)gn * 128 + k];
        ushort4 o = { f2bf(v.x), f2bf(v.y), f2bf(v.z), f2bf(v.w) };
        *(ushort4*)&Xs[node * 136 + k] = o;
    }
    for (int idx = t; idx < 64 * 64; idx += 256) {
        int n = idx & 63, kp = idx >> 6;
        float w0 = W[(2 * kp) * 64 + n];
        float w1 = W[(2 * kp + 1) * 64 + n];
        Wt[n * 68 + kp] = (unsigned)f2bf(w0) | ((unsigned)f2bf(w1) << 16);
    }
    __syncthreads();

    const int w = t >> 6;
    const int lane = t & 63;
    const int l15 = lane & 15;
    const int quad = lane >> 4;
    f32x4 acc[4] = {{0.f,0.f,0.f,0.f},{0.f,0.f,0.f,0.f},{0.f,0.f,0.f,0.f},{0.f,0.f,0.f,0.f}};
#pragma unroll
    for (int kk = 0; kk < 4; ++kk) {
        const bf16x8 a = *(const bf16x8*)&Xs[(w * 16 + l15) * 136 + quad * 8 + kk * 32];
#pragma unroll
        for (int nt = 0; nt < 4; ++nt) {
            const bf16x8 b = *(const bf16x8*)&Wt[(nt * 16 + l15) * 68 + quad * 4 + kk * 16];
            acc[nt] = __builtin_amdgcn_mfma_f32_16x16x32_bf16(a, b, acc[nt], 0, 0, 0);
        }
    }
    const int r0 = base + w * 16 + quad * 4;
    float4 d4 = *(const float4*)&dis[r0];   // tail over-read; stores guarded
    const float dd[4] = { d4.x, d4.y, d4.z, d4.w };
#pragma unroll
    for (int reg = 0; reg < 4; ++reg) {
        const int row = r0 + reg;
        if (row < NN) {
#pragma unroll
            for (int nt = 0; nt < 4; ++nt)
                Y[(size_t)row * 64 + nt * 16 + l15] = f2bf(acc[nt][reg] * dd[reg]);
        }
    }
}

// ---------------------------------------------------------------- sub-group gather core (4 rows in flight/sub)
static __device__ __forceinline__ void acc8(float* acc, const uint4 u) {
    acc[0] += lo16(u.x); acc[1] += hi16(u.x);
    acc[2] += lo16(u.y); acc[3] += hi16(u.y);
    acc[4] += lo16(u.z); acc[5] += hi16(u.z);
    acc[6] += lo16(u.w); acc[7] += hi16(u.w);
}

static __device__ __forceinline__ void gather_rows(const unsigned short* __restrict__ h,
                                                   const int* __restrict__ csr_src,
                                                   int lo, int hi, int p8, float* acc) {
    int i = lo;
    for (; i + 4 <= hi; i += 4) {
        const int i0 = csr_src[i];
        const int i1 = csr_src[i + 1];
        const int i2 = csr_src[i + 2];
        const int i3 = csr_src[i + 3];
        const uint4 u0 = *(const uint4*)&h[(i0 << 6) + p8];
        const uint4 u1 = *(const uint4*)&h[(i1 << 6) + p8];
        const uint4 u2 = *(const uint4*)&h[(i2 << 6) + p8];
        const uint4 u3 = *(const uint4*)&h[(i3 << 6) + p8];
        acc8(acc, u0); acc8(acc, u1); acc8(acc, u2); acc8(acc, u3);
    }
    for (; i + 2 <= hi; i += 2) {
        const int i0 = csr_src[i];
        const int i1 = csr_src[i + 1];
        const uint4 u0 = *(const uint4*)&h[(i0 << 6) + p8];
        const uint4 u1 = *(const uint4*)&h[(i1 << 6) + p8];
        acc8(acc, u0); acc8(acc, u1);
    }
    if (i < hi) {
        const int i0 = csr_src[i];
        acc8(acc, *(const uint4*)&h[(i0 << 6) + p8]);
    }
}

// ---------------------------------------------------------------- agg1 + gemm2 fused (MFMA phase 2)
// phase 1: 32 nodes/block, sub-per-node gather -> h1 rows bf16 into A[m][k]
//          (stride 72: 2-way bank alias only on b128 reads).
// phase 2: 32x64 @ 64x64 via 16x16x32 bf16 MFMA, 2 tiles/wave.
__global__ __launch_bounds__(256) void agg_gemv(const unsigned short* __restrict__ h,
                                                const int2* __restrict__ row_range,
                                                const int* __restrict__ csr_src,
                                                const float* __restrict__ dis,
                                                const float* __restrict__ b1,
                                                const float* __restrict__ W2,
                                                unsigned short* __restrict__ g) {
    __shared__ unsigned short W2b[64 * 72];  // [n][k] bf16
    __shared__ unsigned short A[32 * 72];    // [m=node][k=dim] bf16
    const int t = threadIdx.x;
    // stage W2^T as bf16 (coalesced row reads of W2[k][n])
    for (int idx = t; idx < 64 * 32; idx += 256) {
        int n = idx & 63, kp = idx >> 6;
        unsigned short w0 = f2bf(W2[(2 * kp) * 64 + n]);
        unsigned short w1 = f2bf(W2[(2 * kp + 1) * 64 + n]);
        *(unsigned*)&W2b[n * 72 + 2 * kp] = (unsigned)w0 | ((unsigned)w1 << 16);
    }

    const int base = blockIdx.x * 32;
    const int nloc = t >> 3;
    const int p8 = (t & 7) * 8;
    const int n = base + nloc;
    float acc[8] = {};
    if (n < NN) {
        const int2 rr = row_range[n];
        gather_rows(h, csr_src, rr.x, rr.y, p8, acc);
        const float dn = dis[n];
        const float4 bv0 = *(const float4*)&b1[p8];
        const float4 bv1 = *(const float4*)&b1[p8 + 4];
        acc[0] = fmaxf(acc[0] * dn + bv0.x, 0.f) * dn;
        acc[1] = fmaxf(acc[1] * dn + bv0.y, 0.f) * dn;
        acc[2] = fmaxf(acc[2] * dn + bv0.z, 0.f) * dn;
        acc[3] = fmaxf(acc[3] * dn + bv0.w, 0.f) * dn;
        acc[4] = fmaxf(acc[4] * dn + bv1.x, 0.f) * dn;
        acc[5] = fmaxf(acc[5] * dn + bv1.y, 0.f) * dn;
        acc[6] = fmaxf(acc[6] * dn + bv1.z, 0.f) * dn;
        acc[7] = fmaxf(acc[7] * dn + bv1.w, 0.f) * dn;
    }
    uint4 pk;
    pk.x = (unsigned)f2bf(acc[0]) | ((unsigned)f2bf(acc[1]) << 16);
    pk.y = (unsigned)f2bf(acc[2]) | ((unsigned)f2bf(acc[3]) << 16);
    pk.z = (unsigned)f2bf(acc[4]) | ((unsigned)f2bf(acc[5]) << 16);
    pk.w = (unsigned)f2bf(acc[6]) | ((unsigned)f2bf(acc[7]) << 16);
    *(uint4*)&A[nloc * 72 + p8] = pk;
    __syncthreads();

    // phase 2: wave w -> m-tile (w&1), n-tiles {2*(w>>1), 2*(w>>1)+1}
    const int w = t >> 6;
    const int lane = t & 63;
    const int l15 = lane & 15;
    const int quad = lane >> 4;
    const int mt = w & 1;
    const int nq = (w >> 1) * 2;
    const bf16x8 a0 = *(const bf16x8*)&A[(mt * 16 + l15) * 72 + quad * 8];
    const bf16x8 a1 = *(const bf16x8*)&A[(mt * 16 + l15) * 72 + 32 + quad * 8];
    const bf16x8 b00 = *(const bf16x8*)&W2b[(nq * 16 + l15) * 72 + quad * 8];
    const bf16x8 b01 = *(const bf16x8*)&W2b[(nq * 16 + l15) * 72 + 32 + quad * 8];
    const bf16x8 b10 = *(const bf16x8*)&W2b[((nq + 1) * 16 + l15) * 72 + quad * 8];
    const bf16x8 b11 = *(const bf16x8*)&W2b[((nq + 1) * 16 + l15) * 72 + 32 + quad * 8];
    f32x4 c0 = {0.f, 0.f, 0.f, 0.f}, c1 = {0.f, 0.f, 0.f, 0.f};
    c0 = __builtin_amdgcn_mfma_f32_16x16x32_bf16(a0, b00, c0, 0, 0, 0);
    c0 = __builtin_amdgcn_mfma_f32_16x16x32_bf16(a1, b01, c0, 0, 0, 0);
    c1 = __builtin_amdgcn_mfma_f32_16x16x32_bf16(a0, b10, c1, 0, 0, 0);
    c1 = __builtin_amdgcn_mfma_f32_16x16x32_bf16(a1, b11, c1, 0, 0, 0);
    const int r0 = base + mt * 16 + quad * 4;
#pragma unroll
    for (int reg = 0; reg < 4; ++reg) {
        const int row = r0 + reg;
        if (row < NN) {
            g[(size_t)row * 64 + nq * 16 + l15] = f2bf(c0[reg]);
            g[(size_t)row * 64 + (nq + 1) * 16 + l15] = f2bf(c1[reg]);
        }
    }
}

// ---------------------------------------------------------------- agg2 + pooling fused
__global__ __launch_bounds__(256) void agg_pool(const unsigned short* __restrict__ h,
                                                const int2* __restrict__ row_range,
                                                const int* __restrict__ csr_src,
                                                const float* __restrict__ dis,
                                                const float* __restrict__ bias,
                                                const int* __restrict__ batch,
                                                float* __restrict__ psum) {
    __shared__ float rowsL[32 * 68];
    __shared__ int nb[32];
    const int t = threadIdx.x;
    const int nloc = t >> 3;
    const int n = blockIdx.x * 32 + nloc;
    const int p8 = (t & 7) * 8;
    if ((t & 7) == 0) nb[nloc] = (n < NN) ? batch[n] : -1;
    if (n < NN) {
        const int2 rr = row_range[n];
        float acc[8] = {};
        gather_rows(h, csr_src, rr.x, rr.y, p8, acc);
        const float dn = dis[n];
        const float4 bv0 = *(const float4*)&bias[p8];
        const float4 bv1 = *(const float4*)&bias[p8 + 4];
        float4 r0, r1;
        r0.x = fmaxf(acc[0] * dn + bv0.x, 0.f);
        r0.y = fmaxf(acc[1] * dn + bv0.y, 0.f);
        r0.z = fmaxf(acc[2] * dn + bv0.z, 0.f);
        r0.w = fmaxf(acc[3] * dn + bv0.w, 0.f);
        r1.x = fmaxf(acc[4] * dn + bv1.x, 0.f);
        r1.y = fmaxf(acc[5] * dn + bv1.y, 0.f);
        r1.z = fmaxf(acc[6] * dn + bv1.z, 0.f);
        r1.w = fmaxf(acc[7] * dn + bv1.w, 0.f);
        *(float4*)&rowsL[nloc * 68 + p8] = r0;
        *(float4*)&rowsL[nloc * 68 + p8 + 4] = r1;
    }
    __syncthreads();
    if (t < 64) {
        float s = 0.f; int curg = -2;
        for (int r = 0; r < 32; ++r) {
            const int gg = nb[r];                 // wave-uniform
            if (gg != curg) {
                if (curg >= 0) atomicAdd(&psum[curg * 64 + t], s);
                s = 0.f; curg = gg;
            }
            if (gg >= 0) s += rowsL[r * 68 + t];
        }
        if (curg >= 0) atomicAdd(&psum[curg * 64 + t], s);
    }
}

// ---------------------------------------------------------------- head: mean + MLP
__global__ __launch_bounds__(64) void head_kernel(const float* __restrict__ psum,
                                                  const int* __restrict__ batch,
                                                  const float* __restrict__ Wm1,
                                                  const float* __restrict__ bm1,
                                                  const float* __restrict__ Wm2,
                                                  const float* __restrict__ bm2,
                                                  float* __restrict__ out) {
    const int g = blockIdx.x;
    const int t = threadIdx.x;
    int lo = 0, hi = NN;
    while (lo < hi) { int m = (lo + hi) >> 1; if (batch[m] < g) lo = m + 1; else hi = m; }
    const int s = lo;
    hi = NN;
    while (lo < hi) { int m = (lo + hi) >> 1; if (batch[m] < g + 1) lo = m + 1; else hi = m; }
    const int cnt = lo - s;

    __shared__ float pl[64];
    pl[t] = psum[g * 64 + t] / (float)(cnt > 0 ? cnt : 1);
    __syncthreads();
    float z = bm1[t];
#pragma unroll 8
    for (int k = 0; k < 64; ++k)
        z += pl[k] * Wm1[k * 64 + t];
    z = fmaxf(z, 0.f);
    float y = z * Wm2[t];
    for (int off = 32; off; off >>= 1) y += __shfl_down(y, off);
    if (t == 0) out[g] = y + bm2[0];
}

// ---------------------------------------------------------------- launch
extern "C" void kernel_launch(void* const* d_in, const int* in_sizes, int n_in,
                              void* d_out, int out_size, void* d_ws, size_t ws_size,
                              hipStream_t stream) {
    const float* x   = (const float*)d_in[0];
    const int*   ei  = (const int*)d_in[1];
    const int*   bat = (const int*)d_in[2];
    const float* W1  = (const float*)d_in[3];
    const float* b1  = (const float*)d_in[4];
    const float* W2  = (const float*)d_in[5];
    const float* b2  = (const float*)d_in[6];
    const float* Wm1 = (const float*)d_in[7];
    const float* bm1 = (const float*)d_in[8];
    const float* Wm2 = (const float*)d_in[9];
    const float* bm2 = (const float*)d_in[10];
    float* out = (float*)d_out;

    char* w = (char*)d_ws;
    int*            histg     = (int*)           (w + 0);          //   153664 B
    int2*           row_range = (int2*)          (w + 153664);     //   400000 B
    float*          dis       = (float*)         (w + 553664);     //   200000 B
    int*            csr_src   = (int*)           (w + 753664);     //  4014080 B
    int2*           ebuf      = (int2*)          (w + 4767744);    // 24586240 B
    unsigned short* bufA      = (unsigned short*)(w + 29353984);   //  6400000 B
    unsigned short* bufB      = (unsigned short*)(w + 35753984);   //  6400000 B
    float*          psum      = (float*)         (w + 42153984);   //    65536 B

    hipMemsetAsync(psum, 0, NG * NH * sizeof(float), stream);
    part_scatter<<<NC, 256, 0, stream>>>(ei, histg, ebuf);
    build_csr   <<<NB, 256, 0, stream>>>(ebuf, histg, row_range, dis, csr_src);

    gemm1_mfma<<<(NN + 63) / 64, 256, 0, stream>>>(x, W1, dis, bufA);
    agg_gemv  <<<(NN + 31) / 32, 256, 0, stream>>>(bufA, row_range, csr_src, dis, b1, W2, bufB);
    agg_pool  <<<(NN + 31) / 32, 256, 0, stream>>>(bufB, row_range, csr_src, dis, b2, bat, psum);
    head_kernel<<<NG, 64, 0, stream>>>(psum, bat, Wm1, bm1, Wm2, bm2, out);
}

// Round 13
// 159.253 us; speedup vs baseline: 1.9948x; 1.0131x over previous
//
#include <hip/hip_runtime.h>

#define NN 50000            // nodes
#define NE 800000           // edges
#define NF 128              // input features
#define NH 64               // hidden
#define NG 256              // graphs
#define NB 196              // buckets of 256 dst nodes
#define NC 196              // chunks: ceil(NE/CH)
#define CH 4096             // edges per partition block
#define CELL 80             // per-(chunk,bucket) capacity
#define CAP 5120            // per-bucket CSR capacity
#define NGB 782             // gemm blocks: ceil(NN/64)

typedef __attribute__((ext_vector_type(8))) short bf16x8;
typedef __attribute__((ext_vector_type(4))) float f32x4;

static __device__ __forceinline__ unsigned short f2bf(float f) {
    union { float f; unsigned u; } v; v.f = f;
    unsigned r = v.u + 0x7FFF + ((v.u >> 16) & 1);   // RNE
    return (unsigned short)(r >> 16);
}
static __device__ __forceinline__ float lo16(unsigned u) {
    return __uint_as_float(u << 16);
}
static __device__ __forceinline__ float hi16(unsigned u) {
    return __uint_as_float(u & 0xFFFF0000u);
}

// ---------------------------------------------------------------- fused: psum-zero + partition + gemm1
// blocks [0,NC): level-1 edge partition; blocks [NC,NC+NGB): gemm1 64-row tile.
// gemm1 writes UNSCALED X@W1 (dis is not ready yet — computed by build_csr;
// the dis[src] factor is applied at gather time in the agg kernels).
__global__ __launch_bounds__(256) void prep_gemm(const int* __restrict__ ei,
                                                 int* __restrict__ histg,
                                                 int2* __restrict__ ebuf,
                                                 const float* __restrict__ X,
                                                 const float* __restrict__ W,
                                                 unsigned short* __restrict__ Y,
                                                 float* __restrict__ psum) {
    __shared__ __align__(16) char smem[35840];
    const int t = threadIdx.x;

    if (blockIdx.x < NC) {
        // ---------------- partition path ----------------
        int* hist = (int*)smem;              // 256
        int* incl = hist + 256;              // 256
        int* lcur = incl + 256;              // 256
        int2* lpairs = (int2*)(smem + 3072); // 4096
        const int c = blockIdx.x;
        const int c0 = c * CH;

        hist[t] = 0;
        __syncthreads();

        int2 loc[16];
#pragma unroll
        for (int j = 0; j < 16; ++j) {
            int e = c0 + j * 256 + t;
            int s = -1, d = -1;
            if (e < NE) {
                s = ei[e]; d = ei[NE + e];
                atomicAdd(&hist[d >> 8], 1);
            }
            loc[j] = make_int2(s, d);
        }
        __syncthreads();

        int v = hist[t];
        incl[t] = v;
        __syncthreads();
        for (int off = 1; off < 256; off <<= 1) {
            int u = (t >= off) ? incl[t - off] : 0;
            __syncthreads();
            incl[t] += u;
            __syncthreads();
        }
        lcur[t] = incl[t] - v;
        if (t < NB) histg[c * NB + t] = v;
        __syncthreads();

#pragma unroll
        for (int j = 0; j < 16; ++j) {
            int d = loc[j].y;
            if (d >= 0) {
                int p = atomicAdd(&lcur[d >> 8], 1);
                lpairs[p] = loc[j];
            }
        }
        __syncthreads();

        const int total = incl[255];
        for (int p = t; p < total; p += 256) {
            int2 pr = lpairs[p];
            int b = pr.y >> 8;
            int i = p - (incl[b] - hist[b]);
            ebuf[(b * NC + c) * CELL + i] = pr;
        }
    } else {
        // ---------------- gemm1 path (no dis dependency) ----------------
        const int gb = blockIdx.x - NC;
        if (gb < 16)   // zero psum (16 blocks x 1024 floats = 16384)
            *(float4*)&psum[gb * 1024 + t * 4] = make_float4(0.f, 0.f, 0.f, 0.f);

        unsigned short* Xs = (unsigned short*)smem;       // 64*136 bf16
        unsigned int* Wt = (unsigned int*)(smem + 17408); // 64*68 packed
        const int base = gb * 64;

        for (int i = t * 4; i < 64 * 128; i += 1024) {
            int node = i >> 7, k = i & 127;
            int gn = base + node; if (gn >= NN) gn = NN - 1;
            float4 v = *(const float4*)&X[(size_t)gn * 128 + k];
            ushort4 o = { f2bf(v.x), f2bf(v.y), f2bf(v.z), f2bf(v.w) };
            *(ushort4*)&Xs[node * 136 + k] = o;
        }
        for (int idx = t; idx < 64 * 64; idx += 256) {
            int n = idx & 63, kp = idx >> 6;
            float w0 = W[(2 * kp) * 64 + n];
            float w1 = W[(2 * kp + 1) * 64 + n];
            Wt[n * 68 + kp] = (unsigned)f2bf(w0) | ((unsigned)f2bf(w1) << 16);
        }
        __syncthreads();

        const int w = t >> 6;
        const int lane = t & 63;
        const int l15 = lane & 15;
        const int quad = lane >> 4;
        f32x4 acc[4] = {{0.f,0.f,0.f,0.f},{0.f,0.f,0.f,0.f},{0.f,0.f,0.f,0.f},{0.f,0.f,0.f,0.f}};
#pragma unroll
        for (int kk = 0; kk < 4; ++kk) {
            const bf16x8 a = *(const bf16x8*)&Xs[(w * 16 + l15) * 136 + quad * 8 + kk * 32];
#pragma unroll
            for (int nt = 0; nt < 4; ++nt) {
                const bf16x8 b = *(const bf16x8*)&Wt[(nt * 16 + l15) * 68 + quad * 4 + kk * 16];
                acc[nt] = __builtin_amdgcn_mfma_f32_16x16x32_bf16(a, b, acc[nt], 0, 0, 0);
            }
        }
        const int r0 = base + w * 16 + quad * 4;
#pragma unroll
        for (int reg = 0; reg < 4; ++reg) {
            const int row = r0 + reg;
            if (row < NN) {
#pragma unroll
                for (int nt = 0; nt < 4; ++nt)
                    Y[(size_t)row * 64 + nt * 16 + l15] = f2bf(acc[nt][reg]);
            }
        }
    }
}

// ---------------------------------------------------------------- level-2: per-bucket CSR + dis
__global__ __launch_bounds__(256) void build_csr(const int2* __restrict__ ebuf,
                                                 const int* __restrict__ histg,
                                                 int2* __restrict__ row_range,
                                                 float* __restrict__ dis,
                                                 int* __restrict__ csr_src) {
    const int b = blockIdx.x, t = threadIdx.x;
    const int e0 = b * CAP;
    const int node = b * 256 + t;
    __shared__ int coff[256];
    __shared__ int deg_l[256];
    __shared__ int pre[256];
    __shared__ int cur[256];
    __shared__ int2 lpairs[CAP];
    __shared__ int lsrc[CAP];

    int cv = (t < NB) ? histg[t * NB + b] : 0;
    coff[t] = cv;
    __syncthreads();
    for (int off = 1; off < 256; off <<= 1) {
        int u = (t >= off) ? coff[t - off] : 0;
        __syncthreads();
        coff[t] += u;
        __syncthreads();
    }
    if (cv > 0) {
        const int2* src = &ebuf[(b * NC + t) * CELL];
        int dst = coff[t] - cv;
        for (int i = 0; i < cv; ++i)
            lpairs[dst + i] = src[i];
    }
    deg_l[t] = (node < NN) ? 1 : 0;   // self-loop
    __syncthreads();

    const int total = coff[255];
    for (int i = t; i < total; i += 256)
        atomicAdd(&deg_l[lpairs[i].y & 255], 1);
    __syncthreads();

    int v = deg_l[t];
    pre[t] = v;
    __syncthreads();
    for (int off = 1; off < 256; off <<= 1) {
        int u = (t >= off) ? pre[t - off] : 0;
        __syncthreads();
        pre[t] += u;
        __syncthreads();
    }
    int excl = pre[t] - v;
    cur[t] = 1;                        // slot 0 = self-loop
    if (node < NN) {
        lsrc[excl] = node;
        row_range[node] = make_int2(e0 + excl, e0 + pre[t]);
        dis[node] = rsqrtf((float)v);  // v = deg+1
    }
    __syncthreads();
    for (int i = t; i < total; i += 256) {
        int2 p = lpairs[i];
        int d = p.y & 255;
        int pos = (pre[d] - deg_l[d]) + atomicAdd(&cur[d], 1);
        lsrc[pos] = p.x;
    }
    __syncthreads();
    const int tot_all = pre[255];
    for (int i = t; i < tot_all; i += 256)
        csr_src[e0 + i] = lsrc[i];
}

// ---------------------------------------------------------------- weighted sub-group gather core
// acc += dis[src] * row[src]; dis load is a same-address broadcast per sub.
static __device__ __forceinline__ void acc8w(float* acc, const uint4 u, float w) {
    acc[0] = fmaf(w, lo16(u.x), acc[0]); acc[1] = fmaf(w, hi16(u.x), acc[1]);
    acc[2] = fmaf(w, lo16(u.y), acc[2]); acc[3] = fmaf(w, hi16(u.y), acc[3]);
    acc[4] = fmaf(w, lo16(u.z), acc[4]); acc[5] = fmaf(w, hi16(u.z), acc[5]);
    acc[6] = fmaf(w, lo16(u.w), acc[6]); acc[7] = fmaf(w, hi16(u.w), acc[7]);
}

static __device__ __forceinline__ void gather_rows_w(const unsigned short* __restrict__ h,
                                                     const int* __restrict__ csr_src,
                                                     const float* __restrict__ dis,
                                                     int lo, int hi, int p8, float* acc) {
    int i = lo;
    for (; i + 4 <= hi; i += 4) {
        const int i0 = csr_src[i];
        const int i1 = csr_src[i + 1];
        const int i2 = csr_src[i + 2];
        const int i3 = csr_src[i + 3];
        const float w0 = dis[i0], w1 = dis[i1], w2 = dis[i2], w3 = dis[i3];
        const uint4 u0 = *(const uint4*)&h[(i0 << 6) + p8];
        const uint4 u1 = *(const uint4*)&h[(i1 << 6) + p8];
        const uint4 u2 = *(const uint4*)&h[(i2 << 6) + p8];
        const uint4 u3 = *(const uint4*)&h[(i3 << 6) + p8];
        acc8w(acc, u0, w0); acc8w(acc, u1, w1);
        acc8w(acc, u2, w2); acc8w(acc, u3, w3);
    }
    for (; i + 2 <= hi; i += 2) {
        const int i0 = csr_src[i];
        const int i1 = csr_src[i + 1];
        const float w0 = dis[i0], w1 = dis[i1];
        const uint4 u0 = *(const uint4*)&h[(i0 << 6) + p8];
        const uint4 u1 = *(const uint4*)&h[(i1 << 6) + p8];
        acc8w(acc, u0, w0); acc8w(acc, u1, w1);
    }
    if (i < hi) {
        const int i0 = csr_src[i];
        acc8w(acc, *(const uint4*)&h[(i0 << 6) + p8], dis[i0]);
    }
}

// ---------------------------------------------------------------- agg1 + gemm2 fused (MFMA phase 2)
// h = X@W1 (unscaled); acc = sum dis[src]*h[src]; h1 = relu(dn*acc + b1);
// A = bf16(h1); g = A @ W2 (unscaled bf16).
__global__ __launch_bounds__(256) void agg_gemv(const unsigned short* __restrict__ h,
                                                const int2* __restrict__ row_range,
                                                const int* __restrict__ csr_src,
                                                const float* __restrict__ dis,
                                                const float* __restrict__ b1,
                                                const float* __restrict__ W2,
                                                unsigned short* __restrict__ g) {
    __shared__ unsigned short W2b[64 * 72];  // [n][k] bf16
    __shared__ unsigned short A[32 * 72];    // [m=node][k=dim] bf16
    const int t = threadIdx.x;
    for (int idx = t; idx < 64 * 32; idx += 256) {
        int n = idx & 63, kp = idx >> 6;
        unsigned short w0 = f2bf(W2[(2 * kp) * 64 + n]);
        unsigned short w1 = f2bf(W2[(2 * kp + 1) * 64 + n]);
        *(unsigned*)&W2b[n * 72 + 2 * kp] = (unsigned)w0 | ((unsigned)w1 << 16);
    }

    const int base = blockIdx.x * 32;
    const int nloc = t >> 3;
    const int p8 = (t & 7) * 8;
    const int n = base + nloc;
    float acc[8] = {};
    if (n < NN) {
        const int2 rr = row_range[n];
        gather_rows_w(h, csr_src, dis, rr.x, rr.y, p8, acc);
        const float dn = dis[n];
        const float4 bv0 = *(const float4*)&b1[p8];
        const float4 bv1 = *(const float4*)&b1[p8 + 4];
        acc[0] = fmaxf(acc[0] * dn + bv0.x, 0.f);
        acc[1] = fmaxf(acc[1] * dn + bv0.y, 0.f);
        acc[2] = fmaxf(acc[2] * dn + bv0.z, 0.f);
        acc[3] = fmaxf(acc[3] * dn + bv0.w, 0.f);
        acc[4] = fmaxf(acc[4] * dn + bv1.x, 0.f);
        acc[5] = fmaxf(acc[5] * dn + bv1.y, 0.f);
        acc[6] = fmaxf(acc[6] * dn + bv1.z, 0.f);
        acc[7] = fmaxf(acc[7] * dn + bv1.w, 0.f);
    }
    uint4 pk;
    pk.x = (unsigned)f2bf(acc[0]) | ((unsigned)f2bf(acc[1]) << 16);
    pk.y = (unsigned)f2bf(acc[2]) | ((unsigned)f2bf(acc[3]) << 16);
    pk.z = (unsigned)f2bf(acc[4]) | ((unsigned)f2bf(acc[5]) << 16);
    pk.w = (unsigned)f2bf(acc[6]) | ((unsigned)f2bf(acc[7]) << 16);
    *(uint4*)&A[nloc * 72 + p8] = pk;
    __syncthreads();

    const int w = t >> 6;
    const int lane = t & 63;
    const int l15 = lane & 15;
    const int quad = lane >> 4;
    const int mt = w & 1;
    const int nq = (w >> 1) * 2;
    const bf16x8 a0 = *(const bf16x8*)&A[(mt * 16 + l15) * 72 + quad * 8];
    const bf16x8 a1 = *(const bf16x8*)&A[(mt * 16 + l15) * 72 + 32 + quad * 8];
    const bf16x8 b00 = *(const bf16x8*)&W2b[(nq * 16 + l15) * 72 + quad * 8];
    const bf16x8 b01 = *(const bf16x8*)&W2b[(nq * 16 + l15) * 72 + 32 + quad * 8];
    const bf16x8 b10 = *(const bf16x8*)&W2b[((nq + 1) * 16 + l15) * 72 + quad * 8];
    const bf16x8 b11 = *(const bf16x8*)&W2b[((nq + 1) * 16 + l15) * 72 + 32 + quad * 8];
    f32x4 c0 = {0.f, 0.f, 0.f, 0.f}, c1 = {0.f, 0.f, 0.f, 0.f};
    c0 = __builtin_amdgcn_mfma_f32_16x16x32_bf16(a0, b00, c0, 0, 0, 0);
    c0 = __builtin_amdgcn_mfma_f32_16x16x32_bf16(a1, b01, c0, 0, 0, 0);
    c1 = __builtin_amdgcn_mfma_f32_16x16x32_bf16(a0, b10, c1, 0, 0, 0);
    c1 = __builtin_amdgcn_mfma_f32_16x16x32_bf16(a1, b11, c1, 0, 0, 0);
    const int r0 = base + mt * 16 + quad * 4;
#pragma unroll
    for (int reg = 0; reg < 4; ++reg) {
        const int row = r0 + reg;
        if (row < NN) {
            g[(size_t)row * 64 + nq * 16 + l15] = f2bf(c0[reg]);
            g[(size_t)row * 64 + (nq + 1) * 16 + l15] = f2bf(c1[reg]);
        }
    }
}

// ---------------------------------------------------------------- agg2 + pooling fused
__global__ __launch_bounds__(256) void agg_pool(const unsigned short* __restrict__ h,
                                                const int2* __restrict__ row_range,
                                                const int* __restrict__ csr_src,
                                                const float* __restrict__ dis,
                                                const float* __restrict__ bias,
                                                const int* __restrict__ batch,
                                                float* __restrict__ psum) {
    __shared__ float rowsL[32 * 68];
    __shared__ int nb[32];
    const int t = threadIdx.x;
    const int nloc = t >> 3;
    const int n = blockIdx.x * 32 + nloc;
    const int p8 = (t & 7) * 8;
    if ((t & 7) == 0) nb[nloc] = (n < NN) ? batch[n] : -1;
    if (n < NN) {
        const int2 rr = row_range[n];
        float acc[8] = {};
        gather_rows_w(h, csr_src, dis, rr.x, rr.y, p8, acc);
        const float dn = dis[n];
        const float4 bv0 = *(const float4*)&bias[p8];
        const float4 bv1 = *(const float4*)&bias[p8 + 4];
        float4 r0, r1;
        r0.x = fmaxf(acc[0] * dn + bv0.x, 0.f);
        r0.y = fmaxf(acc[1] * dn + bv0.y, 0.f);
        r0.z = fmaxf(acc[2] * dn + bv0.z, 0.f);
        r0.w = fmaxf(acc[3] * dn + bv0.w, 0.f);
        r1.x = fmaxf(acc[4] * dn + bv1.x, 0.f);
        r1.y = fmaxf(acc[5] * dn + bv1.y, 0.f);
        r1.z = fmaxf(acc[6] * dn + bv1.z, 0.f);
        r1.w = fmaxf(acc[7] * dn + bv1.w, 0.f);
        *(float4*)&rowsL[nloc * 68 + p8] = r0;
        *(float4*)&rowsL[nloc * 68 + p8 + 4] = r1;
    }
    __syncthreads();
    if (t < 64) {
        float s = 0.f; int curg = -2;
        for (int r = 0; r < 32; ++r) {
            const int gg = nb[r];                 // wave-uniform
            if (gg != curg) {
                if (curg >= 0) atomicAdd(&psum[curg * 64 + t], s);
                s = 0.f; curg = gg;
            }
            if (gg >= 0) s += rowsL[r * 68 + t];
        }
        if (curg >= 0) atomicAdd(&psum[curg * 64 + t], s);
    }
}

// ---------------------------------------------------------------- head: mean + MLP
__global__ __launch_bounds__(64) void head_kernel(const float* __restrict__ psum,
                                                  const int* __restrict__ batch,
                                                  const float* __restrict__ Wm1,
                                                  const float* __restrict__ bm1,
                                                  const float* __restrict__ Wm2,
                                                  const float* __restrict__ bm2,
                                                  float* __restrict__ out) {
    const int g = blockIdx.x;
    const int t = threadIdx.x;
    int lo = 0, hi = NN;
    while (lo < hi) { int m = (lo + hi) >> 1; if (batch[m] < g) lo = m + 1; else hi = m; }
    const int s = lo;
    hi = NN;
    while (lo < hi) { int m = (lo + hi) >> 1; if (batch[m] < g + 1) lo = m + 1; else hi = m; }
    const int cnt = lo - s;

    __shared__ float pl[64];
    pl[t] = psum[g * 64 + t] / (float)(cnt > 0 ? cnt : 1);
    __syncthreads();
    float z = bm1[t];
#pragma unroll 8
    for (int k = 0; k < 64; ++k)
        z += pl[k] * Wm1[k * 64 + t];
    z = fmaxf(z, 0.f);
    float y = z * Wm2[t];
    for (int off = 32; off; off >>= 1) y += __shfl_down(y, off);
    if (t == 0) out[g] = y + bm2[0];
}

// ---------------------------------------------------------------- launch
extern "C" void kernel_launch(void* const* d_in, const int* in_sizes, int n_in,
                              void* d_out, int out_size, void* d_ws, size_t ws_size,
                              hipStream_t stream) {
    const float* x   = (const float*)d_in[0];
    const int*   ei  = (const int*)d_in[1];
    const int*   bat = (const int*)d_in[2];
    const float* W1  = (const float*)d_in[3];
    const float* b1  = (const float*)d_in[4];
    const float* W2  = (const float*)d_in[5];
    const float* b2  = (const float*)d_in[6];
    const float* Wm1 = (const float*)d_in[7];
    const float* bm1 = (const float*)d_in[8];
    const float* Wm2 = (const float*)d_in[9];
    const float* bm2 = (const float*)d_in[10];
    float* out = (float*)d_out;

    char* w = (char*)d_ws;
    int*            histg     = (int*)           (w + 0);          //   153664 B
    int2*           row_range = (int2*)          (w + 153664);     //   400000 B
    float*          dis       = (float*)         (w + 553664);     //   200000 B
    int*            csr_src   = (int*)           (w + 753664);     //  4014080 B
    int2*           ebuf      = (int2*)          (w + 4767744);    // 24586240 B
    unsigned short* bufA      = (unsigned short*)(w + 29353984);   //  6400000 B
    unsigned short* bufB      = (unsigned short*)(w + 35753984);   //  6400000 B
    float*          psum      = (float*)         (w + 42153984);   //    65536 B

    prep_gemm <<<NC + NGB, 256, 0, stream>>>(ei, histg, ebuf, x, W1, bufA, psum);
    build_csr <<<NB, 256, 0, stream>>>(ebuf, histg, row_range, dis, csr_src);
    agg_gemv  <<<(NN + 31) / 32, 256, 0, stream>>>(bufA, row_range, csr_src, dis, b1, W2, bufB);
    agg_pool  <<<(NN + 31) / 32, 256, 0, stream>>>(bufB, row_range, csr_src, dis, b2, bat, psum);
    head_kernel<<<NG, 64, 0, stream>>>(psum, bat, Wm1, bm1, Wm2, bm2, out);
}

// Round 14
// 156.354 us; speedup vs baseline: 2.0317x; 1.0185x over previous
//
#include <hip/hip_runtime.h>

#define NN 50000            // nodes
#define NE 800000           // edges
#define NF 128              // input features
#define NH 64               // hidden
#define NG 256              // graphs
#define NB 196              // buckets of 256 dst nodes
#define NC 196              // chunks: ceil(NE/CH)
#define CH 4096             // edges per partition block
#define CELL 80             // per-(chunk,bucket) capacity
#define CAP 5120            // per-bucket CSR capacity
#define NGB 782             // gemm blocks: ceil(NN/64)

typedef __attribute__((ext_vector_type(8))) short bf16x8;
typedef __attribute__((ext_vector_type(4))) float f32x4;

static __device__ __forceinline__ unsigned short f2bf(float f) {
    union { float f; unsigned u; } v; v.f = f;
    unsigned r = v.u + 0x7FFF + ((v.u >> 16) & 1);   // RNE
    return (unsigned short)(r >> 16);
}
static __device__ __forceinline__ float lo16(unsigned u) {
    return __uint_as_float(u << 16);
}
static __device__ __forceinline__ float hi16(unsigned u) {
    return __uint_as_float(u & 0xFFFF0000u);
}
static __device__ __forceinline__ unsigned pack2(float a, float b) {
    return (unsigned)f2bf(a) | ((unsigned)f2bf(b) << 16);
}

// ---------------------------------------------------------------- fused: psum-zero + partition + gemm1
// blocks [0,NC): level-1 edge partition; blocks [NC,NC+NGB): gemm1 64-row tile.
// gemm1 writes UNSCALED X@W1 (dis not ready yet); build_csr folds dis in.
__global__ __launch_bounds__(256) void prep_gemm(const int* __restrict__ ei,
                                                 int* __restrict__ histg,
                                                 int2* __restrict__ ebuf,
                                                 const float* __restrict__ X,
                                                 const float* __restrict__ W,
                                                 unsigned short* __restrict__ Y,
                                                 float* __restrict__ psum) {
    __shared__ __align__(16) char smem[35840];
    const int t = threadIdx.x;

    if (blockIdx.x < NC) {
        // ---------------- partition path ----------------
        int* hist = (int*)smem;
        int* incl = hist + 256;
        int* lcur = incl + 256;
        int2* lpairs = (int2*)(smem + 3072);
        const int c = blockIdx.x;
        const int c0 = c * CH;

        hist[t] = 0;
        __syncthreads();

        int2 loc[16];
#pragma unroll
        for (int j = 0; j < 16; ++j) {
            int e = c0 + j * 256 + t;
            int s = -1, d = -1;
            if (e < NE) {
                s = ei[e]; d = ei[NE + e];
                atomicAdd(&hist[d >> 8], 1);
            }
            loc[j] = make_int2(s, d);
        }
        __syncthreads();

        int v = hist[t];
        incl[t] = v;
        __syncthreads();
        for (int off = 1; off < 256; off <<= 1) {
            int u = (t >= off) ? incl[t - off] : 0;
            __syncthreads();
            incl[t] += u;
            __syncthreads();
        }
        lcur[t] = incl[t] - v;
        if (t < NB) histg[c * NB + t] = v;
        __syncthreads();

#pragma unroll
        for (int j = 0; j < 16; ++j) {
            int d = loc[j].y;
            if (d >= 0) {
                int p = atomicAdd(&lcur[d >> 8], 1);
                lpairs[p] = loc[j];
            }
        }
        __syncthreads();

        const int total = incl[255];
        for (int p = t; p < total; p += 256) {
            int2 pr = lpairs[p];
            int b = pr.y >> 8;
            int i = p - (incl[b] - hist[b]);
            ebuf[(b * NC + c) * CELL + i] = pr;
        }
    } else {
        // ---------------- gemm1 path (no dis dependency) ----------------
        const int gb = blockIdx.x - NC;
        if (gb < 16)   // zero psum
            *(float4*)&psum[gb * 1024 + t * 4] = make_float4(0.f, 0.f, 0.f, 0.f);

        unsigned short* Xs = (unsigned short*)smem;       // 64*136 bf16
        unsigned int* Wt = (unsigned int*)(smem + 17408); // 64*68 packed
        const int base = gb * 64;

        for (int i = t * 4; i < 64 * 128; i += 1024) {
            int node = i >> 7, k = i & 127;
            int gn = base + node; if (gn >= NN) gn = NN - 1;
            float4 v = *(const float4*)&X[(size_t)gn * 128 + k];
            ushort4 o = { f2bf(v.x), f2bf(v.y), f2bf(v.z), f2bf(v.w) };
            *(ushort4*)&Xs[node * 136 + k] = o;
        }
        for (int idx = t; idx < 64 * 64; idx += 256) {
            int n = idx & 63, kp = idx >> 6;
            float w0 = W[(2 * kp) * 64 + n];
            float w1 = W[(2 * kp + 1) * 64 + n];
            Wt[n * 68 + kp] = (unsigned)f2bf(w0) | ((unsigned)f2bf(w1) << 16);
        }
        __syncthreads();

        const int w = t >> 6;
        const int lane = t & 63;
        const int l15 = lane & 15;
        const int quad = lane >> 4;
        f32x4 acc[4] = {{0.f,0.f,0.f,0.f},{0.f,0.f,0.f,0.f},{0.f,0.f,0.f,0.f},{0.f,0.f,0.f,0.f}};
#pragma unroll
        for (int kk = 0; kk < 4; ++kk) {
            const bf16x8 a = *(const bf16x8*)&Xs[(w * 16 + l15) * 136 + quad * 8 + kk * 32];
#pragma unroll
            for (int nt = 0; nt < 4; ++nt) {
                const bf16x8 b = *(const bf16x8*)&Wt[(nt * 16 + l15) * 68 + quad * 4 + kk * 16];
                acc[nt] = __builtin_amdgcn_mfma_f32_16x16x32_bf16(a, b, acc[nt], 0, 0, 0);
            }
        }
        const int r0 = base + w * 16 + quad * 4;
#pragma unroll
        for (int reg = 0; reg < 4; ++reg) {
            const int row = r0 + reg;
            if (row < NN) {
#pragma unroll
                for (int nt = 0; nt < 4; ++nt)
                    Y[(size_t)row * 64 + nt * 16 + l15] = f2bf(acc[nt][reg]);
            }
        }
    }
}

// ---------------------------------------------------------------- level-2: per-bucket CSR + dis + fold dis into h
__global__ __launch_bounds__(256) void build_csr(const int2* __restrict__ ebuf,
                                                 const int* __restrict__ histg,
                                                 int2* __restrict__ row_range,
                                                 float* __restrict__ dis,
                                                 int* __restrict__ csr_src,
                                                 unsigned short* __restrict__ h) {
    const int b = blockIdx.x, t = threadIdx.x;
    const int e0 = b * CAP;
    const int node = b * 256 + t;
    __shared__ int coff[256];
    __shared__ int deg_l[256];
    __shared__ int pre[256];
    __shared__ int cur[256];
    __shared__ float sdis[256];
    __shared__ int2 lpairs[CAP];
    __shared__ int lsrc[CAP];

    int cv = (t < NB) ? histg[t * NB + b] : 0;
    coff[t] = cv;
    __syncthreads();
    for (int off = 1; off < 256; off <<= 1) {
        int u = (t >= off) ? coff[t - off] : 0;
        __syncthreads();
        coff[t] += u;
        __syncthreads();
    }
    if (cv > 0) {
        const int2* src = &ebuf[(b * NC + t) * CELL];
        int dst = coff[t] - cv;
        for (int i = 0; i < cv; ++i)
            lpairs[dst + i] = src[i];
    }
    deg_l[t] = (node < NN) ? 1 : 0;   // self-loop
    __syncthreads();

    const int total = coff[255];
    for (int i = t; i < total; i += 256)
        atomicAdd(&deg_l[lpairs[i].y & 255], 1);
    __syncthreads();

    int v = deg_l[t];
    pre[t] = v;
    __syncthreads();
    for (int off = 1; off < 256; off <<= 1) {
        int u = (t >= off) ? pre[t - off] : 0;
        __syncthreads();
        pre[t] += u;
        __syncthreads();
    }
    int excl = pre[t] - v;
    cur[t] = 1;                        // slot 0 = self-loop
    float dv = 0.f;
    if (node < NN) {
        lsrc[excl] = node;
        row_range[node] = make_int2(e0 + excl, e0 + pre[t]);
        dv = rsqrtf((float)v);         // v = deg+1
        dis[node] = dv;
    }
    sdis[t] = dv;
    __syncthreads();
    for (int i = t; i < total; i += 256) {
        int2 p = lpairs[i];
        int d = p.y & 255;
        int pos = (pre[d] - deg_l[d]) + atomicAdd(&cur[d], 1);
        lsrc[pos] = p.x;
    }
    __syncthreads();
    const int tot_all = pre[255];
    for (int i = t; i < tot_all; i += 256)
        csr_src[e0 + i] = lsrc[i];

    // fold dis into h rows (bufA written by prep_gemm, previous dispatch):
    // 8 lanes per row, 32 rows per pass — fully coalesced r/m/w.
    const int rl0 = t >> 3;
    const int d8 = (t & 7) * 8;
#pragma unroll
    for (int c = 0; c < 8; ++c) {
        const int rl = c * 32 + rl0;
        const int n2 = b * 256 + rl;
        if (n2 < NN) {
            const float dd = sdis[rl];
            uint4 u = *(uint4*)&h[(size_t)n2 * 64 + d8];
            uint4 o;
            o.x = pack2(lo16(u.x) * dd, hi16(u.x) * dd);
            o.y = pack2(lo16(u.y) * dd, hi16(u.y) * dd);
            o.z = pack2(lo16(u.z) * dd, hi16(u.z) * dd);
            o.w = pack2(lo16(u.w) * dd, hi16(u.w) * dd);
            *(uint4*)&h[(size_t)n2 * 64 + d8] = o;
        }
    }
}

// ---------------------------------------------------------------- sub-group gather core (pre-scaled rows, no dis)
static __device__ __forceinline__ void acc8(float* acc, const uint4 u) {
    acc[0] += lo16(u.x); acc[1] += hi16(u.x);
    acc[2] += lo16(u.y); acc[3] += hi16(u.y);
    acc[4] += lo16(u.z); acc[5] += hi16(u.z);
    acc[6] += lo16(u.w); acc[7] += hi16(u.w);
}

static __device__ __forceinline__ void gather_rows(const unsigned short* __restrict__ h,
                                                   const int* __restrict__ csr_src,
                                                   int lo, int hi, int p8, float* acc) {
    int i = lo;
    for (; i + 4 <= hi; i += 4) {
        const int i0 = csr_src[i];
        const int i1 = csr_src[i + 1];
        const int i2 = csr_src[i + 2];
        const int i3 = csr_src[i + 3];
        const uint4 u0 = *(const uint4*)&h[(i0 << 6) + p8];
        const uint4 u1 = *(const uint4*)&h[(i1 << 6) + p8];
        const uint4 u2 = *(const uint4*)&h[(i2 << 6) + p8];
        const uint4 u3 = *(const uint4*)&h[(i3 << 6) + p8];
        acc8(acc, u0); acc8(acc, u1); acc8(acc, u2); acc8(acc, u3);
    }
    for (; i + 2 <= hi; i += 2) {
        const int i0 = csr_src[i];
        const int i1 = csr_src[i + 1];
        const uint4 u0 = *(const uint4*)&h[(i0 << 6) + p8];
        const uint4 u1 = *(const uint4*)&h[(i1 << 6) + p8];
        acc8(acc, u0); acc8(acc, u1);
    }
    if (i < hi) {
        const int i0 = csr_src[i];
        acc8(acc, *(const uint4*)&h[(i0 << 6) + p8]);
    }
}

// ---------------------------------------------------------------- agg1 + gemm2 fused (MFMA phase 2)
// h rows pre-scaled by dis[src]; h1 = relu(dn*acc + b1); A = bf16(h1);
// bufB row = dis[row] * (A @ W2)  (pre-scaled for layer 2).
__global__ __launch_bounds__(256) void agg_gemv(const unsigned short* __restrict__ h,
                                                const int2* __restrict__ row_range,
                                                const int* __restrict__ csr_src,
                                                const float* __restrict__ dis,
                                                const float* __restrict__ b1,
                                                const float* __restrict__ W2,
                                                unsigned short* __restrict__ g) {
    __shared__ unsigned short W2b[64 * 72];  // [n][k] bf16
    __shared__ unsigned short A[32 * 72];    // [m=node][k=dim] bf16
    const int t = threadIdx.x;
    for (int idx = t; idx < 64 * 32; idx += 256) {
        int n = idx & 63, kp = idx >> 6;
        unsigned short w0 = f2bf(W2[(2 * kp) * 64 + n]);
        unsigned short w1 = f2bf(W2[(2 * kp + 1) * 64 + n]);
        *(unsigned*)&W2b[n * 72 + 2 * kp] = (unsigned)w0 | ((unsigned)w1 << 16);
    }

    const int base = blockIdx.x * 32;
    const int nloc = t >> 3;
    const int p8 = (t & 7) * 8;
    const int n = base + nloc;
    float acc[8] = {};
    if (n < NN) {
        const int2 rr = row_range[n];
        gather_rows(h, csr_src, rr.x, rr.y, p8, acc);
        const float dn = dis[n];
        const float4 bv0 = *(const float4*)&b1[p8];
        const float4 bv1 = *(const float4*)&b1[p8 + 4];
        acc[0] = fmaxf(acc[0] * dn + bv0.x, 0.f);
        acc[1] = fmaxf(acc[1] * dn + bv0.y, 0.f);
        acc[2] = fmaxf(acc[2] * dn + bv0.z, 0.f);
        acc[3] = fmaxf(acc[3] * dn + bv0.w, 0.f);
        acc[4] = fmaxf(acc[4] * dn + bv1.x, 0.f);
        acc[5] = fmaxf(acc[5] * dn + bv1.y, 0.f);
        acc[6] = fmaxf(acc[6] * dn + bv1.z, 0.f);
        acc[7] = fmaxf(acc[7] * dn + bv1.w, 0.f);
    }
    uint4 pk;
    pk.x = pack2(acc[0], acc[1]);
    pk.y = pack2(acc[2], acc[3]);
    pk.z = pack2(acc[4], acc[5]);
    pk.w = pack2(acc[6], acc[7]);
    *(uint4*)&A[nloc * 72 + p8] = pk;
    __syncthreads();

    const int w = t >> 6;
    const int lane = t & 63;
    const int l15 = lane & 15;
    const int quad = lane >> 4;
    const int mt = w & 1;
    const int nq = (w >> 1) * 2;
    const bf16x8 a0 = *(const bf16x8*)&A[(mt * 16 + l15) * 72 + quad * 8];
    const bf16x8 a1 = *(const bf16x8*)&A[(mt * 16 + l15) * 72 + 32 + quad * 8];
    const bf16x8 b00 = *(const bf16x8*)&W2b[(nq * 16 + l15) * 72 + quad * 8];
    const bf16x8 b01 = *(const bf16x8*)&W2b[(nq * 16 + l15) * 72 + 32 + quad * 8];
    const bf16x8 b10 = *(const bf16x8*)&W2b[((nq + 1) * 16 + l15) * 72 + quad * 8];
    const bf16x8 b11 = *(const bf16x8*)&W2b[((nq + 1) * 16 + l15) * 72 + 32 + quad * 8];
    f32x4 c0 = {0.f, 0.f, 0.f, 0.f}, c1 = {0.f, 0.f, 0.f, 0.f};
    c0 = __builtin_amdgcn_mfma_f32_16x16x32_bf16(a0, b00, c0, 0, 0, 0);
    c0 = __builtin_amdgcn_mfma_f32_16x16x32_bf16(a1, b01, c0, 0, 0, 0);
    c1 = __builtin_amdgcn_mfma_f32_16x16x32_bf16(a0, b10, c1, 0, 0, 0);
    c1 = __builtin_amdgcn_mfma_f32_16x16x32_bf16(a1, b11, c1, 0, 0, 0);
    const int r0 = base + mt * 16 + quad * 4;
    float4 d4 = *(const float4*)&dis[r0];   // tail over-read; stores guarded
    const float dd[4] = { d4.x, d4.y, d4.z, d4.w };
#pragma unroll
    for (int reg = 0; reg < 4; ++reg) {
        const int row = r0 + reg;
        if (row < NN) {
            g[(size_t)row * 64 + nq * 16 + l15] = f2bf(c0[reg] * dd[reg]);
            g[(size_t)row * 64 + (nq + 1) * 16 + l15] = f2bf(c1[reg] * dd[reg]);
        }
    }
}

// ---------------------------------------------------------------- agg2 + pooling fused
__global__ __launch_bounds__(256) void agg_pool(const unsigned short* __restrict__ h,
                                                const int2* __restrict__ row_range,
                                                const int* __restrict__ csr_src,
                                                const float* __restrict__ dis,
                                                const float* __restrict__ bias,
                                                const int* __restrict__ batch,
                                                float* __restrict__ psum) {
    __shared__ float rowsL[32 * 68];
    __shared__ int nb[32];
    const int t = threadIdx.x;
    const int nloc = t >> 3;
    const int n = blockIdx.x * 32 + nloc;
    const int p8 = (t & 7) * 8;
    if ((t & 7) == 0) nb[nloc] = (n < NN) ? batch[n] : -1;
    if (n < NN) {
        const int2 rr = row_range[n];
        float acc[8] = {};
        gather_rows(h, csr_src, rr.x, rr.y, p8, acc);
        const float dn = dis[n];
        const float4 bv0 = *(const float4*)&bias[p8];
        const float4 bv1 = *(const float4*)&bias[p8 + 4];
        float4 r0, r1;
        r0.x = fmaxf(acc[0] * dn + bv0.x, 0.f);
        r0.y = fmaxf(acc[1] * dn + bv0.y, 0.f);
        r0.z = fmaxf(acc[2] * dn + bv0.z, 0.f);
        r0.w = fmaxf(acc[3] * dn + bv0.w, 0.f);
        r1.x = fmaxf(acc[4] * dn + bv1.x, 0.f);
        r1.y = fmaxf(acc[5] * dn + bv1.y, 0.f);
        r1.z = fmaxf(acc[6] * dn + bv1.z, 0.f);
        r1.w = fmaxf(acc[7] * dn + bv1.w, 0.f);
        *(float4*)&rowsL[nloc * 68 + p8] = r0;
        *(float4*)&rowsL[nloc * 68 + p8 + 4] = r1;
    }
    __syncthreads();
    if (t < 64) {
        float s = 0.f; int curg = -2;
        for (int r = 0; r < 32; ++r) {
            const int gg = nb[r];                 // wave-uniform
            if (gg != curg) {
                if (curg >= 0) atomicAdd(&psum[curg * 64 + t], s);
                s = 0.f; curg = gg;
            }
            if (gg >= 0) s += rowsL[r * 68 + t];
        }
        if (curg >= 0) atomicAdd(&psum[curg * 64 + t], s);
    }
}

// ---------------------------------------------------------------- head: mean + MLP
__global__ __launch_bounds__(64) void head_kernel(const float* __restrict__ psum,
                                                  const int* __restrict__ batch,
                                                  const float* __restrict__ Wm1,
                                                  const float* __restrict__ bm1,
                                                  const float* __restrict__ Wm2,
                                                  const float* __restrict__ bm2,
                                                  float* __restrict__ out) {
    const int g = blockIdx.x;
    const int t = threadIdx.x;
    int lo = 0, hi = NN;
    while (lo < hi) { int m = (lo + hi) >> 1; if (batch[m] < g) lo = m + 1; else hi = m; }
    const int s = lo;
    hi = NN;
    while (lo < hi) { int m = (lo + hi) >> 1; if (batch[m] < g + 1) lo = m + 1; else hi = m; }
    const int cnt = lo - s;

    __shared__ float pl[64];
    pl[t] = psum[g * 64 + t] / (float)(cnt > 0 ? cnt : 1);
    __syncthreads();
    float z = bm1[t];
#pragma unroll 8
    for (int k = 0; k < 64; ++k)
        z += pl[k] * Wm1[k * 64 + t];
    z = fmaxf(z, 0.f);
    float y = z * Wm2[t];
    for (int off = 32; off; off >>= 1) y += __shfl_down(y, off);
    if (t == 0) out[g] = y + bm2[0];
}

// ---------------------------------------------------------------- launch
extern "C" void kernel_launch(void* const* d_in, const int* in_sizes, int n_in,
                              void* d_out, int out_size, void* d_ws, size_t ws_size,
                              hipStream_t stream) {
    const float* x   = (const float*)d_in[0];
    const int*   ei  = (const int*)d_in[1];
    const int*   bat = (const int*)d_in[2];
    const float* W1  = (const float*)d_in[3];
    const float* b1  = (const float*)d_in[4];
    const float* W2  = (const float*)d_in[5];
    const float* b2  = (const float*)d_in[6];
    const float* Wm1 = (const float*)d_in[7];
    const float* bm1 = (const float*)d_in[8];
    const float* Wm2 = (const float*)d_in[9];
    const float* bm2 = (const float*)d_in[10];
    float* out = (float*)d_out;

    char* w = (char*)d_ws;
    int*            histg     = (int*)           (w + 0);          //   153664 B
    int2*           row_range = (int2*)          (w + 153664);     //   400000 B
    float*          dis       = (float*)         (w + 553664);     //   200000 B
    int*            csr_src   = (int*)           (w + 753664);     //  4014080 B
    int2*           ebuf      = (int2*)          (w + 4767744);    // 24586240 B
    unsigned short* bufA      = (unsigned short*)(w + 29353984);   //  6400000 B
    unsigned short* bufB      = (unsigned short*)(w + 35753984);   //  6400000 B
    float*          psum      = (float*)         (w + 42153984);   //    65536 B

    prep_gemm <<<NC + NGB, 256, 0, stream>>>(ei, histg, ebuf, x, W1, bufA, psum);
    build_csr <<<NB, 256, 0, stream>>>(ebuf, histg, row_range, dis, csr_src, bufA);
    agg_gemv  <<<(NN + 31) / 32, 256, 0, stream>>>(bufA, row_range, csr_src, dis, b1, W2, bufB);
    agg_pool  <<<(NN + 31) / 32, 256, 0, stream>>>(bufB, row_range, csr_src, dis, b2, bat, psum);
    head_kernel<<<NG, 64, 0, stream>>>(psum, bat, Wm1, bm1, Wm2, bm2, out);
}